// Round 1
// baseline (2011.120 us; speedup 1.0000x reference)
//
#include <hip/hip_runtime.h>
#include <hip/hip_bf16.h>
#include <math.h>

// ---------------- problem constants ----------------
#define NPIX   2500      // 50*50
#define CFEAT  256
#define NTOP   300
#define DFLAT  12544     // 256*7*7

// ---------------- workspace offsets (bytes) ----------------
// total needed ~31.2 MB
static constexpr size_t OFF_FEAT  = 0;          // 256*2500*4 = 2,560,000
static constexpr size_t OFF_HMAP  = 0x280000;   // 2,560,000
static constexpr size_t OFF_SCORE = 0x500000;   // 10,000
static constexpr size_t OFF_PREB  = 0x510000;   // 40,000
static constexpr size_t OFF_TS    = 0x520000;   // 1,200
static constexpr size_t OFF_TI    = 0x521000;   // 1,200
static constexpr size_t OFF_BOX   = 0x522000;   // 4,800
static constexpr size_t OFF_VAL   = 0x524000;   // 1,200
static constexpr size_t OFF_KEEP  = 0x525000;   // 1,200
static constexpr size_t OFF_IX    = 0x526000;   // 300*14*4 = 16,800
static constexpr size_t OFF_IY    = 0x52B000;   // 16,800
static constexpr size_t OFF_FLAT  = 0x540000;   // 300*12544*4 = 15,052,800
static constexpr size_t OFF_H1    = 0x1400000;  // 300*4096*4 = 4,915,200
static constexpr size_t OFF_H2    = 0x1900000;  // 4,915,200

// robust scalar decode: harness passes python ints as int32 (maybe int64 low
// word) or possibly float32; 800 as int is small, as float bits is huge.
__device__ inline float decode_dim(const void* p) {
    int iv = *(const int*)p;
    if (iv > 0 && iv < (1 << 20)) return (float)iv;
    return __int_as_float(iv);
}

// ---------------- 1. patchify conv: 16x16 stride16 VALID ----------------
// x: (3,800,800)  Wf: (256,3,16,16)  feat: (256,50,50)
__global__ void patch_conv(const float* __restrict__ x, const float* __restrict__ Wf,
                           const float* __restrict__ bf, float* __restrict__ feat) {
    __shared__ float w[768];
    int co = blockIdx.y;
    for (int t = threadIdx.x; t < 768; t += 256) w[t] = Wf[co * 768 + t];
    __syncthreads();
    int p = blockIdx.x * 256 + threadIdx.x;
    if (p >= NPIX) return;
    int py = p / 50, px = p % 50;
    float acc = bf[co];
    for (int ci = 0; ci < 3; ++ci) {
        const float* xp = x + ci * 640000 + (py * 16) * 800 + px * 16;
        const float* wc = w + ci * 256;
        for (int ky = 0; ky < 16; ++ky) {
            const float* row = xp + ky * 800;
            const float* wr = wc + ky * 16;
            #pragma unroll
            for (int kx = 0; kx < 16; ++kx) acc += row[kx] * wr[kx];
        }
    }
    feat[co * NPIX + p] = acc;
}

// ---------------- 2. 3x3 SAME conv + relu ----------------
// feat: (256,50,50)  W1: (256,256,3,3)  hmap: (256,50,50)
__global__ void conv3x3_relu(const float* __restrict__ feat, const float* __restrict__ W1,
                             const float* __restrict__ b1, float* __restrict__ hmap) {
    __shared__ float w[2304];
    int co = blockIdx.y;
    for (int t = threadIdx.x; t < 2304; t += 256) w[t] = W1[co * 2304 + t];
    __syncthreads();
    int p = blockIdx.x * 256 + threadIdx.x;
    if (p >= NPIX) return;
    int y = p / 50, xx0 = p % 50;
    float acc = b1[co];
    for (int ci = 0; ci < CFEAT; ++ci) {
        const float* f = feat + ci * NPIX;
        const float* wk = w + ci * 9;
        #pragma unroll
        for (int dy = 0; dy < 3; ++dy) {
            int yy = y + dy - 1;
            if (yy < 0 || yy > 49) continue;
            #pragma unroll
            for (int dx = 0; dx < 3; ++dx) {
                int xc = xx0 + dx - 1;
                if (xc < 0 || xc > 49) continue;
                acc += f[yy * 50 + xc] * wk[dy * 3 + dx];
            }
        }
    }
    hmap[co * NPIX + p] = fmaxf(acc, 0.0f);
}

// ---------------- 3. heads: score + pre_boxes ----------------
__global__ void head_k(const float* __restrict__ hmap, const float* __restrict__ Wc,
                       const float* __restrict__ bc, const float* __restrict__ Wb,
                       const float* __restrict__ bb, float* __restrict__ score,
                       float* __restrict__ preb) {
    int p = blockIdx.x * 256 + threadIdx.x;
    if (p >= NPIX) return;
    float s0 = bc[0], s1 = bc[1];
    float v0 = bb[0], v1 = bb[1], v2 = bb[2], v3 = bb[3];
    for (int c = 0; c < CFEAT; ++c) {
        float h = hmap[c * NPIX + p];
        s0 += h * Wc[c];
        s1 += h * Wc[256 + c];
        v0 += h * Wb[c];
        v1 += h * Wb[256 + c];
        v2 += h * Wb[512 + c];
        v3 += h * Wb[768 + c];
    }
    float m = fmaxf(s0, s1);
    float e0 = __expf(s0 - m), e1 = __expf(s1 - m);
    // use precise expf to track reference closely
    e0 = expf(s0 - m); e1 = expf(s1 - m);
    score[p] = e1 / (e0 + e1);
    preb[p * 4 + 0] = v0; preb[p * 4 + 1] = v1;
    preb[p * 4 + 2] = v2; preb[p * 4 + 3] = v3;
}

// ---------------- 4. top-k via full bitonic sort (desc value, asc index) ----
__global__ void __launch_bounds__(1024) topk_k(const float* __restrict__ score,
                                               float* __restrict__ ts, int* __restrict__ ti) {
    __shared__ float sv[4096];
    __shared__ int   si[4096];
    int tid = threadIdx.x;
    for (int t = tid; t < 4096; t += 1024) {
        sv[t] = (t < NPIX) ? score[t] : -INFINITY;
        si[t] = t;
    }
    __syncthreads();
    for (int k = 2; k <= 4096; k <<= 1) {
        for (int j = k >> 1; j > 0; j >>= 1) {
            for (int t = tid; t < 4096; t += 1024) {
                int l = t ^ j;
                if (l > t) {
                    float vt = sv[t], vl = sv[l];
                    int it = si[t], il = si[l];
                    // "before" in desired order: higher score first, tie -> lower idx
                    bool l_before_t = (vl > vt) || (vl == vt && il < it);
                    bool dir = ((t & k) == 0);
                    if (dir == l_before_t) {
                        sv[t] = vl; sv[l] = vt;
                        si[t] = il; si[l] = it;
                    }
                }
            }
            __syncthreads();
        }
    }
    for (int t = tid; t < NTOP; t += 1024) { ts[t] = sv[t]; ti[t] = si[t]; }
}

// ---------------- 5. box decode + valid + roi sample coords ----------------
__global__ void boxes_k(const float* __restrict__ preb, const int* __restrict__ ti,
                        const float* __restrict__ ts, const void* wp, const void* hp,
                        float* __restrict__ boxes, int* __restrict__ valid,
                        int* __restrict__ ixb, int* __restrict__ iyb) {
    int j = threadIdx.x;
    if (j >= NTOP) return;
    float wf = decode_dim(wp), hf = decode_dim(hp);
    int id = ti[j];
    float p0 = preb[id * 4 + 0], p1 = preb[id * 4 + 1];
    float p2 = preb[id * 4 + 2], p3 = preb[id * 4 + 3];
    float x1 = fmaxf(p2 - p0 * 0.5f, 0.0f);
    float y1 = fmaxf(p3 - p1 * 0.5f, 0.0f);
    float x2 = fminf(p2 + p0, wf);
    float y2 = fminf(p3 + p1, hf);
    boxes[j * 4 + 0] = x1; boxes[j * 4 + 1] = y1;
    boxes[j * 4 + 2] = x2; boxes[j * 4 + 3] = y2;
    valid[j] = (ts[j] > 0.5f) ? 1 : 0;
    float bx1 = x1 * 0.0625f, by1 = y1 * 0.0625f;
    float bx2 = x2 * 0.0625f, by2 = y2 * 0.0625f;
    #pragma unroll
    for (int m = 0; m < 14; ++m) {
        int i = m >> 1, s = m & 1;
        float frac = ((float)i + (s ? 0.75f : 0.25f)) / 7.0f;
        float xs = bx1 + frac * (bx2 - bx1);
        float ys = by1 + frac * (by2 - by1);
        float fx = floorf(xs); fx = fminf(fmaxf(fx, 0.0f), 49.0f);
        float fy = floorf(ys); fy = fminf(fmaxf(fy, 0.0f), 49.0f);
        ixb[j * 14 + m] = (int)fx;
        iyb[j * 14 + m] = (int)fy;
    }
}

// ---------------- 6. greedy NMS (matches the reference fori_loop) -----------
__global__ void nms_k(const float* __restrict__ boxes, const int* __restrict__ valid,
                      int* __restrict__ keep) {
    __shared__ float X1[NTOP], Y1[NTOP], X2[NTOP], Y2[NTOP], AR[NTOP];
    __shared__ int kp[NTOP];
    int t = threadIdx.x;
    if (t < NTOP) {
        float x1 = boxes[t * 4 + 0], y1 = boxes[t * 4 + 1];
        float x2 = boxes[t * 4 + 2], y2 = boxes[t * 4 + 3];
        X1[t] = x1; Y1[t] = y1; X2[t] = x2; Y2[t] = y2;
        AR[t] = fmaxf(x2 - x1, 0.0f) * fmaxf(y2 - y1, 0.0f);
        kp[t] = valid[t];
    }
    __syncthreads();
    for (int i = 0; i < NTOP - 1; ++i) {
        if (kp[i]) {
            if (t > i && t < NTOP && kp[t]) {
                float ix1 = fmaxf(X1[i], X1[t]);
                float iy1 = fmaxf(Y1[i], Y1[t]);
                float ix2 = fminf(X2[i], X2[t]);
                float iy2 = fminf(Y2[i], Y2[t]);
                float inter = fmaxf(ix2 - ix1, 0.0f) * fmaxf(iy2 - iy1, 0.0f);
                float iou = inter / fmaxf(AR[i] + AR[t] - inter, 1e-6f);
                if (iou > 0.7f) kp[t] = 0;
            }
        }
        __syncthreads();
    }
    if (t < NTOP) keep[t] = kp[t];
}

// ---------------- 7. ROI max pool -> flat (300, 256*7*7) ----------------
__global__ void roipool_k(const float* __restrict__ feat, const int* __restrict__ ixb,
                          const int* __restrict__ iyb, float* __restrict__ flat) {
    int id = blockIdx.x * 256 + threadIdx.x;
    if (id >= NTOP * DFLAT) return;
    int k = id / DFLAT, r = id % DFLAT;
    int c = r / 49, ij = r % 49, i = ij / 7, jx = ij % 7;
    const int* ix = ixb + k * 14;
    const int* iy = iyb + k * 14;
    int y0 = iy[2 * i], y1 = iy[2 * i + 1];
    int x0 = ix[2 * jx], x1 = ix[2 * jx + 1];
    const float* f = feat + c * NPIX;
    float v = fmaxf(fmaxf(f[y0 * 50 + x0], f[y0 * 50 + x1]),
                    fmaxf(f[y1 * 50 + x0], f[y1 * 50 + x1]));
    flat[id] = v;
}

// ---------------- 8. tiled f32 GEMM: C = act(A * B^T + bias) ----------------
// A: (M,K) row-major, B: (N,K) row-major, C: (M,N). K % 16 == 0, N % 64 == 0.
template <int RELU>
__global__ void __launch_bounds__(256) gemm_nt(const float* __restrict__ A,
                                               const float* __restrict__ B,
                                               const float* __restrict__ bias,
                                               float* __restrict__ C,
                                               int M, int N, int K) {
    __shared__ float As[16][68];
    __shared__ float Bs[16][68];
    int tid = threadIdx.x;
    int n0 = blockIdx.x * 64;
    int m0 = blockIdx.y * 64;
    int tr = tid & 15;   // row group: rows m0 + tr*4 + q
    int tc = tid >> 4;   // col group: cols n0 + tc*4 + p
    float acc[4][4];
    #pragma unroll
    for (int q = 0; q < 4; ++q)
        #pragma unroll
        for (int p = 0; p < 4; ++p) acc[q][p] = 0.0f;

    int arow = tid >> 2;      // 0..63
    int kq = tid & 3;         // which float4 of the 16-wide K tile
    for (int k0 = 0; k0 < K; k0 += 16) {
        // load A tile (with M bounds -> zeros)
        float4 a4 = make_float4(0.f, 0.f, 0.f, 0.f);
        int gm = m0 + arow;
        if (gm < M) a4 = *reinterpret_cast<const float4*>(A + (size_t)gm * K + k0 + kq * 4);
        As[kq * 4 + 0][arow] = a4.x;
        As[kq * 4 + 1][arow] = a4.y;
        As[kq * 4 + 2][arow] = a4.z;
        As[kq * 4 + 3][arow] = a4.w;
        // load B tile (N is multiple of 64 -> always in range)
        float4 b4 = *reinterpret_cast<const float4*>(B + (size_t)(n0 + arow) * K + k0 + kq * 4);
        Bs[kq * 4 + 0][arow] = b4.x;
        Bs[kq * 4 + 1][arow] = b4.y;
        Bs[kq * 4 + 2][arow] = b4.z;
        Bs[kq * 4 + 3][arow] = b4.w;
        __syncthreads();
        #pragma unroll
        for (int kk = 0; kk < 16; ++kk) {
            float4 av = *reinterpret_cast<const float4*>(&As[kk][tr * 4]);
            float4 bv = *reinterpret_cast<const float4*>(&Bs[kk][tc * 4]);
            float a[4] = {av.x, av.y, av.z, av.w};
            float b[4] = {bv.x, bv.y, bv.z, bv.w};
            #pragma unroll
            for (int q = 0; q < 4; ++q)
                #pragma unroll
                for (int p = 0; p < 4; ++p) acc[q][p] += a[q] * b[p];
        }
        __syncthreads();
    }
    // epilogue: bias + optional relu, float4 stores
    int n = n0 + tc * 4;
    float4 bsv = *reinterpret_cast<const float4*>(bias + n);
    float bvv[4] = {bsv.x, bsv.y, bsv.z, bsv.w};
    #pragma unroll
    for (int q = 0; q < 4; ++q) {
        int m = m0 + tr * 4 + q;
        if (m < M) {
            float4 o;
            float* op = &o.x;
            #pragma unroll
            for (int p = 0; p < 4; ++p) {
                float v = acc[q][p] + bvv[p];
                if (RELU) v = fmaxf(v, 0.0f);
                op[p] = v;
            }
            *reinterpret_cast<float4*>(C + (size_t)m * N + n) = o;
        }
    }
}

// ---------------- 9. final heads + keep mask ----------------
__global__ void final_k(const float* __restrict__ h2, const float* __restrict__ clsw,
                        const float* __restrict__ clsb, const float* __restrict__ boxw,
                        const float* __restrict__ boxb, const int* __restrict__ keep,
                        float* __restrict__ out) {
    int id = blockIdx.x * 256 + threadIdx.x;
    if (id >= NTOP * 25) return;
    int k = id / 25, o = id % 25;
    if (!keep[k]) { out[id] = 0.0f; return; }
    const float* h = h2 + (size_t)k * 4096;
    const float* w;
    float b;
    if (o < 21) { w = clsw + (size_t)o * 4096; b = clsb[o]; }
    else        { w = boxw + (size_t)(o - 21) * 4096; b = boxb[o - 21]; }
    float acc = b;
    for (int d = 0; d < 4096; ++d) acc += h[d] * w[d];
    out[id] = acc;
}

// ---------------- launch ----------------
extern "C" void kernel_launch(void* const* d_in, const int* in_sizes, int n_in,
                              void* d_out, int out_size, void* d_ws, size_t ws_size,
                              hipStream_t stream) {
    const float* x    = (const float*)d_in[0];
    // d_in[1] = gt_boxes: unused by the reference
    const float* Wf   = (const float*)d_in[2];
    const float* bf   = (const float*)d_in[3];
    const float* W1   = (const float*)d_in[4];
    const float* b1   = (const float*)d_in[5];
    const float* Wc   = (const float*)d_in[6];
    const float* bc   = (const float*)d_in[7];
    const float* Wb   = (const float*)d_in[8];
    const float* bb   = (const float*)d_in[9];
    const float* fc1w = (const float*)d_in[10];
    const float* fc1b = (const float*)d_in[11];
    const float* fc2w = (const float*)d_in[12];
    const float* fc2b = (const float*)d_in[13];
    const float* clsw = (const float*)d_in[14];
    const float* clsb = (const float*)d_in[15];
    const float* boxw = (const float*)d_in[16];
    const float* boxb = (const float*)d_in[17];
    const void*  wp   = d_in[18];
    const void*  hp   = d_in[19];

    char* ws = (char*)d_ws;
    float* feat  = (float*)(ws + OFF_FEAT);
    float* hmap  = (float*)(ws + OFF_HMAP);
    float* score = (float*)(ws + OFF_SCORE);
    float* preb  = (float*)(ws + OFF_PREB);
    float* ts    = (float*)(ws + OFF_TS);
    int*   ti    = (int*)(ws + OFF_TI);
    float* boxes = (float*)(ws + OFF_BOX);
    int*   valid = (int*)(ws + OFF_VAL);
    int*   keep  = (int*)(ws + OFF_KEEP);
    int*   ixb   = (int*)(ws + OFF_IX);
    int*   iyb   = (int*)(ws + OFF_IY);
    float* flat  = (float*)(ws + OFF_FLAT);
    float* h1    = (float*)(ws + OFF_H1);
    float* h2    = (float*)(ws + OFF_H2);
    float* out   = (float*)d_out;

    patch_conv<<<dim3(10, 256), 256, 0, stream>>>(x, Wf, bf, feat);
    conv3x3_relu<<<dim3(10, 256), 256, 0, stream>>>(feat, W1, b1, hmap);
    head_k<<<10, 256, 0, stream>>>(hmap, Wc, bc, Wb, bb, score, preb);
    topk_k<<<1, 1024, 0, stream>>>(score, ts, ti);
    boxes_k<<<1, 320, 0, stream>>>(preb, ti, ts, wp, hp, boxes, valid, ixb, iyb);
    nms_k<<<1, 320, 0, stream>>>(boxes, valid, keep);
    roipool_k<<<(NTOP * DFLAT + 255) / 256, 256, 0, stream>>>(feat, ixb, iyb, flat);
    gemm_nt<1><<<dim3(64, 5), 256, 0, stream>>>(flat, fc1w, fc1b, h1, NTOP, 4096, DFLAT);
    gemm_nt<1><<<dim3(64, 5), 256, 0, stream>>>(h1, fc2w, fc2b, h2, NTOP, 4096, 4096);
    final_k<<<(NTOP * 25 + 255) / 256, 256, 0, stream>>>(h2, clsw, clsb, boxw, boxb, keep, out);
}

// Round 2
// 994.403 us; speedup vs baseline: 2.0224x; 2.0224x over previous
//
#include <hip/hip_runtime.h>
#include <hip/hip_bf16.h>
#include <math.h>

// ---------------- problem constants ----------------
#define NPIX   2500      // 50*50
#define CFEAT  256
#define NTOP   300
#define DFLAT  12544     // 256*7*7
#define FCN    4096

typedef _Float16 f16x8 __attribute__((ext_vector_type(8)));
typedef float    f32x4 __attribute__((ext_vector_type(4)));

// ---------------- workspace offsets (bytes) ----------------
static constexpr size_t OFF_FEAT  = 0;          // 2.56 MB  (co, pix)
static constexpr size_t OFF_HMAP  = 0x280000;   // 2.56 MB  (pix, co)
static constexpr size_t OFF_SCORE = 0x500000;
static constexpr size_t OFF_PREB  = 0x510000;
static constexpr size_t OFF_TS    = 0x520000;
static constexpr size_t OFF_TI    = 0x521000;
static constexpr size_t OFF_BOX   = 0x522000;
static constexpr size_t OFF_VAL   = 0x524000;
static constexpr size_t OFF_KEEP  = 0x525000;
static constexpr size_t OFF_IX    = 0x526000;
static constexpr size_t OFF_IY    = 0x52B000;
static constexpr size_t OFF_FLAT  = 0x540000;   // 15.05 MB (also fc2 partial fallback)
static constexpr size_t OFF_H1    = 0x1400000;  // 4.9 MB
static constexpr size_t OFF_H2    = 0x1900000;  // 4.9 MB (also W1t transient, fc1 partial fallback)
static constexpr size_t OFF_PART  = 0x1E00000;  // split-K partials (up to 7 slots)

__device__ inline float decode_dim(const void* p) {
    int iv = *(const int*)p;
    if (iv > 0 && iv < (1 << 20)) return (float)iv;
    return __int_as_float(iv);
}

// ---------------- 1. patchify conv: 16x16 stride16 VALID ----------------
__global__ void patch_conv(const float* __restrict__ x, const float* __restrict__ Wf,
                           const float* __restrict__ bf, float* __restrict__ feat) {
    __shared__ float w[768];
    int co = blockIdx.y;
    for (int t = threadIdx.x; t < 768; t += 256) w[t] = Wf[co * 768 + t];
    __syncthreads();
    int p = blockIdx.x * 256 + threadIdx.x;
    if (p >= NPIX) return;
    int py = p / 50, px = p % 50;
    float acc = bf[co];
    for (int ci = 0; ci < 3; ++ci) {
        const float* xp = x + ci * 640000 + (py * 16) * 800 + px * 16;
        const float* wc = w + ci * 256;
        for (int ky = 0; ky < 16; ++ky) {
            const float* row = xp + ky * 800;
            const float* wr = wc + ky * 16;
            #pragma unroll
            for (int kx = 0; kx < 16; ++kx) acc += row[kx] * wr[kx];
        }
    }
    feat[co * NPIX + p] = acc;
}

// ---------------- 1b. transpose W1 -> (ci*9+j, co) ----------------
__global__ void transpose_w1(const float* __restrict__ W1, float* __restrict__ W1t) {
    int idx = blockIdx.x * 256 + threadIdx.x;
    if (idx >= 2304 * 256) return;
    int r = idx >> 8, co = idx & 255;
    W1t[idx] = W1[co * 2304 + r];
}

// ---------------- 2. 3x3 SAME conv + relu (lanes = co, 10-pixel batch) -----
__global__ void __launch_bounds__(256)
conv3x3_relu(const float* __restrict__ feat, const float* __restrict__ W1t,
             const float* __restrict__ b1, float* __restrict__ hmap) {
    int co = threadIdx.x;
    int b  = blockIdx.x;         // 0..249
    int y  = b / 5;
    int xb = (b % 5) * 10;
    float acc[10];
    float bv = b1[co];
    #pragma unroll
    for (int p = 0; p < 10; ++p) acc[p] = bv;
    for (int ci = 0; ci < 256; ++ci) {
        float frow[3][12];
        #pragma unroll
        for (int dy = 0; dy < 3; ++dy) {
            int yy = y + dy - 1;
            bool rowok = (yy >= 0 && yy < 50);
            const float* fr = feat + ci * NPIX + yy * 50;
            #pragma unroll
            for (int i = 0; i < 12; ++i) {
                int xc = xb + i - 1;
                frow[dy][i] = (rowok && xc >= 0 && xc < 50) ? fr[xc] : 0.0f;
            }
        }
        #pragma unroll
        for (int dy = 0; dy < 3; ++dy) {
            #pragma unroll
            for (int dx = 0; dx < 3; ++dx) {
                float wv = W1t[(ci * 9 + dy * 3 + dx) * 256 + co];
                #pragma unroll
                for (int p = 0; p < 10; ++p)
                    acc[p] += frow[dy][p + dx] * wv;
            }
        }
    }
    #pragma unroll
    for (int p = 0; p < 10; ++p)
        hmap[(y * 50 + xb + p) * 256 + co] = fmaxf(acc[p], 0.0f);
}

// ---------------- 3. heads: wave per pixel, float4 dot + shuffle reduce ----
__global__ void head_k(const float* __restrict__ hmap, const float* __restrict__ Wc,
                       const float* __restrict__ bc, const float* __restrict__ Wb,
                       const float* __restrict__ bb, float* __restrict__ score,
                       float* __restrict__ preb) {
    int lane = threadIdx.x & 63;
    int p = blockIdx.x * 4 + (threadIdx.x >> 6);
    if (p >= NPIX) return;
    float4 h  = *(const float4*)(hmap + (size_t)p * 256 + lane * 4);
    float4 c0 = *(const float4*)(Wc + lane * 4);
    float4 c1 = *(const float4*)(Wc + 256 + lane * 4);
    float4 w0 = *(const float4*)(Wb + lane * 4);
    float4 w1 = *(const float4*)(Wb + 256 + lane * 4);
    float4 w2 = *(const float4*)(Wb + 512 + lane * 4);
    float4 w3 = *(const float4*)(Wb + 768 + lane * 4);
    float s[6];
    s[0] = h.x*c0.x + h.y*c0.y + h.z*c0.z + h.w*c0.w;
    s[1] = h.x*c1.x + h.y*c1.y + h.z*c1.z + h.w*c1.w;
    s[2] = h.x*w0.x + h.y*w0.y + h.z*w0.z + h.w*w0.w;
    s[3] = h.x*w1.x + h.y*w1.y + h.z*w1.z + h.w*w1.w;
    s[4] = h.x*w2.x + h.y*w2.y + h.z*w2.z + h.w*w2.w;
    s[5] = h.x*w3.x + h.y*w3.y + h.z*w3.z + h.w*w3.w;
    #pragma unroll
    for (int o = 1; o < 64; o <<= 1) {
        #pragma unroll
        for (int q = 0; q < 6; ++q) s[q] += __shfl_xor(s[q], o, 64);
    }
    if (lane == 0) {
        float s0 = s[0] + bc[0], s1 = s[1] + bc[1];
        float m = fmaxf(s0, s1);
        float e0 = expf(s0 - m), e1 = expf(s1 - m);
        score[p] = e1 / (e0 + e1);
        preb[p * 4 + 0] = s[2] + bb[0];
        preb[p * 4 + 1] = s[3] + bb[1];
        preb[p * 4 + 2] = s[4] + bb[2];
        preb[p * 4 + 3] = s[5] + bb[3];
    }
}

// ---------------- 4. top-k via full bitonic sort (desc value, asc index) ---
__global__ void __launch_bounds__(1024) topk_k(const float* __restrict__ score,
                                               float* __restrict__ ts, int* __restrict__ ti) {
    __shared__ float sv[4096];
    __shared__ int   si[4096];
    int tid = threadIdx.x;
    for (int t = tid; t < 4096; t += 1024) {
        sv[t] = (t < NPIX) ? score[t] : -INFINITY;
        si[t] = t;
    }
    __syncthreads();
    for (int k = 2; k <= 4096; k <<= 1) {
        for (int j = k >> 1; j > 0; j >>= 1) {
            for (int t = tid; t < 4096; t += 1024) {
                int l = t ^ j;
                if (l > t) {
                    float vt = sv[t], vl = sv[l];
                    int it = si[t], il = si[l];
                    bool l_before_t = (vl > vt) || (vl == vt && il < it);
                    bool dir = ((t & k) == 0);
                    if (dir == l_before_t) {
                        sv[t] = vl; sv[l] = vt;
                        si[t] = il; si[l] = it;
                    }
                }
            }
            __syncthreads();
        }
    }
    for (int t = tid; t < NTOP; t += 1024) { ts[t] = sv[t]; ti[t] = si[t]; }
}

// ---------------- 5. box decode + valid + roi sample coords ----------------
__global__ void boxes_k(const float* __restrict__ preb, const int* __restrict__ ti,
                        const float* __restrict__ ts, const void* wp, const void* hp,
                        float* __restrict__ boxes, int* __restrict__ valid,
                        int* __restrict__ ixb, int* __restrict__ iyb) {
    int j = threadIdx.x;
    if (j >= NTOP) return;
    float wf = decode_dim(wp), hf = decode_dim(hp);
    int id = ti[j];
    float p0 = preb[id * 4 + 0], p1 = preb[id * 4 + 1];
    float p2 = preb[id * 4 + 2], p3 = preb[id * 4 + 3];
    float x1 = fmaxf(p2 - p0 * 0.5f, 0.0f);
    float y1 = fmaxf(p3 - p1 * 0.5f, 0.0f);
    float x2 = fminf(p2 + p0, wf);
    float y2 = fminf(p3 + p1, hf);
    boxes[j * 4 + 0] = x1; boxes[j * 4 + 1] = y1;
    boxes[j * 4 + 2] = x2; boxes[j * 4 + 3] = y2;
    valid[j] = (ts[j] > 0.5f) ? 1 : 0;
    float bx1 = x1 * 0.0625f, by1 = y1 * 0.0625f;
    float bx2 = x2 * 0.0625f, by2 = y2 * 0.0625f;
    #pragma unroll
    for (int m = 0; m < 14; ++m) {
        int i = m >> 1, s = m & 1;
        float frac = ((float)i + (s ? 0.75f : 0.25f)) / 7.0f;
        float xs = bx1 + frac * (bx2 - bx1);
        float ys = by1 + frac * (by2 - by1);
        float fx = floorf(xs); fx = fminf(fmaxf(fx, 0.0f), 49.0f);
        float fy = floorf(ys); fy = fminf(fmaxf(fy, 0.0f), 49.0f);
        ixb[j * 14 + m] = (int)fx;
        iyb[j * 14 + m] = (int)fy;
    }
}

// ---------------- 6. greedy NMS ----------------
__global__ void nms_k(const float* __restrict__ boxes, const int* __restrict__ valid,
                      int* __restrict__ keep) {
    __shared__ float X1[NTOP], Y1[NTOP], X2[NTOP], Y2[NTOP], AR[NTOP];
    __shared__ int kp[NTOP];
    int t = threadIdx.x;
    if (t < NTOP) {
        float x1 = boxes[t * 4 + 0], y1 = boxes[t * 4 + 1];
        float x2 = boxes[t * 4 + 2], y2 = boxes[t * 4 + 3];
        X1[t] = x1; Y1[t] = y1; X2[t] = x2; Y2[t] = y2;
        AR[t] = fmaxf(x2 - x1, 0.0f) * fmaxf(y2 - y1, 0.0f);
        kp[t] = valid[t];
    }
    __syncthreads();
    for (int i = 0; i < NTOP - 1; ++i) {
        if (kp[i]) {
            if (t > i && t < NTOP && kp[t]) {
                float ix1 = fmaxf(X1[i], X1[t]);
                float iy1 = fmaxf(Y1[i], Y1[t]);
                float ix2 = fminf(X2[i], X2[t]);
                float iy2 = fminf(Y2[i], Y2[t]);
                float inter = fmaxf(ix2 - ix1, 0.0f) * fmaxf(iy2 - iy1, 0.0f);
                float iou = inter / fmaxf(AR[i] + AR[t] - inter, 1e-6f);
                if (iou > 0.7f) kp[t] = 0;
            }
        }
        __syncthreads();
    }
    if (t < NTOP) keep[t] = kp[t];
}

// ---------------- 7. ROI max pool -> flat (300, 256*7*7) ----------------
__global__ void roipool_k(const float* __restrict__ feat, const int* __restrict__ ixb,
                          const int* __restrict__ iyb, float* __restrict__ flat) {
    int id = blockIdx.x * 256 + threadIdx.x;
    if (id >= NTOP * DFLAT) return;
    int k = id / DFLAT, r = id % DFLAT;
    int c = r / 49, ij = r % 49, i = ij / 7, jx = ij % 7;
    const int* ix = ixb + k * 14;
    const int* iy = iyb + k * 14;
    int y0 = iy[2 * i], y1 = iy[2 * i + 1];
    int x0 = ix[2 * jx], x1 = ix[2 * jx + 1];
    const float* f = feat + c * NPIX;
    float v = fmaxf(fmaxf(f[y0 * 50 + x0], f[y0 * 50 + x1]),
                    fmaxf(f[y1 * 50 + x0], f[y1 * 50 + x1]));
    flat[id] = v;
}

// ---------------- 8. f16 MFMA GEMM with split-K ----------------
// part[z] (M,N) += A(M,K)[ks..ks+kchunk) x B(N,K)^T, f32 in, f16 mfma, f32 acc.
__global__ void __launch_bounds__(256)
gemm_mfma(const float* __restrict__ A, const float* __restrict__ B,
          float* __restrict__ part, int M, int N, int K, int kchunk) {
    __shared__ char Asb[64 * 128];    // 64 rows x 64 f16
    __shared__ char Bsb[128 * 128];   // 128 rows x 64 f16
    int tid = threadIdx.x;
    int n0 = blockIdx.x * 128;
    int m0 = blockIdx.y * 64;
    int z  = blockIdx.z;
    int ks = z * kchunk;
    int klen = K - ks; if (klen > kchunk) klen = kchunk;
    int lane = tid & 63;
    int w = tid >> 6;

    f32x4 acc[4][2];
    #pragma unroll
    for (int tm = 0; tm < 4; ++tm)
        #pragma unroll
        for (int tn = 0; tn < 2; ++tn)
            acc[tm][tn] = f32x4{0.f, 0.f, 0.f, 0.f};

    for (int k0 = 0; k0 < klen; k0 += 64) {
        #pragma unroll
        for (int i = 0; i < 4; ++i) {          // A: 1024 float4
            int idx = tid + i * 256;
            int r = idx >> 4, fq = idx & 15;
            int gm = m0 + r;
            float4 v = make_float4(0.f, 0.f, 0.f, 0.f);
            if (gm < M) v = *(const float4*)(A + (size_t)gm * K + ks + k0 + fq * 4);
            union { _Float16 h[4]; uint2 u; } cv;
            cv.h[0] = (_Float16)v.x; cv.h[1] = (_Float16)v.y;
            cv.h[2] = (_Float16)v.z; cv.h[3] = (_Float16)v.w;
            *(uint2*)(Asb + r * 128 + ((fq * 8) ^ ((r & 7) << 4))) = cv.u;
        }
        #pragma unroll
        for (int i = 0; i < 8; ++i) {          // B: 2048 float4
            int idx = tid + i * 256;
            int r = idx >> 4, fq = idx & 15;
            float4 v = *(const float4*)(B + (size_t)(n0 + r) * K + ks + k0 + fq * 4);
            union { _Float16 h[4]; uint2 u; } cv;
            cv.h[0] = (_Float16)v.x; cv.h[1] = (_Float16)v.y;
            cv.h[2] = (_Float16)v.z; cv.h[3] = (_Float16)v.w;
            *(uint2*)(Bsb + r * 128 + ((fq * 8) ^ ((r & 7) << 4))) = cv.u;
        }
        __syncthreads();
        #pragma unroll
        for (int kk = 0; kk < 2; ++kk) {
            int kbyte = kk * 64 + (lane >> 4) * 16;
            f16x8 a[4], bfr[2];
            #pragma unroll
            for (int tm = 0; tm < 4; ++tm) {
                int r = tm * 16 + (lane & 15);
                a[tm] = *(const f16x8*)(Asb + r * 128 + (kbyte ^ ((r & 7) << 4)));
            }
            #pragma unroll
            for (int tn = 0; tn < 2; ++tn) {
                int r = w * 32 + tn * 16 + (lane & 15);
                bfr[tn] = *(const f16x8*)(Bsb + r * 128 + (kbyte ^ ((r & 7) << 4)));
            }
            #pragma unroll
            for (int tm = 0; tm < 4; ++tm)
                #pragma unroll
                for (int tn = 0; tn < 2; ++tn)
                    acc[tm][tn] = __builtin_amdgcn_mfma_f32_16x16x32_f16(a[tm], bfr[tn], acc[tm][tn], 0, 0, 0);
        }
        __syncthreads();
    }
    float* pout = part + (size_t)z * M * N;
    #pragma unroll
    for (int tm = 0; tm < 4; ++tm) {
        int mbase = m0 + tm * 16 + (lane >> 4) * 4;
        #pragma unroll
        for (int j = 0; j < 4; ++j) {
            int m = mbase + j;
            if (m < M) {
                #pragma unroll
                for (int tn = 0; tn < 2; ++tn) {
                    int n = n0 + w * 32 + tn * 16 + (lane & 15);
                    pout[(size_t)m * N + n] = acc[tm][tn][j];
                }
            }
        }
    }
}

// ---------------- 8b. reduce partials + bias + relu ----------------
__global__ void reduce_k(const float* __restrict__ part, const float* __restrict__ bias,
                         float* __restrict__ outp, int M, int N, int ns) {
    size_t i = (size_t)blockIdx.x * 256 + threadIdx.x;    // float4 index
    size_t mn4 = (size_t)M * N / 4;
    if (i >= mn4) return;
    float4 s = *(const float4*)(part + i * 4);
    for (int zz = 1; zz < ns; ++zz) {
        float4 v = *(const float4*)(part + (size_t)zz * M * N + i * 4);
        s.x += v.x; s.y += v.y; s.z += v.z; s.w += v.w;
    }
    int n = (int)((i * 4) % N);
    float4 b = *(const float4*)(bias + n);
    s.x = fmaxf(s.x + b.x, 0.f); s.y = fmaxf(s.y + b.y, 0.f);
    s.z = fmaxf(s.z + b.z, 0.f); s.w = fmaxf(s.w + b.w, 0.f);
    *(float4*)(outp + i * 4) = s;
}

// ---------------- 9. final heads + keep mask ----------------
__global__ void final_k(const float* __restrict__ h2, const float* __restrict__ clsw,
                        const float* __restrict__ clsb, const float* __restrict__ boxw,
                        const float* __restrict__ boxb, const int* __restrict__ keep,
                        float* __restrict__ out) {
    int id = blockIdx.x * 256 + threadIdx.x;
    if (id >= NTOP * 25) return;
    int k = id / 25, o = id % 25;
    if (!keep[k]) { out[id] = 0.0f; return; }
    const float* h = h2 + (size_t)k * 4096;
    const float* w;
    float b;
    if (o < 21) { w = clsw + (size_t)o * 4096; b = clsb[o]; }
    else        { w = boxw + (size_t)(o - 21) * 4096; b = boxb[o - 21]; }
    float acc = b;
    for (int d = 0; d < 4096; ++d) acc += h[d] * w[d];
    out[id] = acc;
}

// ---------------- launch ----------------
extern "C" void kernel_launch(void* const* d_in, const int* in_sizes, int n_in,
                              void* d_out, int out_size, void* d_ws, size_t ws_size,
                              hipStream_t stream) {
    const float* x    = (const float*)d_in[0];
    const float* Wf   = (const float*)d_in[2];
    const float* bf   = (const float*)d_in[3];
    const float* W1   = (const float*)d_in[4];
    const float* b1   = (const float*)d_in[5];
    const float* Wc   = (const float*)d_in[6];
    const float* bc   = (const float*)d_in[7];
    const float* Wb   = (const float*)d_in[8];
    const float* bb   = (const float*)d_in[9];
    const float* fc1w = (const float*)d_in[10];
    const float* fc1b = (const float*)d_in[11];
    const float* fc2w = (const float*)d_in[12];
    const float* fc2b = (const float*)d_in[13];
    const float* clsw = (const float*)d_in[14];
    const float* clsb = (const float*)d_in[15];
    const float* boxw = (const float*)d_in[16];
    const float* boxb = (const float*)d_in[17];
    const void*  wp   = d_in[18];
    const void*  hp   = d_in[19];

    char* ws = (char*)d_ws;
    float* feat  = (float*)(ws + OFF_FEAT);
    float* hmap  = (float*)(ws + OFF_HMAP);
    float* score = (float*)(ws + OFF_SCORE);
    float* preb  = (float*)(ws + OFF_PREB);
    float* ts    = (float*)(ws + OFF_TS);
    int*   ti    = (int*)(ws + OFF_TI);
    float* boxes = (float*)(ws + OFF_BOX);
    int*   valid = (int*)(ws + OFF_VAL);
    int*   keep  = (int*)(ws + OFF_KEEP);
    int*   ixb   = (int*)(ws + OFF_IX);
    int*   iyb   = (int*)(ws + OFF_IY);
    float* flat  = (float*)(ws + OFF_FLAT);
    float* h1    = (float*)(ws + OFF_H1);
    float* h2    = (float*)(ws + OFF_H2);
    float* w1t   = (float*)(ws + OFF_H2);   // transient, dead before h2 written
    float* out   = (float*)d_out;

    // split-K configuration, guarded by ws_size
    size_t slot = (size_t)NTOP * FCN * 4;   // 4.9 MB
    size_t avail = ws_size > OFF_PART ? (ws_size - OFF_PART) / slot : 0;
    float *part1, *part2;
    int ns1, ns2;
    if (avail >= 2) {
        part1 = part2 = (float*)(ws + OFF_PART);
        ns1 = (int)(avail < 7 ? avail : 7);
        ns2 = (int)(avail < 4 ? avail : 4);
    } else {
        part1 = (float*)(ws + OFF_H2);   ns1 = 1;  // h2 region free during fc1
        part2 = (float*)(ws + OFF_FLAT); ns2 = 3;  // flat free after fc1
    }
    int st1 = (196 + ns1 - 1) / ns1;  int kch1 = st1 * 64;  int ns1e = (196 + st1 - 1) / st1;
    int st2 = (64 + ns2 - 1) / ns2;   int kch2 = st2 * 64;  int ns2e = (64 + st2 - 1) / st2;

    patch_conv<<<dim3(10, 256), 256, 0, stream>>>(x, Wf, bf, feat);
    transpose_w1<<<(2304 * 256 + 255) / 256, 256, 0, stream>>>(W1, w1t);
    conv3x3_relu<<<250, 256, 0, stream>>>(feat, w1t, b1, hmap);
    head_k<<<625, 256, 0, stream>>>(hmap, Wc, bc, Wb, bb, score, preb);
    topk_k<<<1, 1024, 0, stream>>>(score, ts, ti);
    boxes_k<<<1, 320, 0, stream>>>(preb, ti, ts, wp, hp, boxes, valid, ixb, iyb);
    nms_k<<<1, 320, 0, stream>>>(boxes, valid, keep);
    roipool_k<<<(NTOP * DFLAT + 255) / 256, 256, 0, stream>>>(feat, ixb, iyb, flat);
    gemm_mfma<<<dim3(32, 5, ns1e), 256, 0, stream>>>(flat, fc1w, part1, NTOP, FCN, DFLAT, kch1);
    reduce_k<<<1200, 256, 0, stream>>>(part1, fc1b, h1, NTOP, FCN, ns1e);
    gemm_mfma<<<dim3(32, 5, ns2e), 256, 0, stream>>>(h1, fc2w, part2, NTOP, FCN, FCN, kch2);
    reduce_k<<<1200, 256, 0, stream>>>(part2, fc2b, h2, NTOP, FCN, ns2e);
    final_k<<<(NTOP * 25 + 255) / 256, 256, 0, stream>>>(h2, clsw, clsb, boxw, boxb, keep, out);
}

// Round 3
// 787.907 us; speedup vs baseline: 2.5525x; 1.2621x over previous
//
#include <hip/hip_runtime.h>
#include <hip/hip_bf16.h>
#include <math.h>

// ---------------- problem constants ----------------
#define NPIX   2500      // 50*50
#define CFEAT  256
#define NTOP   300
#define DFLAT  12544     // 256*7*7
#define FCN    4096

typedef _Float16 f16x8 __attribute__((ext_vector_type(8)));
typedef float    f32x4 __attribute__((ext_vector_type(4)));

// ---------------- workspace offsets (bytes) ----------------
static constexpr size_t OFF_FEAT  = 0;          // 2.56 MB  (co, pix)
static constexpr size_t OFF_HMAP  = 0x280000;   // 2.56 MB  (pix, co)
static constexpr size_t OFF_SCORE = 0x500000;
static constexpr size_t OFF_PREB  = 0x510000;
static constexpr size_t OFF_TS    = 0x520000;
static constexpr size_t OFF_TI    = 0x521000;
static constexpr size_t OFF_BOX   = 0x522000;
static constexpr size_t OFF_VAL   = 0x524000;
static constexpr size_t OFF_KEEP  = 0x525000;
static constexpr size_t OFF_IX    = 0x526000;
static constexpr size_t OFF_IY    = 0x52B000;
static constexpr size_t OFF_FLAT  = 0x540000;   // 15.05 MB (also fc2 partial fallback)
static constexpr size_t OFF_H1    = 0x1400000;  // 4.9 MB
static constexpr size_t OFF_H2    = 0x1900000;  // 4.9 MB (also W1t transient, fc1 partial fallback)
static constexpr size_t OFF_PART  = 0x1E00000;  // split-K partials (up to 7 slots)

__device__ inline float decode_dim(const void* p) {
    int iv = *(const int*)p;
    if (iv > 0 && iv < (1 << 20)) return (float)iv;
    return __int_as_float(iv);
}

// ---------------- 1. patchify conv: 16x16 stride16 VALID ----------------
// 4 output channels per block; x loads (float4) reused across the 4 channels.
// feat: (co, pix) f32
__global__ void __launch_bounds__(256)
patch_conv(const float* __restrict__ x, const float* __restrict__ Wf,
           const float* __restrict__ bf, float* __restrict__ feat) {
    __shared__ float w[3072];          // 4 co x 768
    int co0 = blockIdx.y * 4;
    for (int t = threadIdx.x; t < 3072; t += 256) w[t] = Wf[co0 * 768 + t];
    __syncthreads();
    int p = blockIdx.x * 256 + threadIdx.x;
    if (p >= NPIX) return;
    int py = p / 50, px = p % 50;
    float acc[4];
    #pragma unroll
    for (int c = 0; c < 4; ++c) acc[c] = bf[co0 + c];
    for (int ci = 0; ci < 3; ++ci) {
        const float* xp = x + ci * 640000 + (py * 16) * 800 + px * 16;
        #pragma unroll
        for (int ky = 0; ky < 16; ++ky) {
            const float* row = xp + ky * 800;
            #pragma unroll
            for (int kq = 0; kq < 4; ++kq) {
                float4 xv = *reinterpret_cast<const float4*>(row + kq * 4);
                int kb = ci * 256 + ky * 16 + kq * 4;
                #pragma unroll
                for (int c = 0; c < 4; ++c) {
                    const float* wc = w + c * 768 + kb;
                    acc[c] += xv.x * wc[0] + xv.y * wc[1] + xv.z * wc[2] + xv.w * wc[3];
                }
            }
        }
    }
    #pragma unroll
    for (int c = 0; c < 4; ++c) feat[(size_t)(co0 + c) * NPIX + p] = acc[c];
}

// ---------------- 1b. transpose W1 -> (ci*9+j, co) ----------------
__global__ void transpose_w1(const float* __restrict__ W1, float* __restrict__ W1t) {
    int idx = blockIdx.x * 256 + threadIdx.x;
    if (idx >= 2304 * 256) return;
    int r = idx >> 8, co = idx & 255;
    W1t[idx] = W1[co * 2304 + r];
}

// ---------------- 2. 3x3 SAME conv + relu (lanes = co, 5-pixel batch) ------
__global__ void __launch_bounds__(256)
conv3x3_relu(const float* __restrict__ feat, const float* __restrict__ W1t,
             const float* __restrict__ b1, float* __restrict__ hmap) {
    int co = threadIdx.x;
    int b  = blockIdx.x;         // 0..499
    int y  = b / 10;
    int xb = (b % 10) * 5;
    float acc[5];
    float bv = b1[co];
    #pragma unroll
    for (int p = 0; p < 5; ++p) acc[p] = bv;
    #pragma unroll 2
    for (int ci = 0; ci < 256; ++ci) {
        float frow[3][7];
        #pragma unroll
        for (int dy = 0; dy < 3; ++dy) {
            int yy = y + dy - 1;
            bool rowok = (yy >= 0 && yy < 50);
            const float* fr = feat + ci * NPIX + yy * 50;
            #pragma unroll
            for (int i = 0; i < 7; ++i) {
                int xc = xb + i - 1;
                frow[dy][i] = (rowok && xc >= 0 && xc < 50) ? fr[xc] : 0.0f;
            }
        }
        #pragma unroll
        for (int dy = 0; dy < 3; ++dy) {
            #pragma unroll
            for (int dx = 0; dx < 3; ++dx) {
                float wv = W1t[(ci * 9 + dy * 3 + dx) * 256 + co];
                #pragma unroll
                for (int p = 0; p < 5; ++p)
                    acc[p] += frow[dy][p + dx] * wv;
            }
        }
    }
    #pragma unroll
    for (int p = 0; p < 5; ++p)
        hmap[(size_t)(y * 50 + xb + p) * 256 + co] = fmaxf(acc[p], 0.0f);
}

// ---------------- 3. heads: wave per pixel, float4 dot + shuffle reduce ----
__global__ void head_k(const float* __restrict__ hmap, const float* __restrict__ Wc,
                       const float* __restrict__ bc, const float* __restrict__ Wb,
                       const float* __restrict__ bb, float* __restrict__ score,
                       float* __restrict__ preb) {
    int lane = threadIdx.x & 63;
    int p = blockIdx.x * 4 + (threadIdx.x >> 6);
    if (p >= NPIX) return;
    float4 h  = *(const float4*)(hmap + (size_t)p * 256 + lane * 4);
    float4 c0 = *(const float4*)(Wc + lane * 4);
    float4 c1 = *(const float4*)(Wc + 256 + lane * 4);
    float4 w0 = *(const float4*)(Wb + lane * 4);
    float4 w1 = *(const float4*)(Wb + 256 + lane * 4);
    float4 w2 = *(const float4*)(Wb + 512 + lane * 4);
    float4 w3 = *(const float4*)(Wb + 768 + lane * 4);
    float s[6];
    s[0] = h.x*c0.x + h.y*c0.y + h.z*c0.z + h.w*c0.w;
    s[1] = h.x*c1.x + h.y*c1.y + h.z*c1.z + h.w*c1.w;
    s[2] = h.x*w0.x + h.y*w0.y + h.z*w0.z + h.w*w0.w;
    s[3] = h.x*w1.x + h.y*w1.y + h.z*w1.z + h.w*w1.w;
    s[4] = h.x*w2.x + h.y*w2.y + h.z*w2.z + h.w*w2.w;
    s[5] = h.x*w3.x + h.y*w3.y + h.z*w3.z + h.w*w3.w;
    #pragma unroll
    for (int o = 1; o < 64; o <<= 1) {
        #pragma unroll
        for (int q = 0; q < 6; ++q) s[q] += __shfl_xor(s[q], o, 64);
    }
    if (lane == 0) {
        float s0 = s[0] + bc[0], s1 = s[1] + bc[1];
        float m = fmaxf(s0, s1);
        float e0 = expf(s0 - m), e1 = expf(s1 - m);
        score[p] = e1 / (e0 + e1);
        preb[p * 4 + 0] = s[2] + bb[0];
        preb[p * 4 + 1] = s[3] + bb[1];
        preb[p * 4 + 2] = s[4] + bb[2];
        preb[p * 4 + 3] = s[5] + bb[3];
    }
}

// ---------------- 4. top-k via full bitonic sort (desc value, asc index) ---
__global__ void __launch_bounds__(1024) topk_k(const float* __restrict__ score,
                                               float* __restrict__ ts, int* __restrict__ ti) {
    __shared__ float sv[4096];
    __shared__ int   si[4096];
    int tid = threadIdx.x;
    for (int t = tid; t < 4096; t += 1024) {
        sv[t] = (t < NPIX) ? score[t] : -INFINITY;
        si[t] = t;
    }
    __syncthreads();
    for (int k = 2; k <= 4096; k <<= 1) {
        for (int j = k >> 1; j > 0; j >>= 1) {
            for (int t = tid; t < 4096; t += 1024) {
                int l = t ^ j;
                if (l > t) {
                    float vt = sv[t], vl = sv[l];
                    int it = si[t], il = si[l];
                    bool l_before_t = (vl > vt) || (vl == vt && il < it);
                    bool dir = ((t & k) == 0);
                    if (dir == l_before_t) {
                        sv[t] = vl; sv[l] = vt;
                        si[t] = il; si[l] = it;
                    }
                }
            }
            __syncthreads();
        }
    }
    for (int t = tid; t < NTOP; t += 1024) { ts[t] = sv[t]; ti[t] = si[t]; }
}

// ---------------- 5. box decode + valid + roi sample coords ----------------
__global__ void boxes_k(const float* __restrict__ preb, const int* __restrict__ ti,
                        const float* __restrict__ ts, const void* wp, const void* hp,
                        float* __restrict__ boxes, int* __restrict__ valid,
                        int* __restrict__ ixb, int* __restrict__ iyb) {
    int j = threadIdx.x;
    if (j >= NTOP) return;
    float wf = decode_dim(wp), hf = decode_dim(hp);
    int id = ti[j];
    float p0 = preb[id * 4 + 0], p1 = preb[id * 4 + 1];
    float p2 = preb[id * 4 + 2], p3 = preb[id * 4 + 3];
    float x1 = fmaxf(p2 - p0 * 0.5f, 0.0f);
    float y1 = fmaxf(p3 - p1 * 0.5f, 0.0f);
    float x2 = fminf(p2 + p0, wf);
    float y2 = fminf(p3 + p1, hf);
    boxes[j * 4 + 0] = x1; boxes[j * 4 + 1] = y1;
    boxes[j * 4 + 2] = x2; boxes[j * 4 + 3] = y2;
    valid[j] = (ts[j] > 0.5f) ? 1 : 0;
    float bx1 = x1 * 0.0625f, by1 = y1 * 0.0625f;
    float bx2 = x2 * 0.0625f, by2 = y2 * 0.0625f;
    #pragma unroll
    for (int m = 0; m < 14; ++m) {
        int i = m >> 1, s = m & 1;
        float frac = ((float)i + (s ? 0.75f : 0.25f)) / 7.0f;
        float xs = bx1 + frac * (bx2 - bx1);
        float ys = by1 + frac * (by2 - by1);
        float fx = floorf(xs); fx = fminf(fmaxf(fx, 0.0f), 49.0f);
        float fy = floorf(ys); fy = fminf(fmaxf(fy, 0.0f), 49.0f);
        ixb[j * 14 + m] = (int)fx;
        iyb[j * 14 + m] = (int)fy;
    }
}

// ---------------- 6. greedy NMS — single wave, cheap barriers ----------------
__global__ void __launch_bounds__(64) nms_k(const float* __restrict__ boxes,
                                            const int* __restrict__ valid,
                                            int* __restrict__ keep) {
    __shared__ float X1[NTOP], Y1[NTOP], X2[NTOP], Y2[NTOP], AR[NTOP];
    __shared__ int kp[NTOP];
    int t = threadIdx.x;   // 0..63
    for (int j = t; j < NTOP; j += 64) {
        float x1 = boxes[j * 4 + 0], y1 = boxes[j * 4 + 1];
        float x2 = boxes[j * 4 + 2], y2 = boxes[j * 4 + 3];
        X1[j] = x1; Y1[j] = y1; X2[j] = x2; Y2[j] = y2;
        AR[j] = fmaxf(x2 - x1, 0.0f) * fmaxf(y2 - y1, 0.0f);
        kp[j] = valid[j];
    }
    __syncthreads();
    for (int i = 0; i < NTOP - 1; ++i) {
        if (kp[i]) {
            float xi1 = X1[i], yi1 = Y1[i], xi2 = X2[i], yi2 = Y2[i], ai = AR[i];
            for (int j = t; j < NTOP; j += 64) {
                if (j > i && kp[j]) {
                    float ix1 = fmaxf(xi1, X1[j]);
                    float iy1 = fmaxf(yi1, Y1[j]);
                    float ix2 = fminf(xi2, X2[j]);
                    float iy2 = fminf(yi2, Y2[j]);
                    float inter = fmaxf(ix2 - ix1, 0.0f) * fmaxf(iy2 - iy1, 0.0f);
                    float iou = inter / fmaxf(ai + AR[j] - inter, 1e-6f);
                    if (iou > 0.7f) kp[j] = 0;
                }
            }
        }
        __syncthreads();
    }
    for (int j = t; j < NTOP; j += 64) keep[j] = kp[j];
}

// ---------------- 7. ROI max pool -> flat (300, 256*7*7) ----------------
__global__ void roipool_k(const float* __restrict__ feat, const int* __restrict__ ixb,
                          const int* __restrict__ iyb, float* __restrict__ flat) {
    int id = blockIdx.x * 256 + threadIdx.x;
    if (id >= NTOP * DFLAT) return;
    int k = id / DFLAT, r = id % DFLAT;
    int c = r / 49, ij = r % 49, i = ij / 7, jx = ij % 7;
    const int* ix = ixb + k * 14;
    const int* iy = iyb + k * 14;
    int y0 = iy[2 * i], y1 = iy[2 * i + 1];
    int x0 = ix[2 * jx], x1 = ix[2 * jx + 1];
    const float* f = feat + c * NPIX;
    float v = fmaxf(fmaxf(f[y0 * 50 + x0], f[y0 * 50 + x1]),
                    fmaxf(f[y1 * 50 + x0], f[y1 * 50 + x1]));
    flat[id] = v;
}

// ---------------- 8. f16 MFMA GEMM with split-K ----------------
__global__ void __launch_bounds__(256)
gemm_mfma(const float* __restrict__ A, const float* __restrict__ B,
          float* __restrict__ part, int M, int N, int K, int kchunk) {
    __shared__ char Asb[64 * 128];    // 64 rows x 64 f16
    __shared__ char Bsb[128 * 128];   // 128 rows x 64 f16
    int tid = threadIdx.x;
    int n0 = blockIdx.x * 128;
    int m0 = blockIdx.y * 64;
    int z  = blockIdx.z;
    int ks = z * kchunk;
    int klen = K - ks; if (klen > kchunk) klen = kchunk;
    int lane = tid & 63;
    int w = tid >> 6;

    f32x4 acc[4][2];
    #pragma unroll
    for (int tm = 0; tm < 4; ++tm)
        #pragma unroll
        for (int tn = 0; tn < 2; ++tn)
            acc[tm][tn] = f32x4{0.f, 0.f, 0.f, 0.f};

    for (int k0 = 0; k0 < klen; k0 += 64) {
        #pragma unroll
        for (int i = 0; i < 4; ++i) {          // A: 1024 float4
            int idx = tid + i * 256;
            int r = idx >> 4, fq = idx & 15;
            int gm = m0 + r;
            float4 v = make_float4(0.f, 0.f, 0.f, 0.f);
            if (gm < M) v = *(const float4*)(A + (size_t)gm * K + ks + k0 + fq * 4);
            union { _Float16 h[4]; uint2 u; } cv;
            cv.h[0] = (_Float16)v.x; cv.h[1] = (_Float16)v.y;
            cv.h[2] = (_Float16)v.z; cv.h[3] = (_Float16)v.w;
            *(uint2*)(Asb + r * 128 + ((fq * 8) ^ ((r & 7) << 4))) = cv.u;
        }
        #pragma unroll
        for (int i = 0; i < 8; ++i) {          // B: 2048 float4
            int idx = tid + i * 256;
            int r = idx >> 4, fq = idx & 15;
            float4 v = *(const float4*)(B + (size_t)(n0 + r) * K + ks + k0 + fq * 4);
            union { _Float16 h[4]; uint2 u; } cv;
            cv.h[0] = (_Float16)v.x; cv.h[1] = (_Float16)v.y;
            cv.h[2] = (_Float16)v.z; cv.h[3] = (_Float16)v.w;
            *(uint2*)(Bsb + r * 128 + ((fq * 8) ^ ((r & 7) << 4))) = cv.u;
        }
        __syncthreads();
        #pragma unroll
        for (int kk = 0; kk < 2; ++kk) {
            int kbyte = kk * 64 + (lane >> 4) * 16;
            f16x8 a[4], bfr[2];
            #pragma unroll
            for (int tm = 0; tm < 4; ++tm) {
                int r = tm * 16 + (lane & 15);
                a[tm] = *(const f16x8*)(Asb + r * 128 + (kbyte ^ ((r & 7) << 4)));
            }
            #pragma unroll
            for (int tn = 0; tn < 2; ++tn) {
                int r = w * 32 + tn * 16 + (lane & 15);
                bfr[tn] = *(const f16x8*)(Bsb + r * 128 + (kbyte ^ ((r & 7) << 4)));
            }
            #pragma unroll
            for (int tm = 0; tm < 4; ++tm)
                #pragma unroll
                for (int tn = 0; tn < 2; ++tn)
                    acc[tm][tn] = __builtin_amdgcn_mfma_f32_16x16x32_f16(a[tm], bfr[tn], acc[tm][tn], 0, 0, 0);
        }
        __syncthreads();
    }
    float* pout = part + (size_t)z * M * N;
    #pragma unroll
    for (int tm = 0; tm < 4; ++tm) {
        int mbase = m0 + tm * 16 + (lane >> 4) * 4;
        #pragma unroll
        for (int j = 0; j < 4; ++j) {
            int m = mbase + j;
            if (m < M) {
                #pragma unroll
                for (int tn = 0; tn < 2; ++tn) {
                    int n = n0 + w * 32 + tn * 16 + (lane & 15);
                    pout[(size_t)m * N + n] = acc[tm][tn][j];
                }
            }
        }
    }
}

// ---------------- 8b. reduce partials + bias + relu ----------------
__global__ void reduce_k(const float* __restrict__ part, const float* __restrict__ bias,
                         float* __restrict__ outp, int M, int N, int ns) {
    size_t i = (size_t)blockIdx.x * 256 + threadIdx.x;    // float4 index
    size_t mn4 = (size_t)M * N / 4;
    if (i >= mn4) return;
    float4 s = *(const float4*)(part + i * 4);
    for (int zz = 1; zz < ns; ++zz) {
        float4 v = *(const float4*)(part + (size_t)zz * M * N + i * 4);
        s.x += v.x; s.y += v.y; s.z += v.z; s.w += v.w;
    }
    int n = (int)((i * 4) % N);
    float4 b = *(const float4*)(bias + n);
    s.x = fmaxf(s.x + b.x, 0.f); s.y = fmaxf(s.y + b.y, 0.f);
    s.z = fmaxf(s.z + b.z, 0.f); s.w = fmaxf(s.w + b.w, 0.f);
    *(float4*)(outp + i * 4) = s;
}

// ---------------- 9. final heads: wave per output + keep mask ----------------
__global__ void __launch_bounds__(256)
final_k(const float* __restrict__ h2, const float* __restrict__ clsw,
        const float* __restrict__ clsb, const float* __restrict__ boxw,
        const float* __restrict__ boxb, const int* __restrict__ keep,
        float* __restrict__ out) {
    int gid = blockIdx.x * 4 + (threadIdx.x >> 6);
    if (gid >= NTOP * 25) return;
    int lane = threadIdx.x & 63;
    int k = gid / 25, o = gid % 25;
    const float* w;
    float b;
    if (o < 21) { w = clsw + (size_t)o * 4096; b = clsb[o]; }
    else        { w = boxw + (size_t)(o - 21) * 4096; b = boxb[o - 21]; }
    const float* h = h2 + (size_t)k * 4096;
    float s = 0.0f;
    #pragma unroll
    for (int i = 0; i < 16; ++i) {
        float4 hv = *(const float4*)(h + (i * 64 + lane) * 4);
        float4 wv = *(const float4*)(w + (i * 64 + lane) * 4);
        s += hv.x * wv.x + hv.y * wv.y + hv.z * wv.z + hv.w * wv.w;
    }
    #pragma unroll
    for (int off = 1; off < 64; off <<= 1) s += __shfl_xor(s, off, 64);
    if (lane == 0) out[gid] = keep[k] ? (s + b) : 0.0f;
}

// ---------------- launch ----------------
extern "C" void kernel_launch(void* const* d_in, const int* in_sizes, int n_in,
                              void* d_out, int out_size, void* d_ws, size_t ws_size,
                              hipStream_t stream) {
    const float* x    = (const float*)d_in[0];
    const float* Wf   = (const float*)d_in[2];
    const float* bf   = (const float*)d_in[3];
    const float* W1   = (const float*)d_in[4];
    const float* b1   = (const float*)d_in[5];
    const float* Wc   = (const float*)d_in[6];
    const float* bc   = (const float*)d_in[7];
    const float* Wb   = (const float*)d_in[8];
    const float* bb   = (const float*)d_in[9];
    const float* fc1w = (const float*)d_in[10];
    const float* fc1b = (const float*)d_in[11];
    const float* fc2w = (const float*)d_in[12];
    const float* fc2b = (const float*)d_in[13];
    const float* clsw = (const float*)d_in[14];
    const float* clsb = (const float*)d_in[15];
    const float* boxw = (const float*)d_in[16];
    const float* boxb = (const float*)d_in[17];
    const void*  wp   = d_in[18];
    const void*  hp   = d_in[19];

    char* ws = (char*)d_ws;
    float* feat  = (float*)(ws + OFF_FEAT);
    float* hmap  = (float*)(ws + OFF_HMAP);
    float* score = (float*)(ws + OFF_SCORE);
    float* preb  = (float*)(ws + OFF_PREB);
    float* ts    = (float*)(ws + OFF_TS);
    int*   ti    = (int*)(ws + OFF_TI);
    float* boxes = (float*)(ws + OFF_BOX);
    int*   valid = (int*)(ws + OFF_VAL);
    int*   keep  = (int*)(ws + OFF_KEEP);
    int*   ixb   = (int*)(ws + OFF_IX);
    int*   iyb   = (int*)(ws + OFF_IY);
    float* flat  = (float*)(ws + OFF_FLAT);
    float* h1    = (float*)(ws + OFF_H1);
    float* h2    = (float*)(ws + OFF_H2);
    float* w1t   = (float*)(ws + OFF_H2);   // transient, dead before h2 written
    float* out   = (float*)d_out;

    // split-K configuration, guarded by ws_size
    size_t slot = (size_t)NTOP * FCN * 4;   // 4.9 MB
    size_t avail = ws_size > OFF_PART ? (ws_size - OFF_PART) / slot : 0;
    float *part1, *part2;
    int ns1, ns2;
    if (avail >= 2) {
        part1 = part2 = (float*)(ws + OFF_PART);
        ns1 = (int)(avail < 7 ? avail : 7);
        ns2 = (int)(avail < 4 ? avail : 4);
    } else {
        part1 = (float*)(ws + OFF_H2);   ns1 = 1;
        part2 = (float*)(ws + OFF_FLAT); ns2 = 3;
    }
    int st1 = (196 + ns1 - 1) / ns1;  int kch1 = st1 * 64;  int ns1e = (196 + st1 - 1) / st1;
    int st2 = (64 + ns2 - 1) / ns2;   int kch2 = st2 * 64;  int ns2e = (64 + st2 - 1) / st2;

    patch_conv<<<dim3(10, 64), 256, 0, stream>>>(x, Wf, bf, feat);
    transpose_w1<<<(2304 * 256 + 255) / 256, 256, 0, stream>>>(W1, w1t);
    conv3x3_relu<<<500, 256, 0, stream>>>(feat, w1t, b1, hmap);
    head_k<<<625, 256, 0, stream>>>(hmap, Wc, bc, Wb, bb, score, preb);
    topk_k<<<1, 1024, 0, stream>>>(score, ts, ti);
    boxes_k<<<1, 320, 0, stream>>>(preb, ti, ts, wp, hp, boxes, valid, ixb, iyb);
    nms_k<<<1, 64, 0, stream>>>(boxes, valid, keep);
    roipool_k<<<(NTOP * DFLAT + 255) / 256, 256, 0, stream>>>(feat, ixb, iyb, flat);
    gemm_mfma<<<dim3(32, 5, ns1e), 256, 0, stream>>>(flat, fc1w, part1, NTOP, FCN, DFLAT, kch1);
    reduce_k<<<1200, 256, 0, stream>>>(part1, fc1b, h1, NTOP, FCN, ns1e);
    gemm_mfma<<<dim3(32, 5, ns2e), 256, 0, stream>>>(h1, fc2w, part2, NTOP, FCN, FCN, kch2);
    reduce_k<<<1200, 256, 0, stream>>>(part2, fc2b, h2, NTOP, FCN, ns2e);
    final_k<<<(NTOP * 25 + 3) / 4, 256, 0, stream>>>(h2, clsw, clsb, boxw, boxb, keep, out);
}

// Round 4
// 627.519 us; speedup vs baseline: 3.2049x; 1.2556x over previous
//
#include <hip/hip_runtime.h>
#include <hip/hip_bf16.h>
#include <math.h>

// ---------------- problem constants ----------------
#define NPIX   2500      // 50*50
#define CFEAT  256
#define NTOP   300
#define DFLAT  12544     // 256*7*7
#define FCN    4096
#define FPSTRIDE 3328    // 52 rows * 64 floats per channel (padded feature)

typedef _Float16 f16x8 __attribute__((ext_vector_type(8)));
typedef float    f32x4 __attribute__((ext_vector_type(4)));

// ---------------- workspace offsets (bytes) ----------------
static constexpr size_t OFF_FPAD  = 0;          // 256*3328*4 = 3,407,872 (0x340000)
static constexpr size_t OFF_HMAP  = 0x340000;   // 2.56 MB (pix, co)
static constexpr size_t OFF_SCORE = 0x5C0000;
static constexpr size_t OFF_PREB  = 0x5D0000;
static constexpr size_t OFF_TS    = 0x5E0000;
static constexpr size_t OFF_TI    = 0x5E1000;
static constexpr size_t OFF_BOX   = 0x5E2000;
static constexpr size_t OFF_VAL   = 0x5E4000;
static constexpr size_t OFF_KEEP  = 0x5E5000;
static constexpr size_t OFF_IX    = 0x5E6000;
static constexpr size_t OFF_IY    = 0x5EB000;
static constexpr size_t OFF_FLAT  = 0x600000;   // 15.05 MB: conv partials (10.24 MB), then roipool flat, then fc2 partial fallback
static constexpr size_t OFF_H1    = 0x1500000;  // 4.9 MB
static constexpr size_t OFF_H2    = 0x1A00000;  // 4.9 MB (also W1t transient, fc1 partial fallback)
static constexpr size_t OFF_PART  = 0x1F00000;  // split-K partials (up to 7 slots)

__device__ inline float decode_dim(const void* p) {
    int iv = *(const int*)p;
    if (iv > 0 && iv < (1 << 20)) return (float)iv;
    return __int_as_float(iv);
}

// ---------------- 0. zero the padded feature buffer ----------------
__global__ void zero_fpad(float* __restrict__ fpad) {
    int i = blockIdx.x * 256 + threadIdx.x;   // float4 index, 256*3328/4 = 212992
    if (i < 212992) *(float4*)(fpad + (size_t)i * 4) = make_float4(0.f, 0.f, 0.f, 0.f);
}

// ---------------- 1. patchify conv: 16x16 stride16 VALID -> padded feat -----
// 4 output channels per block; x loads (float4) reused across the 4 channels.
__global__ void __launch_bounds__(256)
patch_conv(const float* __restrict__ x, const float* __restrict__ Wf,
           const float* __restrict__ bf, float* __restrict__ fpad) {
    __shared__ float w[3072];          // 4 co x 768
    int co0 = blockIdx.y * 4;
    for (int t = threadIdx.x; t < 3072; t += 256) w[t] = Wf[co0 * 768 + t];
    __syncthreads();
    int p = blockIdx.x * 256 + threadIdx.x;
    if (p >= NPIX) return;
    int py = p / 50, px = p % 50;
    float acc[4];
    #pragma unroll
    for (int c = 0; c < 4; ++c) acc[c] = bf[co0 + c];
    for (int ci = 0; ci < 3; ++ci) {
        const float* xp = x + ci * 640000 + (py * 16) * 800 + px * 16;
        #pragma unroll
        for (int ky = 0; ky < 16; ++ky) {
            const float* row = xp + ky * 800;
            #pragma unroll
            for (int kq = 0; kq < 4; ++kq) {
                float4 xv = *reinterpret_cast<const float4*>(row + kq * 4);
                int kb = ci * 256 + ky * 16 + kq * 4;
                #pragma unroll
                for (int c = 0; c < 4; ++c) {
                    const float* wc = w + c * 768 + kb;
                    acc[c] += xv.x * wc[0] + xv.y * wc[1] + xv.z * wc[2] + xv.w * wc[3];
                }
            }
        }
    }
    size_t o = (size_t)(py + 1) * 64 + (px + 1);
    #pragma unroll
    for (int c = 0; c < 4; ++c) fpad[(size_t)(co0 + c) * FPSTRIDE + o] = acc[c];
}

// ---------------- 1b. transpose W1 -> (ci*9+j, co) ----------------
__global__ void transpose_w1(const float* __restrict__ W1, float* __restrict__ W1t) {
    int idx = blockIdx.x * 256 + threadIdx.x;
    if (idx >= 2304 * 256) return;
    int r = idx >> 8, co = idx & 255;
    W1t[idx] = W1[co * 2304 + r];
}

// ---------------- 2. 3x3 SAME conv partials (lanes=co, 8-pixel batch, ci split 4) --
// grid (7, 50, 4): xgroup, row, ci-chunk. Output: cpart[z][pix][co].
__global__ void __launch_bounds__(256)
conv3x3_part(const float* __restrict__ fpad, const float* __restrict__ W1t,
             float* __restrict__ cpart) {
    int co = threadIdx.x;
    int xb = blockIdx.x * 8;          // 0,8,...,48
    int y  = blockIdx.y;              // 0..49
    int z  = blockIdx.z;              // 0..3
    float acc[8];
    #pragma unroll
    for (int p = 0; p < 8; ++p) acc[p] = 0.0f;
    const float* fp = fpad + (size_t)(z * 64) * FPSTRIDE + (size_t)y * 64 + xb;
    const float* wp = W1t + (size_t)(z * 64) * 9 * 256 + co;
    #pragma unroll 2
    for (int ci = 0; ci < 64; ++ci) {
        float v[3][12];
        #pragma unroll
        for (int dy = 0; dy < 3; ++dy) {
            #pragma unroll
            for (int q = 0; q < 3; ++q) {
                float4 r4 = *(const float4*)(fp + dy * 64 + q * 4);
                v[dy][q * 4 + 0] = r4.x; v[dy][q * 4 + 1] = r4.y;
                v[dy][q * 4 + 2] = r4.z; v[dy][q * 4 + 3] = r4.w;
            }
        }
        float wv[9];
        #pragma unroll
        for (int k = 0; k < 9; ++k) wv[k] = wp[k * 256];
        #pragma unroll
        for (int dy = 0; dy < 3; ++dy)
            #pragma unroll
            for (int dx = 0; dx < 3; ++dx) {
                float wvv = wv[dy * 3 + dx];
                #pragma unroll
                for (int p = 0; p < 8; ++p)
                    acc[p] += v[dy][p + dx] * wvv;
            }
        fp += FPSTRIDE;
        wp += 9 * 256;
    }
    size_t base = (size_t)z * (NPIX * 256) + (size_t)(y * 50 + xb) * 256 + co;
    #pragma unroll
    for (int p = 0; p < 8; ++p)
        if (xb + p < 50) cpart[base + (size_t)p * 256] = acc[p];
}

// ---------------- 2b. reduce conv partials + bias + relu -> hmap (pix, co) --
__global__ void reduce_conv(const float* __restrict__ cpart, const float* __restrict__ b1,
                            float* __restrict__ hmap) {
    int i = blockIdx.x * 256 + threadIdx.x;   // float4 index over 2500*256/4
    if (i >= NPIX * 256 / 4) return;
    float4 s = *(const float4*)(cpart + (size_t)i * 4);
    #pragma unroll
    for (int z = 1; z < 4; ++z) {
        float4 v = *(const float4*)(cpart + (size_t)z * (NPIX * 256) + (size_t)i * 4);
        s.x += v.x; s.y += v.y; s.z += v.z; s.w += v.w;
    }
    float4 b = *(const float4*)(b1 + (i & 63) * 4);
    s.x = fmaxf(s.x + b.x, 0.f); s.y = fmaxf(s.y + b.y, 0.f);
    s.z = fmaxf(s.z + b.z, 0.f); s.w = fmaxf(s.w + b.w, 0.f);
    *(float4*)(hmap + (size_t)i * 4) = s;
}

// ---------------- 3. heads: wave per pixel, float4 dot + shuffle reduce ----
__global__ void head_k(const float* __restrict__ hmap, const float* __restrict__ Wc,
                       const float* __restrict__ bc, const float* __restrict__ Wb,
                       const float* __restrict__ bb, float* __restrict__ score,
                       float* __restrict__ preb) {
    int lane = threadIdx.x & 63;
    int p = blockIdx.x * 4 + (threadIdx.x >> 6);
    if (p >= NPIX) return;
    float4 h  = *(const float4*)(hmap + (size_t)p * 256 + lane * 4);
    float4 c0 = *(const float4*)(Wc + lane * 4);
    float4 c1 = *(const float4*)(Wc + 256 + lane * 4);
    float4 w0 = *(const float4*)(Wb + lane * 4);
    float4 w1 = *(const float4*)(Wb + 256 + lane * 4);
    float4 w2 = *(const float4*)(Wb + 512 + lane * 4);
    float4 w3 = *(const float4*)(Wb + 768 + lane * 4);
    float s[6];
    s[0] = h.x*c0.x + h.y*c0.y + h.z*c0.z + h.w*c0.w;
    s[1] = h.x*c1.x + h.y*c1.y + h.z*c1.z + h.w*c1.w;
    s[2] = h.x*w0.x + h.y*w0.y + h.z*w0.z + h.w*w0.w;
    s[3] = h.x*w1.x + h.y*w1.y + h.z*w1.z + h.w*w1.w;
    s[4] = h.x*w2.x + h.y*w2.y + h.z*w2.z + h.w*w2.w;
    s[5] = h.x*w3.x + h.y*w3.y + h.z*w3.z + h.w*w3.w;
    #pragma unroll
    for (int o = 1; o < 64; o <<= 1) {
        #pragma unroll
        for (int q = 0; q < 6; ++q) s[q] += __shfl_xor(s[q], o, 64);
    }
    if (lane == 0) {
        float s0 = s[0] + bc[0], s1 = s[1] + bc[1];
        float m = fmaxf(s0, s1);
        float e0 = expf(s0 - m), e1 = expf(s1 - m);
        score[p] = e1 / (e0 + e1);
        preb[p * 4 + 0] = s[2] + bb[0];
        preb[p * 4 + 1] = s[3] + bb[1];
        preb[p * 4 + 2] = s[4] + bb[2];
        preb[p * 4 + 3] = s[5] + bb[3];
    }
}

// ---------------- 4. top-k via full bitonic sort (desc value, asc index) ---
__global__ void __launch_bounds__(1024) topk_k(const float* __restrict__ score,
                                               float* __restrict__ ts, int* __restrict__ ti) {
    __shared__ float sv[4096];
    __shared__ int   si[4096];
    int tid = threadIdx.x;
    for (int t = tid; t < 4096; t += 1024) {
        sv[t] = (t < NPIX) ? score[t] : -INFINITY;
        si[t] = t;
    }
    __syncthreads();
    for (int k = 2; k <= 4096; k <<= 1) {
        for (int j = k >> 1; j > 0; j >>= 1) {
            for (int t = tid; t < 4096; t += 1024) {
                int l = t ^ j;
                if (l > t) {
                    float vt = sv[t], vl = sv[l];
                    int it = si[t], il = si[l];
                    bool l_before_t = (vl > vt) || (vl == vt && il < it);
                    bool dir = ((t & k) == 0);
                    if (dir == l_before_t) {
                        sv[t] = vl; sv[l] = vt;
                        si[t] = il; si[l] = it;
                    }
                }
            }
            __syncthreads();
        }
    }
    for (int t = tid; t < NTOP; t += 1024) { ts[t] = sv[t]; ti[t] = si[t]; }
}

// ---------------- 5. box decode + valid + roi sample coords ----------------
__global__ void boxes_k(const float* __restrict__ preb, const int* __restrict__ ti,
                        const float* __restrict__ ts, const void* wp, const void* hp,
                        float* __restrict__ boxes, int* __restrict__ valid,
                        int* __restrict__ ixb, int* __restrict__ iyb) {
    int j = threadIdx.x;
    if (j >= NTOP) return;
    float wf = decode_dim(wp), hf = decode_dim(hp);
    int id = ti[j];
    float p0 = preb[id * 4 + 0], p1 = preb[id * 4 + 1];
    float p2 = preb[id * 4 + 2], p3 = preb[id * 4 + 3];
    float x1 = fmaxf(p2 - p0 * 0.5f, 0.0f);
    float y1 = fmaxf(p3 - p1 * 0.5f, 0.0f);
    float x2 = fminf(p2 + p0, wf);
    float y2 = fminf(p3 + p1, hf);
    boxes[j * 4 + 0] = x1; boxes[j * 4 + 1] = y1;
    boxes[j * 4 + 2] = x2; boxes[j * 4 + 3] = y2;
    valid[j] = (ts[j] > 0.5f) ? 1 : 0;
    float bx1 = x1 * 0.0625f, by1 = y1 * 0.0625f;
    float bx2 = x2 * 0.0625f, by2 = y2 * 0.0625f;
    #pragma unroll
    for (int m = 0; m < 14; ++m) {
        int i = m >> 1, s = m & 1;
        float frac = ((float)i + (s ? 0.75f : 0.25f)) / 7.0f;
        float xs = bx1 + frac * (bx2 - bx1);
        float ys = by1 + frac * (by2 - by1);
        float fx = floorf(xs); fx = fminf(fmaxf(fx, 0.0f), 49.0f);
        float fy = floorf(ys); fy = fminf(fmaxf(fy, 0.0f), 49.0f);
        ixb[j * 14 + m] = (int)fx;
        iyb[j * 14 + m] = (int)fy;
    }
}

// ---------------- 6. greedy NMS — single wave ----------------
__global__ void __launch_bounds__(64) nms_k(const float* __restrict__ boxes,
                                            const int* __restrict__ valid,
                                            int* __restrict__ keep) {
    __shared__ float X1[NTOP], Y1[NTOP], X2[NTOP], Y2[NTOP], AR[NTOP];
    __shared__ int kp[NTOP];
    int t = threadIdx.x;   // 0..63
    for (int j = t; j < NTOP; j += 64) {
        float x1 = boxes[j * 4 + 0], y1 = boxes[j * 4 + 1];
        float x2 = boxes[j * 4 + 2], y2 = boxes[j * 4 + 3];
        X1[j] = x1; Y1[j] = y1; X2[j] = x2; Y2[j] = y2;
        AR[j] = fmaxf(x2 - x1, 0.0f) * fmaxf(y2 - y1, 0.0f);
        kp[j] = valid[j];
    }
    __syncthreads();
    for (int i = 0; i < NTOP - 1; ++i) {
        if (kp[i]) {
            float xi1 = X1[i], yi1 = Y1[i], xi2 = X2[i], yi2 = Y2[i], ai = AR[i];
            for (int j = t; j < NTOP; j += 64) {
                if (j > i && kp[j]) {
                    float ix1 = fmaxf(xi1, X1[j]);
                    float iy1 = fmaxf(yi1, Y1[j]);
                    float ix2 = fminf(xi2, X2[j]);
                    float iy2 = fminf(yi2, Y2[j]);
                    float inter = fmaxf(ix2 - ix1, 0.0f) * fmaxf(iy2 - iy1, 0.0f);
                    float iou = inter / fmaxf(ai + AR[j] - inter, 1e-6f);
                    if (iou > 0.7f) kp[j] = 0;
                }
            }
        }
        __syncthreads();
    }
    for (int j = t; j < NTOP; j += 64) keep[j] = kp[j];
}

// ---------------- 7. ROI max pool -> flat (300, 256*7*7) ----------------
__global__ void roipool_k(const float* __restrict__ fpad, const int* __restrict__ ixb,
                          const int* __restrict__ iyb, float* __restrict__ flat) {
    int id = blockIdx.x * 256 + threadIdx.x;
    if (id >= NTOP * DFLAT) return;
    int k = id / DFLAT, r = id % DFLAT;
    int c = r / 49, ij = r % 49, i = ij / 7, jx = ij % 7;
    const int* ix = ixb + k * 14;
    const int* iy = iyb + k * 14;
    int y0 = iy[2 * i] + 1, y1 = iy[2 * i + 1] + 1;
    int x0 = ix[2 * jx] + 1, x1 = ix[2 * jx + 1] + 1;
    const float* f = fpad + (size_t)c * FPSTRIDE;
    float v = fmaxf(fmaxf(f[y0 * 64 + x0], f[y0 * 64 + x1]),
                    fmaxf(f[y1 * 64 + x0], f[y1 * 64 + x1]));
    flat[id] = v;
}

// ---------------- 8. f16 MFMA GEMM with split-K ----------------
__global__ void __launch_bounds__(256)
gemm_mfma(const float* __restrict__ A, const float* __restrict__ B,
          float* __restrict__ part, int M, int N, int K, int kchunk) {
    __shared__ char Asb[64 * 128];    // 64 rows x 64 f16
    __shared__ char Bsb[128 * 128];   // 128 rows x 64 f16
    int tid = threadIdx.x;
    int n0 = blockIdx.x * 128;
    int m0 = blockIdx.y * 64;
    int z  = blockIdx.z;
    int ks = z * kchunk;
    int klen = K - ks; if (klen > kchunk) klen = kchunk;
    int lane = tid & 63;
    int w = tid >> 6;

    f32x4 acc[4][2];
    #pragma unroll
    for (int tm = 0; tm < 4; ++tm)
        #pragma unroll
        for (int tn = 0; tn < 2; ++tn)
            acc[tm][tn] = f32x4{0.f, 0.f, 0.f, 0.f};

    for (int k0 = 0; k0 < klen; k0 += 64) {
        #pragma unroll
        for (int i = 0; i < 4; ++i) {          // A: 1024 float4
            int idx = tid + i * 256;
            int r = idx >> 4, fq = idx & 15;
            int gm = m0 + r;
            float4 v = make_float4(0.f, 0.f, 0.f, 0.f);
            if (gm < M) v = *(const float4*)(A + (size_t)gm * K + ks + k0 + fq * 4);
            union { _Float16 h[4]; uint2 u; } cv;
            cv.h[0] = (_Float16)v.x; cv.h[1] = (_Float16)v.y;
            cv.h[2] = (_Float16)v.z; cv.h[3] = (_Float16)v.w;
            *(uint2*)(Asb + r * 128 + ((fq * 8) ^ ((r & 7) << 4))) = cv.u;
        }
        #pragma unroll
        for (int i = 0; i < 8; ++i) {          // B: 2048 float4
            int idx = tid + i * 256;
            int r = idx >> 4, fq = idx & 15;
            float4 v = *(const float4*)(B + (size_t)(n0 + r) * K + ks + k0 + fq * 4);
            union { _Float16 h[4]; uint2 u; } cv;
            cv.h[0] = (_Float16)v.x; cv.h[1] = (_Float16)v.y;
            cv.h[2] = (_Float16)v.z; cv.h[3] = (_Float16)v.w;
            *(uint2*)(Bsb + r * 128 + ((fq * 8) ^ ((r & 7) << 4))) = cv.u;
        }
        __syncthreads();
        #pragma unroll
        for (int kk = 0; kk < 2; ++kk) {
            int kbyte = kk * 64 + (lane >> 4) * 16;
            f16x8 a[4], bfr[2];
            #pragma unroll
            for (int tm = 0; tm < 4; ++tm) {
                int r = tm * 16 + (lane & 15);
                a[tm] = *(const f16x8*)(Asb + r * 128 + (kbyte ^ ((r & 7) << 4)));
            }
            #pragma unroll
            for (int tn = 0; tn < 2; ++tn) {
                int r = w * 32 + tn * 16 + (lane & 15);
                bfr[tn] = *(const f16x8*)(Bsb + r * 128 + (kbyte ^ ((r & 7) << 4)));
            }
            #pragma unroll
            for (int tm = 0; tm < 4; ++tm)
                #pragma unroll
                for (int tn = 0; tn < 2; ++tn)
                    acc[tm][tn] = __builtin_amdgcn_mfma_f32_16x16x32_f16(a[tm], bfr[tn], acc[tm][tn], 0, 0, 0);
        }
        __syncthreads();
    }
    float* pout = part + (size_t)z * M * N;
    #pragma unroll
    for (int tm = 0; tm < 4; ++tm) {
        int mbase = m0 + tm * 16 + (lane >> 4) * 4;
        #pragma unroll
        for (int j = 0; j < 4; ++j) {
            int m = mbase + j;
            if (m < M) {
                #pragma unroll
                for (int tn = 0; tn < 2; ++tn) {
                    int n = n0 + w * 32 + tn * 16 + (lane & 15);
                    pout[(size_t)m * N + n] = acc[tm][tn][j];
                }
            }
        }
    }
}

// ---------------- 8b. reduce partials + bias + relu ----------------
__global__ void reduce_k(const float* __restrict__ part, const float* __restrict__ bias,
                         float* __restrict__ outp, int M, int N, int ns) {
    size_t i = (size_t)blockIdx.x * 256 + threadIdx.x;    // float4 index
    size_t mn4 = (size_t)M * N / 4;
    if (i >= mn4) return;
    float4 s = *(const float4*)(part + i * 4);
    for (int zz = 1; zz < ns; ++zz) {
        float4 v = *(const float4*)(part + (size_t)zz * M * N + i * 4);
        s.x += v.x; s.y += v.y; s.z += v.z; s.w += v.w;
    }
    int n = (int)((i * 4) % N);
    float4 b = *(const float4*)(bias + n);
    s.x = fmaxf(s.x + b.x, 0.f); s.y = fmaxf(s.y + b.y, 0.f);
    s.z = fmaxf(s.z + b.z, 0.f); s.w = fmaxf(s.w + b.w, 0.f);
    *(float4*)(outp + i * 4) = s;
}

// ---------------- 9. final heads: wave per output + keep mask ----------------
__global__ void __launch_bounds__(256)
final_k(const float* __restrict__ h2, const float* __restrict__ clsw,
        const float* __restrict__ clsb, const float* __restrict__ boxw,
        const float* __restrict__ boxb, const int* __restrict__ keep,
        float* __restrict__ out) {
    int gid = blockIdx.x * 4 + (threadIdx.x >> 6);
    if (gid >= NTOP * 25) return;
    int lane = threadIdx.x & 63;
    int k = gid / 25, o = gid % 25;
    const float* w;
    float b;
    if (o < 21) { w = clsw + (size_t)o * 4096; b = clsb[o]; }
    else        { w = boxw + (size_t)(o - 21) * 4096; b = boxb[o - 21]; }
    const float* h = h2 + (size_t)k * 4096;
    float s = 0.0f;
    #pragma unroll
    for (int i = 0; i < 16; ++i) {
        float4 hv = *(const float4*)(h + (i * 64 + lane) * 4);
        float4 wv = *(const float4*)(w + (i * 64 + lane) * 4);
        s += hv.x * wv.x + hv.y * wv.y + hv.z * wv.z + hv.w * wv.w;
    }
    #pragma unroll
    for (int off = 1; off < 64; off <<= 1) s += __shfl_xor(s, off, 64);
    if (lane == 0) out[gid] = keep[k] ? (s + b) : 0.0f;
}

// ---------------- launch ----------------
extern "C" void kernel_launch(void* const* d_in, const int* in_sizes, int n_in,
                              void* d_out, int out_size, void* d_ws, size_t ws_size,
                              hipStream_t stream) {
    const float* x    = (const float*)d_in[0];
    const float* Wf   = (const float*)d_in[2];
    const float* bf   = (const float*)d_in[3];
    const float* W1   = (const float*)d_in[4];
    const float* b1   = (const float*)d_in[5];
    const float* Wc   = (const float*)d_in[6];
    const float* bc   = (const float*)d_in[7];
    const float* Wb   = (const float*)d_in[8];
    const float* bb   = (const float*)d_in[9];
    const float* fc1w = (const float*)d_in[10];
    const float* fc1b = (const float*)d_in[11];
    const float* fc2w = (const float*)d_in[12];
    const float* fc2b = (const float*)d_in[13];
    const float* clsw = (const float*)d_in[14];
    const float* clsb = (const float*)d_in[15];
    const float* boxw = (const float*)d_in[16];
    const float* boxb = (const float*)d_in[17];
    const void*  wp   = d_in[18];
    const void*  hp   = d_in[19];

    char* ws = (char*)d_ws;
    float* fpad  = (float*)(ws + OFF_FPAD);
    float* hmap  = (float*)(ws + OFF_HMAP);
    float* score = (float*)(ws + OFF_SCORE);
    float* preb  = (float*)(ws + OFF_PREB);
    float* ts    = (float*)(ws + OFF_TS);
    int*   ti    = (int*)(ws + OFF_TI);
    float* boxes = (float*)(ws + OFF_BOX);
    int*   valid = (int*)(ws + OFF_VAL);
    int*   keep  = (int*)(ws + OFF_KEEP);
    int*   ixb   = (int*)(ws + OFF_IX);
    int*   iyb   = (int*)(ws + OFF_IY);
    float* flat  = (float*)(ws + OFF_FLAT);
    float* cpart = (float*)(ws + OFF_FLAT);   // conv partials, dead before roipool
    float* h1    = (float*)(ws + OFF_H1);
    float* h2    = (float*)(ws + OFF_H2);
    float* w1t   = (float*)(ws + OFF_H2);     // transient, dead before h2 written
    float* out   = (float*)d_out;

    // split-K configuration, guarded by ws_size
    size_t slot = (size_t)NTOP * FCN * 4;   // 4.9 MB
    size_t avail = ws_size > OFF_PART ? (ws_size - OFF_PART) / slot : 0;
    float *part1, *part2;
    int ns1, ns2;
    if (avail >= 2) {
        part1 = part2 = (float*)(ws + OFF_PART);
        ns1 = (int)(avail < 7 ? avail : 7);
        ns2 = (int)(avail < 4 ? avail : 4);
    } else {
        part1 = (float*)(ws + OFF_H2);   ns1 = 1;
        part2 = (float*)(ws + OFF_FLAT); ns2 = 3;
    }
    int st1 = (196 + ns1 - 1) / ns1;  int kch1 = st1 * 64;  int ns1e = (196 + st1 - 1) / st1;
    int st2 = (64 + ns2 - 1) / ns2;   int kch2 = st2 * 64;  int ns2e = (64 + st2 - 1) / st2;

    zero_fpad<<<832, 256, 0, stream>>>(fpad);
    patch_conv<<<dim3(10, 64), 256, 0, stream>>>(x, Wf, bf, fpad);
    transpose_w1<<<(2304 * 256 + 255) / 256, 256, 0, stream>>>(W1, w1t);
    conv3x3_part<<<dim3(7, 50, 4), 256, 0, stream>>>(fpad, w1t, cpart);
    reduce_conv<<<(NPIX * 256 / 4 + 255) / 256, 256, 0, stream>>>(cpart, b1, hmap);
    head_k<<<625, 256, 0, stream>>>(hmap, Wc, bc, Wb, bb, score, preb);
    topk_k<<<1, 1024, 0, stream>>>(score, ts, ti);
    boxes_k<<<1, 320, 0, stream>>>(preb, ti, ts, wp, hp, boxes, valid, ixb, iyb);
    nms_k<<<1, 64, 0, stream>>>(boxes, valid, keep);
    roipool_k<<<(NTOP * DFLAT + 255) / 256, 256, 0, stream>>>(fpad, ixb, iyb, flat);
    gemm_mfma<<<dim3(32, 5, ns1e), 256, 0, stream>>>(flat, fc1w, part1, NTOP, FCN, DFLAT, kch1);
    reduce_k<<<1200, 256, 0, stream>>>(part1, fc1b, h1, NTOP, FCN, ns1e);
    gemm_mfma<<<dim3(32, 5, ns2e), 256, 0, stream>>>(h1, fc2w, part2, NTOP, FCN, FCN, kch2);
    reduce_k<<<1200, 256, 0, stream>>>(part2, fc2b, h2, NTOP, FCN, ns2e);
    final_k<<<(NTOP * 25 + 3) / 4, 256, 0, stream>>>(h2, clsw, clsb, boxw, boxb, keep, out);
}

// Round 5
// 486.910 us; speedup vs baseline: 4.1304x; 1.2888x over previous
//
#include <hip/hip_runtime.h>
#include <hip/hip_bf16.h>
#include <math.h>

// ---------------- problem constants ----------------
#define NPIX   2500      // 50*50
#define CFEAT  256
#define NTOP   300
#define DFLAT  12544     // 256*7*7
#define FCN    4096
#define FPSTRIDE 3328    // 52 rows * 64 floats per channel (padded feature)

typedef _Float16 f16x8 __attribute__((ext_vector_type(8)));
typedef float    f32x4 __attribute__((ext_vector_type(4)));

// ---------------- workspace offsets (bytes) ----------------
static constexpr size_t OFF_FPAD  = 0;          // 256*3328*4 = 3,407,872 (0x340000)
static constexpr size_t OFF_HMAP  = 0x340000;   // 2.56 MB (pix, co)
static constexpr size_t OFF_SCORE = 0x5C0000;
static constexpr size_t OFF_PREB  = 0x5D0000;
static constexpr size_t OFF_TS    = 0x5E0000;
static constexpr size_t OFF_TI    = 0x5E1000;
static constexpr size_t OFF_BOX   = 0x5E2000;
static constexpr size_t OFF_VAL   = 0x5E4000;
static constexpr size_t OFF_KEEP  = 0x5E5000;
static constexpr size_t OFF_IX    = 0x5E6000;
static constexpr size_t OFF_IY    = 0x5EB000;
static constexpr size_t OFF_FLAT  = 0x600000;   // 15.05 MB: conv partials (10.24 MB), then roipool flat, then fc2 partial fallback
static constexpr size_t OFF_H1    = 0x1500000;  // 4.9 MB
static constexpr size_t OFF_H2    = 0x1A00000;  // 4.9 MB (also W1t transient, fc1 partial fallback)
static constexpr size_t OFF_PART  = 0x1F00000;  // split-K partials (up to 7 slots)

__device__ inline float decode_dim(const void* p) {
    int iv = *(const int*)p;
    if (iv > 0 && iv < (1 << 20)) return (float)iv;
    return __int_as_float(iv);
}

// ---------------- 0. zero the padded feature buffer ----------------
__global__ void zero_fpad(float* __restrict__ fpad) {
    int i = blockIdx.x * 256 + threadIdx.x;   // float4 index, 256*3328/4 = 212992
    if (i < 212992) *(float4*)(fpad + (size_t)i * 4) = make_float4(0.f, 0.f, 0.f, 0.f);
}

// ---------------- 1. patchify conv: 16x16 stride16 VALID -> padded feat -----
__global__ void __launch_bounds__(256)
patch_conv(const float* __restrict__ x, const float* __restrict__ Wf,
           const float* __restrict__ bf, float* __restrict__ fpad) {
    __shared__ float w[3072];          // 4 co x 768
    int co0 = blockIdx.y * 4;
    for (int t = threadIdx.x; t < 3072; t += 256) w[t] = Wf[co0 * 768 + t];
    __syncthreads();
    int p = blockIdx.x * 256 + threadIdx.x;
    if (p >= NPIX) return;
    int py = p / 50, px = p % 50;
    float acc[4];
    #pragma unroll
    for (int c = 0; c < 4; ++c) acc[c] = bf[co0 + c];
    for (int ci = 0; ci < 3; ++ci) {
        const float* xp = x + ci * 640000 + (py * 16) * 800 + px * 16;
        #pragma unroll
        for (int ky = 0; ky < 16; ++ky) {
            const float* row = xp + ky * 800;
            #pragma unroll
            for (int kq = 0; kq < 4; ++kq) {
                float4 xv = *reinterpret_cast<const float4*>(row + kq * 4);
                int kb = ci * 256 + ky * 16 + kq * 4;
                #pragma unroll
                for (int c = 0; c < 4; ++c) {
                    const float* wc = w + c * 768 + kb;
                    acc[c] += xv.x * wc[0] + xv.y * wc[1] + xv.z * wc[2] + xv.w * wc[3];
                }
            }
        }
    }
    size_t o = (size_t)(py + 1) * 64 + (px + 1);
    #pragma unroll
    for (int c = 0; c < 4; ++c) fpad[(size_t)(co0 + c) * FPSTRIDE + o] = acc[c];
}

// ---------------- 1b. transpose W1 -> (ci*9+j, co) ----------------
__global__ void transpose_w1(const float* __restrict__ W1, float* __restrict__ W1t) {
    int idx = blockIdx.x * 256 + threadIdx.x;
    if (idx >= 2304 * 256) return;
    int r = idx >> 8, co = idx & 255;
    W1t[idx] = W1[co * 2304 + r];
}

// ---------------- 2. 3x3 SAME conv partials (lanes=co, 8-pixel batch, ci split 4) --
__global__ void __launch_bounds__(256)
conv3x3_part(const float* __restrict__ fpad, const float* __restrict__ W1t,
             float* __restrict__ cpart) {
    int co = threadIdx.x;
    int xb = blockIdx.x * 8;          // 0,8,...,48
    int y  = blockIdx.y;              // 0..49
    int z  = blockIdx.z;              // 0..3
    float acc[8];
    #pragma unroll
    for (int p = 0; p < 8; ++p) acc[p] = 0.0f;
    const float* fp = fpad + (size_t)(z * 64) * FPSTRIDE + (size_t)y * 64 + xb;
    const float* wp = W1t + (size_t)(z * 64) * 9 * 256 + co;
    #pragma unroll 2
    for (int ci = 0; ci < 64; ++ci) {
        float v[3][12];
        #pragma unroll
        for (int dy = 0; dy < 3; ++dy) {
            #pragma unroll
            for (int q = 0; q < 3; ++q) {
                float4 r4 = *(const float4*)(fp + dy * 64 + q * 4);
                v[dy][q * 4 + 0] = r4.x; v[dy][q * 4 + 1] = r4.y;
                v[dy][q * 4 + 2] = r4.z; v[dy][q * 4 + 3] = r4.w;
            }
        }
        float wv[9];
        #pragma unroll
        for (int k = 0; k < 9; ++k) wv[k] = wp[k * 256];
        #pragma unroll
        for (int dy = 0; dy < 3; ++dy)
            #pragma unroll
            for (int dx = 0; dx < 3; ++dx) {
                float wvv = wv[dy * 3 + dx];
                #pragma unroll
                for (int p = 0; p < 8; ++p)
                    acc[p] += v[dy][p + dx] * wvv;
            }
        fp += FPSTRIDE;
        wp += 9 * 256;
    }
    size_t base = (size_t)z * (NPIX * 256) + (size_t)(y * 50 + xb) * 256 + co;
    #pragma unroll
    for (int p = 0; p < 8; ++p)
        if (xb + p < 50) cpart[base + (size_t)p * 256] = acc[p];
}

// ---------------- 2b. reduce conv partials + bias + relu -> hmap (pix, co) --
__global__ void reduce_conv(const float* __restrict__ cpart, const float* __restrict__ b1,
                            float* __restrict__ hmap) {
    int i = blockIdx.x * 256 + threadIdx.x;   // float4 index over 2500*256/4
    if (i >= NPIX * 256 / 4) return;
    float4 s = *(const float4*)(cpart + (size_t)i * 4);
    #pragma unroll
    for (int z = 1; z < 4; ++z) {
        float4 v = *(const float4*)(cpart + (size_t)z * (NPIX * 256) + (size_t)i * 4);
        s.x += v.x; s.y += v.y; s.z += v.z; s.w += v.w;
    }
    float4 b = *(const float4*)(b1 + (i & 63) * 4);
    s.x = fmaxf(s.x + b.x, 0.f); s.y = fmaxf(s.y + b.y, 0.f);
    s.z = fmaxf(s.z + b.z, 0.f); s.w = fmaxf(s.w + b.w, 0.f);
    *(float4*)(hmap + (size_t)i * 4) = s;
}

// ---------------- 3. heads: wave per pixel, float4 dot + shuffle reduce ----
__global__ void head_k(const float* __restrict__ hmap, const float* __restrict__ Wc,
                       const float* __restrict__ bc, const float* __restrict__ Wb,
                       const float* __restrict__ bb, float* __restrict__ score,
                       float* __restrict__ preb) {
    int lane = threadIdx.x & 63;
    int p = blockIdx.x * 4 + (threadIdx.x >> 6);
    if (p >= NPIX) return;
    float4 h  = *(const float4*)(hmap + (size_t)p * 256 + lane * 4);
    float4 c0 = *(const float4*)(Wc + lane * 4);
    float4 c1 = *(const float4*)(Wc + 256 + lane * 4);
    float4 w0 = *(const float4*)(Wb + lane * 4);
    float4 w1 = *(const float4*)(Wb + 256 + lane * 4);
    float4 w2 = *(const float4*)(Wb + 512 + lane * 4);
    float4 w3 = *(const float4*)(Wb + 768 + lane * 4);
    float s[6];
    s[0] = h.x*c0.x + h.y*c0.y + h.z*c0.z + h.w*c0.w;
    s[1] = h.x*c1.x + h.y*c1.y + h.z*c1.z + h.w*c1.w;
    s[2] = h.x*w0.x + h.y*w0.y + h.z*w0.z + h.w*w0.w;
    s[3] = h.x*w1.x + h.y*w1.y + h.z*w1.z + h.w*w1.w;
    s[4] = h.x*w2.x + h.y*w2.y + h.z*w2.z + h.w*w2.w;
    s[5] = h.x*w3.x + h.y*w3.y + h.z*w3.z + h.w*w3.w;
    #pragma unroll
    for (int o = 1; o < 64; o <<= 1) {
        #pragma unroll
        for (int q = 0; q < 6; ++q) s[q] += __shfl_xor(s[q], o, 64);
    }
    if (lane == 0) {
        float s0 = s[0] + bc[0], s1 = s[1] + bc[1];
        float m = fmaxf(s0, s1);
        float e0 = expf(s0 - m), e1 = expf(s1 - m);
        score[p] = e1 / (e0 + e1);
        preb[p * 4 + 0] = s[2] + bb[0];
        preb[p * 4 + 1] = s[3] + bb[1];
        preb[p * 4 + 2] = s[4] + bb[2];
        preb[p * 4 + 3] = s[5] + bb[3];
    }
}

// ---------------- 4. top-k via full bitonic sort (desc value, asc index) ---
__global__ void __launch_bounds__(1024) topk_k(const float* __restrict__ score,
                                               float* __restrict__ ts, int* __restrict__ ti) {
    __shared__ float sv[4096];
    __shared__ int   si[4096];
    int tid = threadIdx.x;
    for (int t = tid; t < 4096; t += 1024) {
        sv[t] = (t < NPIX) ? score[t] : -INFINITY;
        si[t] = t;
    }
    __syncthreads();
    for (int k = 2; k <= 4096; k <<= 1) {
        for (int j = k >> 1; j > 0; j >>= 1) {
            for (int t = tid; t < 4096; t += 1024) {
                int l = t ^ j;
                if (l > t) {
                    float vt = sv[t], vl = sv[l];
                    int it = si[t], il = si[l];
                    bool l_before_t = (vl > vt) || (vl == vt && il < it);
                    bool dir = ((t & k) == 0);
                    if (dir == l_before_t) {
                        sv[t] = vl; sv[l] = vt;
                        si[t] = il; si[l] = it;
                    }
                }
            }
            __syncthreads();
        }
    }
    for (int t = tid; t < NTOP; t += 1024) { ts[t] = sv[t]; ti[t] = si[t]; }
}

// ---------------- 5+6. fused box decode + ROI coords + bitmask NMS ----------
// 320 threads (5 waves). Phase A: decode boxes/coords. Phase B: wave w, lane l
// computes suppression bitmask for i = 64w+l (5 u64 over j). Phase C: wave 0
// does the 300-step serial scan entirely in registers via shfl broadcasts.
__global__ void __launch_bounds__(320)
nms_fused(const float* __restrict__ preb, const int* __restrict__ ti,
          const float* __restrict__ ts, const void* wp_, const void* hp_,
          int* __restrict__ keep, int* __restrict__ ixb, int* __restrict__ iyb) {
    __shared__ float X1[320], Y1[320], X2[320], Y2[320], AR[320];
    __shared__ unsigned long long MASK[320][5];
    __shared__ unsigned long long KEEPW[5];
    int t = threadIdx.x;
    int lane = t & 63;
    int w = t >> 6;

    // ---- phase A: box decode + roi sample coords ----
    float x1 = 0.f, y1 = 0.f, x2 = 0.f, y2 = 0.f;
    bool v = false;
    if (t < NTOP) {
        float wf = decode_dim(wp_), hf = decode_dim(hp_);
        int id = ti[t];
        float p0 = preb[id * 4 + 0], p1 = preb[id * 4 + 1];
        float p2 = preb[id * 4 + 2], p3 = preb[id * 4 + 3];
        x1 = fmaxf(p2 - p0 * 0.5f, 0.0f);
        y1 = fmaxf(p3 - p1 * 0.5f, 0.0f);
        x2 = fminf(p2 + p0, wf);
        y2 = fminf(p3 + p1, hf);
        v = ts[t] > 0.5f;
        float bx1 = x1 * 0.0625f, by1 = y1 * 0.0625f;
        float bx2 = x2 * 0.0625f, by2 = y2 * 0.0625f;
        #pragma unroll
        for (int m = 0; m < 14; ++m) {
            int i = m >> 1, s = m & 1;
            float frac = ((float)i + (s ? 0.75f : 0.25f)) / 7.0f;
            float xs = bx1 + frac * (bx2 - bx1);
            float ys = by1 + frac * (by2 - by1);
            float fx = floorf(xs); fx = fminf(fmaxf(fx, 0.0f), 49.0f);
            float fy = floorf(ys); fy = fminf(fmaxf(fy, 0.0f), 49.0f);
            ixb[t * 14 + m] = (int)fx;
            iyb[t * 14 + m] = (int)fy;
        }
    }
    X1[t] = x1; Y1[t] = y1; X2[t] = x2; Y2[t] = y2;
    AR[t] = fmaxf(x2 - x1, 0.0f) * fmaxf(y2 - y1, 0.0f);
    unsigned long long vb = __ballot(v);
    if (lane == 0) KEEPW[w] = vb;
    __syncthreads();

    // ---- phase B: per-i suppression masks ----
    float xi1 = X1[t], yi1 = Y1[t], xi2 = X2[t], yi2 = Y2[t], ai = AR[t];
    #pragma unroll
    for (int jw = 0; jw < 5; ++jw) {
        unsigned long long mword = 0ull;
        #pragma unroll 4
        for (int j2 = 0; j2 < 64; ++j2) {
            int j = jw * 64 + j2;
            float ix1 = fmaxf(xi1, X1[j]);
            float iy1 = fmaxf(yi1, Y1[j]);
            float ix2 = fminf(xi2, X2[j]);
            float iy2 = fminf(yi2, Y2[j]);
            float inter = fmaxf(ix2 - ix1, 0.0f) * fmaxf(iy2 - iy1, 0.0f);
            float iou = inter / fmaxf(ai + AR[j] - inter, 1e-6f);
            bool sup = (iou > 0.7f) && (j > t) && (j < NTOP);
            mword |= sup ? (1ull << j2) : 0ull;
        }
        MASK[t][jw] = mword;
    }
    __syncthreads();
    if (w != 0) return;

    // ---- phase C: serial scan, wave 0, all in registers ----
    unsigned long long m[5][5];   // [group][word], statically indexed
    #pragma unroll
    for (int g = 0; g < 5; ++g)
        #pragma unroll
        for (int q = 0; q < 5; ++q)
            m[g][q] = MASK[g * 64 + lane][q];
    unsigned long long kw0 = KEEPW[0], kw1 = KEEPW[1], kw2 = KEEPW[2],
                       kw3 = KEEPW[3], kw4 = KEEPW[4];
    #pragma unroll
    for (int g = 0; g < 5; ++g) {
        for (int i2 = 0; i2 < 64; ++i2) {
            unsigned long long kg = (g == 0) ? kw0 : (g == 1) ? kw1 :
                                    (g == 2) ? kw2 : (g == 3) ? kw3 : kw4;
            bool alive = (kg >> i2) & 1ull;
            unsigned long long b0 = __shfl(m[g][0], i2, 64);
            unsigned long long b1 = __shfl(m[g][1], i2, 64);
            unsigned long long b2 = __shfl(m[g][2], i2, 64);
            unsigned long long b3 = __shfl(m[g][3], i2, 64);
            unsigned long long b4 = __shfl(m[g][4], i2, 64);
            if (alive) {
                kw0 &= ~b0; kw1 &= ~b1; kw2 &= ~b2; kw3 &= ~b3; kw4 &= ~b4;
            }
        }
    }
    #pragma unroll
    for (int g = 0; g < 5; ++g) {
        unsigned long long kg = (g == 0) ? kw0 : (g == 1) ? kw1 :
                                (g == 2) ? kw2 : (g == 3) ? kw3 : kw4;
        int j = g * 64 + lane;
        if (j < NTOP) keep[j] = (int)((kg >> lane) & 1ull);
    }
}

// ---------------- 7. ROI max pool -> flat (300, 256*7*7) ----------------
__global__ void roipool_k(const float* __restrict__ fpad, const int* __restrict__ ixb,
                          const int* __restrict__ iyb, float* __restrict__ flat) {
    int id = blockIdx.x * 256 + threadIdx.x;
    if (id >= NTOP * DFLAT) return;
    int k = id / DFLAT, r = id % DFLAT;
    int c = r / 49, ij = r % 49, i = ij / 7, jx = ij % 7;
    const int* ix = ixb + k * 14;
    const int* iy = iyb + k * 14;
    int y0 = iy[2 * i] + 1, y1 = iy[2 * i + 1] + 1;
    int x0 = ix[2 * jx] + 1, x1 = ix[2 * jx + 1] + 1;
    const float* f = fpad + (size_t)c * FPSTRIDE;
    float v = fmaxf(fmaxf(f[y0 * 64 + x0], f[y0 * 64 + x1]),
                    fmaxf(f[y1 * 64 + x0], f[y1 * 64 + x1]));
    flat[id] = v;
}

// ---------------- 8. f16 MFMA GEMM with split-K ----------------
__global__ void __launch_bounds__(256)
gemm_mfma(const float* __restrict__ A, const float* __restrict__ B,
          float* __restrict__ part, int M, int N, int K, int kchunk) {
    __shared__ char Asb[64 * 128];    // 64 rows x 64 f16
    __shared__ char Bsb[128 * 128];   // 128 rows x 64 f16
    int tid = threadIdx.x;
    int n0 = blockIdx.x * 128;
    int m0 = blockIdx.y * 64;
    int z  = blockIdx.z;
    int ks = z * kchunk;
    int klen = K - ks; if (klen > kchunk) klen = kchunk;
    int lane = tid & 63;
    int w = tid >> 6;

    f32x4 acc[4][2];
    #pragma unroll
    for (int tm = 0; tm < 4; ++tm)
        #pragma unroll
        for (int tn = 0; tn < 2; ++tn)
            acc[tm][tn] = f32x4{0.f, 0.f, 0.f, 0.f};

    for (int k0 = 0; k0 < klen; k0 += 64) {
        #pragma unroll
        for (int i = 0; i < 4; ++i) {          // A: 1024 float4
            int idx = tid + i * 256;
            int r = idx >> 4, fq = idx & 15;
            int gm = m0 + r;
            float4 v = make_float4(0.f, 0.f, 0.f, 0.f);
            if (gm < M) v = *(const float4*)(A + (size_t)gm * K + ks + k0 + fq * 4);
            union { _Float16 h[4]; uint2 u; } cv;
            cv.h[0] = (_Float16)v.x; cv.h[1] = (_Float16)v.y;
            cv.h[2] = (_Float16)v.z; cv.h[3] = (_Float16)v.w;
            *(uint2*)(Asb + r * 128 + ((fq * 8) ^ ((r & 7) << 4))) = cv.u;
        }
        #pragma unroll
        for (int i = 0; i < 8; ++i) {          // B: 2048 float4
            int idx = tid + i * 256;
            int r = idx >> 4, fq = idx & 15;
            float4 v = *(const float4*)(B + (size_t)(n0 + r) * K + ks + k0 + fq * 4);
            union { _Float16 h[4]; uint2 u; } cv;
            cv.h[0] = (_Float16)v.x; cv.h[1] = (_Float16)v.y;
            cv.h[2] = (_Float16)v.z; cv.h[3] = (_Float16)v.w;
            *(uint2*)(Bsb + r * 128 + ((fq * 8) ^ ((r & 7) << 4))) = cv.u;
        }
        __syncthreads();
        #pragma unroll
        for (int kk = 0; kk < 2; ++kk) {
            int kbyte = kk * 64 + (lane >> 4) * 16;
            f16x8 a[4], bfr[2];
            #pragma unroll
            for (int tm = 0; tm < 4; ++tm) {
                int r = tm * 16 + (lane & 15);
                a[tm] = *(const f16x8*)(Asb + r * 128 + (kbyte ^ ((r & 7) << 4)));
            }
            #pragma unroll
            for (int tn = 0; tn < 2; ++tn) {
                int r = w * 32 + tn * 16 + (lane & 15);
                bfr[tn] = *(const f16x8*)(Bsb + r * 128 + (kbyte ^ ((r & 7) << 4)));
            }
            #pragma unroll
            for (int tm = 0; tm < 4; ++tm)
                #pragma unroll
                for (int tn = 0; tn < 2; ++tn)
                    acc[tm][tn] = __builtin_amdgcn_mfma_f32_16x16x32_f16(a[tm], bfr[tn], acc[tm][tn], 0, 0, 0);
        }
        __syncthreads();
    }
    float* pout = part + (size_t)z * M * N;
    #pragma unroll
    for (int tm = 0; tm < 4; ++tm) {
        int mbase = m0 + tm * 16 + (lane >> 4) * 4;
        #pragma unroll
        for (int j = 0; j < 4; ++j) {
            int m = mbase + j;
            if (m < M) {
                #pragma unroll
                for (int tn = 0; tn < 2; ++tn) {
                    int n = n0 + w * 32 + tn * 16 + (lane & 15);
                    pout[(size_t)m * N + n] = acc[tm][tn][j];
                }
            }
        }
    }
}

// ---------------- 8b. reduce partials + bias + relu ----------------
__global__ void reduce_k(const float* __restrict__ part, const float* __restrict__ bias,
                         float* __restrict__ outp, int M, int N, int ns) {
    size_t i = (size_t)blockIdx.x * 256 + threadIdx.x;    // float4 index
    size_t mn4 = (size_t)M * N / 4;
    if (i >= mn4) return;
    float4 s = *(const float4*)(part + i * 4);
    for (int zz = 1; zz < ns; ++zz) {
        float4 v = *(const float4*)(part + (size_t)zz * M * N + i * 4);
        s.x += v.x; s.y += v.y; s.z += v.z; s.w += v.w;
    }
    int n = (int)((i * 4) % N);
    float4 b = *(const float4*)(bias + n);
    s.x = fmaxf(s.x + b.x, 0.f); s.y = fmaxf(s.y + b.y, 0.f);
    s.z = fmaxf(s.z + b.z, 0.f); s.w = fmaxf(s.w + b.w, 0.f);
    *(float4*)(outp + i * 4) = s;
}

// ---------------- 9. final heads: wave per output + keep mask ----------------
__global__ void __launch_bounds__(256)
final_k(const float* __restrict__ h2, const float* __restrict__ clsw,
        const float* __restrict__ clsb, const float* __restrict__ boxw,
        const float* __restrict__ boxb, const int* __restrict__ keep,
        float* __restrict__ out) {
    int gid = blockIdx.x * 4 + (threadIdx.x >> 6);
    if (gid >= NTOP * 25) return;
    int lane = threadIdx.x & 63;
    int k = gid / 25, o = gid % 25;
    const float* w;
    float b;
    if (o < 21) { w = clsw + (size_t)o * 4096; b = clsb[o]; }
    else        { w = boxw + (size_t)(o - 21) * 4096; b = boxb[o - 21]; }
    const float* h = h2 + (size_t)k * 4096;
    float s = 0.0f;
    #pragma unroll
    for (int i = 0; i < 16; ++i) {
        float4 hv = *(const float4*)(h + (i * 64 + lane) * 4);
        float4 wv = *(const float4*)(w + (i * 64 + lane) * 4);
        s += hv.x * wv.x + hv.y * wv.y + hv.z * wv.z + hv.w * wv.w;
    }
    #pragma unroll
    for (int off = 1; off < 64; off <<= 1) s += __shfl_xor(s, off, 64);
    if (lane == 0) out[gid] = keep[k] ? (s + b) : 0.0f;
}

// ---------------- launch ----------------
extern "C" void kernel_launch(void* const* d_in, const int* in_sizes, int n_in,
                              void* d_out, int out_size, void* d_ws, size_t ws_size,
                              hipStream_t stream) {
    const float* x    = (const float*)d_in[0];
    const float* Wf   = (const float*)d_in[2];
    const float* bf   = (const float*)d_in[3];
    const float* W1   = (const float*)d_in[4];
    const float* b1   = (const float*)d_in[5];
    const float* Wc   = (const float*)d_in[6];
    const float* bc   = (const float*)d_in[7];
    const float* Wb   = (const float*)d_in[8];
    const float* bb   = (const float*)d_in[9];
    const float* fc1w = (const float*)d_in[10];
    const float* fc1b = (const float*)d_in[11];
    const float* fc2w = (const float*)d_in[12];
    const float* fc2b = (const float*)d_in[13];
    const float* clsw = (const float*)d_in[14];
    const float* clsb = (const float*)d_in[15];
    const float* boxw = (const float*)d_in[16];
    const float* boxb = (const float*)d_in[17];
    const void*  wp   = d_in[18];
    const void*  hp   = d_in[19];

    char* ws = (char*)d_ws;
    float* fpad  = (float*)(ws + OFF_FPAD);
    float* hmap  = (float*)(ws + OFF_HMAP);
    float* score = (float*)(ws + OFF_SCORE);
    float* preb  = (float*)(ws + OFF_PREB);
    float* ts    = (float*)(ws + OFF_TS);
    int*   ti    = (int*)(ws + OFF_TI);
    int*   keep  = (int*)(ws + OFF_KEEP);
    int*   ixb   = (int*)(ws + OFF_IX);
    int*   iyb   = (int*)(ws + OFF_IY);
    float* flat  = (float*)(ws + OFF_FLAT);
    float* cpart = (float*)(ws + OFF_FLAT);   // conv partials, dead before roipool
    float* h1    = (float*)(ws + OFF_H1);
    float* h2    = (float*)(ws + OFF_H2);
    float* w1t   = (float*)(ws + OFF_H2);     // transient, dead before h2 written
    float* out   = (float*)d_out;

    // split-K configuration, guarded by ws_size
    size_t slot = (size_t)NTOP * FCN * 4;   // 4.9 MB
    size_t avail = ws_size > OFF_PART ? (ws_size - OFF_PART) / slot : 0;
    float *part1, *part2;
    int ns1, ns2;
    if (avail >= 2) {
        part1 = part2 = (float*)(ws + OFF_PART);
        ns1 = (int)(avail < 7 ? avail : 7);
        ns2 = (int)(avail < 4 ? avail : 4);
    } else {
        part1 = (float*)(ws + OFF_H2);   ns1 = 1;
        part2 = (float*)(ws + OFF_FLAT); ns2 = 3;
    }
    int st1 = (196 + ns1 - 1) / ns1;  int kch1 = st1 * 64;  int ns1e = (196 + st1 - 1) / st1;
    int st2 = (64 + ns2 - 1) / ns2;   int kch2 = st2 * 64;  int ns2e = (64 + st2 - 1) / st2;

    zero_fpad<<<832, 256, 0, stream>>>(fpad);
    patch_conv<<<dim3(10, 64), 256, 0, stream>>>(x, Wf, bf, fpad);
    transpose_w1<<<(2304 * 256 + 255) / 256, 256, 0, stream>>>(W1, w1t);
    conv3x3_part<<<dim3(7, 50, 4), 256, 0, stream>>>(fpad, w1t, cpart);
    reduce_conv<<<(NPIX * 256 / 4 + 255) / 256, 256, 0, stream>>>(cpart, b1, hmap);
    head_k<<<625, 256, 0, stream>>>(hmap, Wc, bc, Wb, bb, score, preb);
    topk_k<<<1, 1024, 0, stream>>>(score, ts, ti);
    nms_fused<<<1, 320, 0, stream>>>(preb, ti, ts, wp, hp, keep, ixb, iyb);
    roipool_k<<<(NTOP * DFLAT + 255) / 256, 256, 0, stream>>>(fpad, ixb, iyb, flat);
    gemm_mfma<<<dim3(32, 5, ns1e), 256, 0, stream>>>(flat, fc1w, part1, NTOP, FCN, DFLAT, kch1);
    reduce_k<<<1200, 256, 0, stream>>>(part1, fc1b, h1, NTOP, FCN, ns1e);
    gemm_mfma<<<dim3(32, 5, ns2e), 256, 0, stream>>>(h1, fc2w, part2, NTOP, FCN, FCN, kch2);
    reduce_k<<<1200, 256, 0, stream>>>(part2, fc2b, h2, NTOP, FCN, ns2e);
    final_k<<<(NTOP * 25 + 3) / 4, 256, 0, stream>>>(h2, clsw, clsb, boxw, boxb, keep, out);
}

// Round 6
// 427.610 us; speedup vs baseline: 4.7032x; 1.1387x over previous
//
#include <hip/hip_runtime.h>
#include <hip/hip_bf16.h>
#include <math.h>

// ---------------- problem constants ----------------
#define NPIX   2500      // 50*50
#define CFEAT  256
#define NTOP   300
#define DFLAT  12544     // 256*7*7
#define FCN    4096
#define FPSTRIDE 3328    // 52 rows * 64 floats per channel (padded feature)
#define KG1    392       // DFLAT/32
#define KG2    128       // FCN/32
#define MT     20        // m-tiles (320 rows padded)

typedef _Float16 f16x8 __attribute__((ext_vector_type(8)));
typedef float    f32x4 __attribute__((ext_vector_type(4)));

// ---------------- workspace offsets (bytes) ----------------
static constexpr size_t OFF_FPAD  = 0;          // 3.4 MB
static constexpr size_t OFF_HMAP  = 0x340000;   // 2.56 MB (pix, co)
static constexpr size_t OFF_SCORE = 0x5C0000;
static constexpr size_t OFF_PREB  = 0x5D0000;
static constexpr size_t OFF_TS    = 0x5E0000;
static constexpr size_t OFF_TI    = 0x5E1000;
static constexpr size_t OFF_KEEP  = 0x5E5000;
static constexpr size_t OFF_IX    = 0x5E6000;
static constexpr size_t OFF_IY    = 0x5EB000;
static constexpr size_t OFF_AFRAG = 0x600000;   // A fragments f16, 8.03 MB (also cpart 10.24MB earlier, dead by then)
static constexpr size_t OFF_H1F   = 0xE00000;   // h1 fragments f16, 2.62 MB
static constexpr size_t OFF_H2    = 0x1100000;  // h2 f32 4.9 MB
static constexpr size_t OFF_W1T   = 0x1600000;  // 2.36 MB transient
static constexpr size_t OFF_PART  = 0x1900000;  // split-K partials (up to 7 x 4.9 MB -> 60.6 MB total)

__device__ inline float decode_dim(const void* p) {
    int iv = *(const int*)p;
    if (iv > 0 && iv < (1 << 20)) return (float)iv;
    return __int_as_float(iv);
}

// ---------------- 0. zero the padded feature buffer ----------------
__global__ void zero_fpad(float* __restrict__ fpad) {
    int i = blockIdx.x * 256 + threadIdx.x;   // float4 index, 256*3328/4 = 212992
    if (i < 212992) *(float4*)(fpad + (size_t)i * 4) = make_float4(0.f, 0.f, 0.f, 0.f);
}

// ---------------- 1. patchify conv: 16x16 stride16 VALID -> padded feat -----
__global__ void __launch_bounds__(256)
patch_conv(const float* __restrict__ x, const float* __restrict__ Wf,
           const float* __restrict__ bf, float* __restrict__ fpad) {
    __shared__ float w[3072];          // 4 co x 768
    int co0 = blockIdx.y * 4;
    for (int t = threadIdx.x; t < 3072; t += 256) w[t] = Wf[co0 * 768 + t];
    __syncthreads();
    int p = blockIdx.x * 256 + threadIdx.x;
    if (p >= NPIX) return;
    int py = p / 50, px = p % 50;
    float acc[4];
    #pragma unroll
    for (int c = 0; c < 4; ++c) acc[c] = bf[co0 + c];
    for (int ci = 0; ci < 3; ++ci) {
        const float* xp = x + ci * 640000 + (py * 16) * 800 + px * 16;
        #pragma unroll
        for (int ky = 0; ky < 16; ++ky) {
            const float* row = xp + ky * 800;
            #pragma unroll
            for (int kq = 0; kq < 4; ++kq) {
                float4 xv = *reinterpret_cast<const float4*>(row + kq * 4);
                int kb = ci * 256 + ky * 16 + kq * 4;
                #pragma unroll
                for (int c = 0; c < 4; ++c) {
                    const float* wc = w + c * 768 + kb;
                    acc[c] += xv.x * wc[0] + xv.y * wc[1] + xv.z * wc[2] + xv.w * wc[3];
                }
            }
        }
    }
    size_t o = (size_t)(py + 1) * 64 + (px + 1);
    #pragma unroll
    for (int c = 0; c < 4; ++c) fpad[(size_t)(co0 + c) * FPSTRIDE + o] = acc[c];
}

// ---------------- 1b. transpose W1 -> (ci*9+j, co) ----------------
__global__ void transpose_w1(const float* __restrict__ W1, float* __restrict__ W1t) {
    int idx = blockIdx.x * 256 + threadIdx.x;
    if (idx >= 2304 * 256) return;
    int r = idx >> 8, co = idx & 255;
    W1t[idx] = W1[co * 2304 + r];
}

// ---------------- 2. 3x3 SAME conv partials (lanes=co, 8-pixel batch, ci split 4) --
__global__ void __launch_bounds__(256)
conv3x3_part(const float* __restrict__ fpad, const float* __restrict__ W1t,
             float* __restrict__ cpart) {
    int co = threadIdx.x;
    int xb = blockIdx.x * 8;          // 0,8,...,48
    int y  = blockIdx.y;              // 0..49
    int z  = blockIdx.z;              // 0..3
    float acc[8];
    #pragma unroll
    for (int p = 0; p < 8; ++p) acc[p] = 0.0f;
    const float* fp = fpad + (size_t)(z * 64) * FPSTRIDE + (size_t)y * 64 + xb;
    const float* wp = W1t + (size_t)(z * 64) * 9 * 256 + co;
    #pragma unroll 2
    for (int ci = 0; ci < 64; ++ci) {
        float v[3][12];
        #pragma unroll
        for (int dy = 0; dy < 3; ++dy) {
            #pragma unroll
            for (int q = 0; q < 3; ++q) {
                float4 r4 = *(const float4*)(fp + dy * 64 + q * 4);
                v[dy][q * 4 + 0] = r4.x; v[dy][q * 4 + 1] = r4.y;
                v[dy][q * 4 + 2] = r4.z; v[dy][q * 4 + 3] = r4.w;
            }
        }
        float wv[9];
        #pragma unroll
        for (int k = 0; k < 9; ++k) wv[k] = wp[k * 256];
        #pragma unroll
        for (int dy = 0; dy < 3; ++dy)
            #pragma unroll
            for (int dx = 0; dx < 3; ++dx) {
                float wvv = wv[dy * 3 + dx];
                #pragma unroll
                for (int p = 0; p < 8; ++p)
                    acc[p] += v[dy][p + dx] * wvv;
            }
        fp += FPSTRIDE;
        wp += 9 * 256;
    }
    size_t base = (size_t)z * (NPIX * 256) + (size_t)(y * 50 + xb) * 256 + co;
    #pragma unroll
    for (int p = 0; p < 8; ++p)
        if (xb + p < 50) cpart[base + (size_t)p * 256] = acc[p];
}

// ---------------- 2b. reduce conv partials + bias + relu -> hmap (pix, co) --
__global__ void reduce_conv(const float* __restrict__ cpart, const float* __restrict__ b1,
                            float* __restrict__ hmap) {
    int i = blockIdx.x * 256 + threadIdx.x;   // float4 index over 2500*256/4
    if (i >= NPIX * 256 / 4) return;
    float4 s = *(const float4*)(cpart + (size_t)i * 4);
    #pragma unroll
    for (int z = 1; z < 4; ++z) {
        float4 v = *(const float4*)(cpart + (size_t)z * (NPIX * 256) + (size_t)i * 4);
        s.x += v.x; s.y += v.y; s.z += v.z; s.w += v.w;
    }
    float4 b = *(const float4*)(b1 + (i & 63) * 4);
    s.x = fmaxf(s.x + b.x, 0.f); s.y = fmaxf(s.y + b.y, 0.f);
    s.z = fmaxf(s.z + b.z, 0.f); s.w = fmaxf(s.w + b.w, 0.f);
    *(float4*)(hmap + (size_t)i * 4) = s;
}

// ---------------- 3. heads: wave per pixel, float4 dot + shuffle reduce ----
__global__ void head_k(const float* __restrict__ hmap, const float* __restrict__ Wc,
                       const float* __restrict__ bc, const float* __restrict__ Wb,
                       const float* __restrict__ bb, float* __restrict__ score,
                       float* __restrict__ preb) {
    int lane = threadIdx.x & 63;
    int p = blockIdx.x * 4 + (threadIdx.x >> 6);
    if (p >= NPIX) return;
    float4 h  = *(const float4*)(hmap + (size_t)p * 256 + lane * 4);
    float4 c0 = *(const float4*)(Wc + lane * 4);
    float4 c1 = *(const float4*)(Wc + 256 + lane * 4);
    float4 w0 = *(const float4*)(Wb + lane * 4);
    float4 w1 = *(const float4*)(Wb + 256 + lane * 4);
    float4 w2 = *(const float4*)(Wb + 512 + lane * 4);
    float4 w3 = *(const float4*)(Wb + 768 + lane * 4);
    float s[6];
    s[0] = h.x*c0.x + h.y*c0.y + h.z*c0.z + h.w*c0.w;
    s[1] = h.x*c1.x + h.y*c1.y + h.z*c1.z + h.w*c1.w;
    s[2] = h.x*w0.x + h.y*w0.y + h.z*w0.z + h.w*w0.w;
    s[3] = h.x*w1.x + h.y*w1.y + h.z*w1.z + h.w*w1.w;
    s[4] = h.x*w2.x + h.y*w2.y + h.z*w2.z + h.w*w2.w;
    s[5] = h.x*w3.x + h.y*w3.y + h.z*w3.z + h.w*w3.w;
    #pragma unroll
    for (int o = 1; o < 64; o <<= 1) {
        #pragma unroll
        for (int q = 0; q < 6; ++q) s[q] += __shfl_xor(s[q], o, 64);
    }
    if (lane == 0) {
        float s0 = s[0] + bc[0], s1 = s[1] + bc[1];
        float m = fmaxf(s0, s1);
        float e0 = expf(s0 - m), e1 = expf(s1 - m);
        score[p] = e1 / (e0 + e1);
        preb[p * 4 + 0] = s[2] + bb[0];
        preb[p * 4 + 1] = s[3] + bb[1];
        preb[p * 4 + 2] = s[4] + bb[2];
        preb[p * 4 + 3] = s[5] + bb[3];
    }
}

// ---------------- 4. top-k via full bitonic sort (desc value, asc index) ---
__global__ void __launch_bounds__(1024) topk_k(const float* __restrict__ score,
                                               float* __restrict__ ts, int* __restrict__ ti) {
    __shared__ float sv[4096];
    __shared__ int   si[4096];
    int tid = threadIdx.x;
    for (int t = tid; t < 4096; t += 1024) {
        sv[t] = (t < NPIX) ? score[t] : -INFINITY;
        si[t] = t;
    }
    __syncthreads();
    for (int k = 2; k <= 4096; k <<= 1) {
        for (int j = k >> 1; j > 0; j >>= 1) {
            for (int t = tid; t < 4096; t += 1024) {
                int l = t ^ j;
                if (l > t) {
                    float vt = sv[t], vl = sv[l];
                    int it = si[t], il = si[l];
                    bool l_before_t = (vl > vt) || (vl == vt && il < it);
                    bool dir = ((t & k) == 0);
                    if (dir == l_before_t) {
                        sv[t] = vl; sv[l] = vt;
                        si[t] = il; si[l] = it;
                    }
                }
            }
            __syncthreads();
        }
    }
    for (int t = tid; t < NTOP; t += 1024) { ts[t] = sv[t]; ti[t] = si[t]; }
}

// ---------------- 5+6. fused box decode + ROI coords + bitmask NMS ----------
__global__ void __launch_bounds__(320)
nms_fused(const float* __restrict__ preb, const int* __restrict__ ti,
          const float* __restrict__ ts, const void* wp_, const void* hp_,
          int* __restrict__ keep, int* __restrict__ ixb, int* __restrict__ iyb) {
    __shared__ float X1[320], Y1[320], X2[320], Y2[320], AR[320];
    __shared__ unsigned long long MASK[320][5];
    __shared__ unsigned long long KEEPW[5];
    int t = threadIdx.x;
    int lane = t & 63;
    int w = t >> 6;

    float x1 = 0.f, y1 = 0.f, x2 = 0.f, y2 = 0.f;
    bool v = false;
    if (t < NTOP) {
        float wf = decode_dim(wp_), hf = decode_dim(hp_);
        int id = ti[t];
        float p0 = preb[id * 4 + 0], p1 = preb[id * 4 + 1];
        float p2 = preb[id * 4 + 2], p3 = preb[id * 4 + 3];
        x1 = fmaxf(p2 - p0 * 0.5f, 0.0f);
        y1 = fmaxf(p3 - p1 * 0.5f, 0.0f);
        x2 = fminf(p2 + p0, wf);
        y2 = fminf(p3 + p1, hf);
        v = ts[t] > 0.5f;
        float bx1 = x1 * 0.0625f, by1 = y1 * 0.0625f;
        float bx2 = x2 * 0.0625f, by2 = y2 * 0.0625f;
        #pragma unroll
        for (int m = 0; m < 14; ++m) {
            int i = m >> 1, s = m & 1;
            float frac = ((float)i + (s ? 0.75f : 0.25f)) / 7.0f;
            float xs = bx1 + frac * (bx2 - bx1);
            float ys = by1 + frac * (by2 - by1);
            float fx = floorf(xs); fx = fminf(fmaxf(fx, 0.0f), 49.0f);
            float fy = floorf(ys); fy = fminf(fmaxf(fy, 0.0f), 49.0f);
            ixb[t * 14 + m] = (int)fx;
            iyb[t * 14 + m] = (int)fy;
        }
    }
    X1[t] = x1; Y1[t] = y1; X2[t] = x2; Y2[t] = y2;
    AR[t] = fmaxf(x2 - x1, 0.0f) * fmaxf(y2 - y1, 0.0f);
    unsigned long long vb = __ballot(v);
    if (lane == 0) KEEPW[w] = vb;
    __syncthreads();

    float xi1 = X1[t], yi1 = Y1[t], xi2 = X2[t], yi2 = Y2[t], ai = AR[t];
    #pragma unroll
    for (int jw = 0; jw < 5; ++jw) {
        unsigned long long mword = 0ull;
        #pragma unroll 4
        for (int j2 = 0; j2 < 64; ++j2) {
            int j = jw * 64 + j2;
            float ix1 = fmaxf(xi1, X1[j]);
            float iy1 = fmaxf(yi1, Y1[j]);
            float ix2 = fminf(xi2, X2[j]);
            float iy2 = fminf(yi2, Y2[j]);
            float inter = fmaxf(ix2 - ix1, 0.0f) * fmaxf(iy2 - iy1, 0.0f);
            float iou = inter / fmaxf(ai + AR[j] - inter, 1e-6f);
            bool sup = (iou > 0.7f) && (j > t) && (j < NTOP);
            mword |= sup ? (1ull << j2) : 0ull;
        }
        MASK[t][jw] = mword;
    }
    __syncthreads();
    if (w != 0) return;

    unsigned long long m[5][5];
    #pragma unroll
    for (int g = 0; g < 5; ++g)
        #pragma unroll
        for (int q = 0; q < 5; ++q)
            m[g][q] = MASK[g * 64 + lane][q];
    unsigned long long kw0 = KEEPW[0], kw1 = KEEPW[1], kw2 = KEEPW[2],
                       kw3 = KEEPW[3], kw4 = KEEPW[4];
    #pragma unroll
    for (int g = 0; g < 5; ++g) {
        for (int i2 = 0; i2 < 64; ++i2) {
            unsigned long long kg = (g == 0) ? kw0 : (g == 1) ? kw1 :
                                    (g == 2) ? kw2 : (g == 3) ? kw3 : kw4;
            bool alive = (kg >> i2) & 1ull;
            unsigned long long b0 = __shfl(m[g][0], i2, 64);
            unsigned long long b1 = __shfl(m[g][1], i2, 64);
            unsigned long long b2 = __shfl(m[g][2], i2, 64);
            unsigned long long b3 = __shfl(m[g][3], i2, 64);
            unsigned long long b4 = __shfl(m[g][4], i2, 64);
            if (alive) {
                kw0 &= ~b0; kw1 &= ~b1; kw2 &= ~b2; kw3 &= ~b3; kw4 &= ~b4;
            }
        }
    }
    #pragma unroll
    for (int g = 0; g < 5; ++g) {
        unsigned long long kg = (g == 0) ? kw0 : (g == 1) ? kw1 :
                                (g == 2) ? kw2 : (g == 3) ? kw3 : kw4;
        int j = g * 64 + lane;
        if (j < NTOP) keep[j] = (int)((kg >> lane) & 1ull);
    }
}

// ---------------- 7. ROI max pool -> A fragments (f16, MFMA per-lane layout) -
// word wid = (T*KG1 + g)*64 + l ; lane l holds A[m=T*16+(l&15)][k=g*32+((l>>4)&3)*8 + e]
__global__ void __launch_bounds__(256)
roipool_frag(const float* __restrict__ fpad, const int* __restrict__ ixb,
             const int* __restrict__ iyb, _Float16* __restrict__ Af) {
    int wid = blockIdx.x * 256 + threadIdx.x;
    if (wid >= MT * KG1 * 64) return;
    int l = wid & 63;
    int g = (wid >> 6) % KG1;
    int T = wid / (KG1 * 64);
    int mm = T * 16 + (l & 15);
    int kbase = g * 32 + ((l >> 4) & 3) * 8;
    union { _Float16 h[8]; uint4 u; } o;
    if (mm < NTOP) {
        const int* ix = ixb + mm * 14;
        const int* iy = iyb + mm * 14;
        #pragma unroll
        for (int e = 0; e < 8; ++e) {
            int k = kbase + e;
            int c = k / 49, ij = k % 49, i = ij / 7, jx = ij % 7;
            int y0 = iy[2 * i] + 1, y1 = iy[2 * i + 1] + 1;
            int x0 = ix[2 * jx] + 1, x1 = ix[2 * jx + 1] + 1;
            const float* f = fpad + (size_t)c * FPSTRIDE;
            float v = fmaxf(fmaxf(f[y0 * 64 + x0], f[y0 * 64 + x1]),
                            fmaxf(f[y1 * 64 + x0], f[y1 * 64 + x1]));
            o.h[e] = (_Float16)v;
        }
    } else {
        o.u.x = 0u; o.u.y = 0u; o.u.z = 0u; o.u.w = 0u;
    }
    *(uint4*)(Af + (size_t)wid * 8) = o.u;
}

// ---------------- 8. full-M MFMA GEMM: part[z] = Afrag x B^T (f32 weights) ---
// block: 512 thr (8 waves, 4 m-groups x 2 n-groups), tile 320m x 64n.
// B read ONCE from HBM (f32 -> f16 in-kernel, XOR-swizzled LDS).
__global__ void __launch_bounds__(512)
gemm_fullm(const _Float16* __restrict__ Af, const float* __restrict__ B,
           float* __restrict__ part, int K, int KG, int kchunk) {
    __shared__ char Bs[64 * 128];   // 64 rows x 64 f16, swizzled
    int tid = threadIdx.x;
    int lane = tid & 63;
    int w = tid >> 6;
    int wm = w & 3, wn = w >> 2;
    int n0 = blockIdx.x * 64;
    int ks = blockIdx.y * kchunk;

    f32x4 acc[5][2];
    #pragma unroll
    for (int tm = 0; tm < 5; ++tm)
        #pragma unroll
        for (int tn = 0; tn < 2; ++tn)
            acc[tm][tn] = f32x4{0.f, 0.f, 0.f, 0.f};

    int srow = tid >> 3;          // 0..63
    int skp  = (tid & 7) * 8;     // 0..56
    const float* bsrc = B + (size_t)(n0 + srow) * K + ks + skp;
    int sboff = srow * 128 + ((skp * 2) ^ ((srow & 7) << 4));

    float4 v0 = *(const float4*)(bsrc);
    float4 v1 = *(const float4*)(bsrc + 4);
    for (int k0 = 0; k0 < kchunk; k0 += 64) {
        union { _Float16 h[8]; uint4 u; } cv;
        cv.h[0] = (_Float16)v0.x; cv.h[1] = (_Float16)v0.y;
        cv.h[2] = (_Float16)v0.z; cv.h[3] = (_Float16)v0.w;
        cv.h[4] = (_Float16)v1.x; cv.h[5] = (_Float16)v1.y;
        cv.h[6] = (_Float16)v1.z; cv.h[7] = (_Float16)v1.w;
        __syncthreads();                       // prev-iter reads done
        *(uint4*)(Bs + sboff) = cv.u;
        __syncthreads();                       // tile ready
        if (k0 + 64 < kchunk) {                // prefetch next B (hides HBM latency under MFMAs)
            v0 = *(const float4*)(bsrc + k0 + 64);
            v1 = *(const float4*)(bsrc + k0 + 68);
        }
        #pragma unroll
        for (int kk = 0; kk < 2; ++kk) {
            int g = (ks + k0 + kk * 32) >> 5;
            f16x8 bfr[2];
            #pragma unroll
            for (int tn = 0; tn < 2; ++tn) {
                int row = wn * 32 + tn * 16 + (lane & 15);
                int kb = kk * 64 + (lane >> 4) * 16;
                bfr[tn] = *(const f16x8*)(Bs + row * 128 + (kb ^ ((row & 7) << 4)));
            }
            #pragma unroll
            for (int tm = 0; tm < 5; ++tm) {
                int T = wm * 5 + tm;
                f16x8 a = *(const f16x8*)(Af + ((size_t)(T * KG + g) * 64 + lane) * 8);
                #pragma unroll
                for (int tn = 0; tn < 2; ++tn)
                    acc[tm][tn] = __builtin_amdgcn_mfma_f32_16x16x32_f16(a, bfr[tn], acc[tm][tn], 0, 0, 0);
            }
        }
    }
    float* pout = part + (size_t)blockIdx.y * (NTOP * FCN);
    #pragma unroll
    for (int tm = 0; tm < 5; ++tm) {
        int mbase = (wm * 5 + tm) * 16 + (lane >> 4) * 4;
        #pragma unroll
        for (int j = 0; j < 4; ++j) {
            int m = mbase + j;
            if (m < NTOP) {
                #pragma unroll
                for (int tn = 0; tn < 2; ++tn) {
                    int n = n0 + wn * 32 + tn * 16 + (lane & 15);
                    pout[(size_t)m * FCN + n] = acc[tm][tn][j];
                }
            }
        }
    }
}

// ---------------- 8b. reduce fc1 partials + bias + relu -> h1 fragments f16 --
__global__ void reduce_fc1(const float* __restrict__ part, const float* __restrict__ bias,
                           _Float16* __restrict__ h1f, int ns) {
    int i = blockIdx.x * 256 + threadIdx.x;     // 300*512
    if (i >= NTOP * 512) return;
    int m = i >> 9;
    int f = (i & 511) * 8;
    float s[8];
    const float* p0 = part + (size_t)m * FCN + f;
    #pragma unroll
    for (int e = 0; e < 8; ++e) s[e] = p0[e];
    for (int z = 1; z < ns; ++z) {
        const float* pz = p0 + (size_t)z * (NTOP * FCN);
        #pragma unroll
        for (int e = 0; e < 8; ++e) s[e] += pz[e];
    }
    union { _Float16 h[8]; uint4 u; } o;
    #pragma unroll
    for (int e = 0; e < 8; ++e) o.h[e] = (_Float16)fmaxf(s[e] + bias[f + e], 0.0f);
    int T = m >> 4, g = f >> 5, l = (m & 15) + 16 * ((f >> 3) & 3);
    *(uint4*)(h1f + ((size_t)(T * KG2 + g) * 64 + l) * 8) = o.u;
}

// ---------------- 8c. reduce fc2 partials + bias + relu -> h2 f32 ----------
__global__ void reduce_fc2(const float* __restrict__ part, const float* __restrict__ bias,
                           float* __restrict__ outp, int ns) {
    size_t i = (size_t)blockIdx.x * 256 + threadIdx.x;    // float4 index
    size_t mn4 = (size_t)NTOP * FCN / 4;
    if (i >= mn4) return;
    float4 s = *(const float4*)(part + i * 4);
    for (int zz = 1; zz < ns; ++zz) {
        float4 v = *(const float4*)(part + (size_t)zz * (NTOP * FCN) + i * 4);
        s.x += v.x; s.y += v.y; s.z += v.z; s.w += v.w;
    }
    int n = (int)((i * 4) % FCN);
    float4 b = *(const float4*)(bias + n);
    s.x = fmaxf(s.x + b.x, 0.f); s.y = fmaxf(s.y + b.y, 0.f);
    s.z = fmaxf(s.z + b.z, 0.f); s.w = fmaxf(s.w + b.w, 0.f);
    *(float4*)(outp + i * 4) = s;
}

// ---------------- 9. final heads: wave per output + keep mask ----------------
__global__ void __launch_bounds__(256)
final_k(const float* __restrict__ h2, const float* __restrict__ clsw,
        const float* __restrict__ clsb, const float* __restrict__ boxw,
        const float* __restrict__ boxb, const int* __restrict__ keep,
        float* __restrict__ out) {
    int gid = blockIdx.x * 4 + (threadIdx.x >> 6);
    if (gid >= NTOP * 25) return;
    int lane = threadIdx.x & 63;
    int k = gid / 25, o = gid % 25;
    const float* w;
    float b;
    if (o < 21) { w = clsw + (size_t)o * 4096; b = clsb[o]; }
    else        { w = boxw + (size_t)(o - 21) * 4096; b = boxb[o - 21]; }
    const float* h = h2 + (size_t)k * 4096;
    float s = 0.0f;
    #pragma unroll
    for (int i = 0; i < 16; ++i) {
        float4 hv = *(const float4*)(h + (i * 64 + lane) * 4);
        float4 wv = *(const float4*)(w + (i * 64 + lane) * 4);
        s += hv.x * wv.x + hv.y * wv.y + hv.z * wv.z + hv.w * wv.w;
    }
    #pragma unroll
    for (int off = 1; off < 64; off <<= 1) s += __shfl_xor(s, off, 64);
    if (lane == 0) out[gid] = keep[k] ? (s + b) : 0.0f;
}

// ---------------- launch ----------------
extern "C" void kernel_launch(void* const* d_in, const int* in_sizes, int n_in,
                              void* d_out, int out_size, void* d_ws, size_t ws_size,
                              hipStream_t stream) {
    const float* x    = (const float*)d_in[0];
    const float* Wf   = (const float*)d_in[2];
    const float* bf   = (const float*)d_in[3];
    const float* W1   = (const float*)d_in[4];
    const float* b1   = (const float*)d_in[5];
    const float* Wc   = (const float*)d_in[6];
    const float* bc   = (const float*)d_in[7];
    const float* Wb   = (const float*)d_in[8];
    const float* bb   = (const float*)d_in[9];
    const float* fc1w = (const float*)d_in[10];
    const float* fc1b = (const float*)d_in[11];
    const float* fc2w = (const float*)d_in[12];
    const float* fc2b = (const float*)d_in[13];
    const float* clsw = (const float*)d_in[14];
    const float* clsb = (const float*)d_in[15];
    const float* boxw = (const float*)d_in[16];
    const float* boxb = (const float*)d_in[17];
    const void*  wp   = d_in[18];
    const void*  hp   = d_in[19];

    char* ws = (char*)d_ws;
    float*     fpad  = (float*)(ws + OFF_FPAD);
    float*     hmap  = (float*)(ws + OFF_HMAP);
    float*     score = (float*)(ws + OFF_SCORE);
    float*     preb  = (float*)(ws + OFF_PREB);
    float*     ts    = (float*)(ws + OFF_TS);
    int*       ti    = (int*)(ws + OFF_TI);
    int*       keep  = (int*)(ws + OFF_KEEP);
    int*       ixb   = (int*)(ws + OFF_IX);
    int*       iyb   = (int*)(ws + OFF_IY);
    _Float16*  Af    = (_Float16*)(ws + OFF_AFRAG);
    float*     cpart = (float*)(ws + OFF_AFRAG);  // conv partials, dead before roipool
    _Float16*  h1f   = (_Float16*)(ws + OFF_H1F);
    float*     h2    = (float*)(ws + OFF_H2);
    float*     w1t   = (float*)(ws + OFF_W1T);
    float*     out   = (float*)d_out;

    // split-K slots, guarded by ws_size
    size_t slot = (size_t)NTOP * FCN * 4;   // 4.9 MB
    size_t avail = ws_size > OFF_PART ? (ws_size - OFF_PART) / slot : 0;
    int ns1 = (avail >= 7) ? 7 : (avail >= 4) ? 4 : (avail >= 2) ? 2 : 1;
    int ns2 = (avail >= 4) ? 4 : (avail >= 2) ? 2 : 1;
    float* part1 = (avail >= 1) ? (float*)(ws + OFF_PART) : h2;              // h2 free during fc1
    float* part2 = (avail >= 1) ? (float*)(ws + OFF_PART) : (float*)Af;      // Af free after fc1
    int kch1 = (196 / ns1) * 64;
    int kch2 = (64 / ns2) * 64;

    zero_fpad<<<832, 256, 0, stream>>>(fpad);
    patch_conv<<<dim3(10, 64), 256, 0, stream>>>(x, Wf, bf, fpad);
    transpose_w1<<<(2304 * 256 + 255) / 256, 256, 0, stream>>>(W1, w1t);
    conv3x3_part<<<dim3(7, 50, 4), 256, 0, stream>>>(fpad, w1t, cpart);
    reduce_conv<<<(NPIX * 256 / 4 + 255) / 256, 256, 0, stream>>>(cpart, b1, hmap);
    head_k<<<625, 256, 0, stream>>>(hmap, Wc, bc, Wb, bb, score, preb);
    topk_k<<<1, 1024, 0, stream>>>(score, ts, ti);
    nms_fused<<<1, 320, 0, stream>>>(preb, ti, ts, wp, hp, keep, ixb, iyb);
    roipool_frag<<<(MT * KG1 * 64 + 255) / 256, 256, 0, stream>>>(fpad, ixb, iyb, Af);
    gemm_fullm<<<dim3(64, ns1), 512, 0, stream>>>(Af, fc1w, part1, DFLAT, KG1, kch1);
    reduce_fc1<<<(NTOP * 512 + 255) / 256, 256, 0, stream>>>(part1, fc1b, h1f, ns1);
    gemm_fullm<<<dim3(64, ns2), 512, 0, stream>>>(h1f, fc2w, part2, FCN, KG2, kch2);
    reduce_fc2<<<(NTOP * FCN / 4 + 255) / 256, 256, 0, stream>>>(part2, fc2b, h2, ns2);
    final_k<<<(NTOP * 25 + 3) / 4, 256, 0, stream>>>(h2, clsw, clsb, boxw, boxb, keep, out);
}

// Round 7
// 408.103 us; speedup vs baseline: 4.9280x; 1.0478x over previous
//
#include <hip/hip_runtime.h>
#include <hip/hip_bf16.h>
#include <math.h>

// ---------------- problem constants ----------------
#define NPIX   2500      // 50*50
#define CFEAT  256
#define NTOP   300
#define DFLAT  12544     // 256*7*7
#define FCN    4096
#define FPSTRIDE 3328    // 52 rows * 64 floats per channel (padded feature)
#define KG1    392       // DFLAT/32
#define KG2    128       // FCN/32
#define MT     20        // m-tiles (320 rows padded)

typedef _Float16 f16x8 __attribute__((ext_vector_type(8)));
typedef float    f32x4 __attribute__((ext_vector_type(4)));

// ---------------- workspace offsets (bytes) ----------------
static constexpr size_t OFF_FPAD  = 0;          // 3.4 MB
static constexpr size_t OFF_SCORE = 0x5C0000;
static constexpr size_t OFF_PREB  = 0x5D0000;
static constexpr size_t OFF_KEEP  = 0x5E5000;
static constexpr size_t OFF_IX    = 0x5E6000;
static constexpr size_t OFF_IY    = 0x5EB000;
static constexpr size_t OFF_AFRAG = 0x600000;   // A fragments f16, 8.03 MB (ends 0xDA8000)
static constexpr size_t OFF_H1F   = 0xE00000;   // h1 fragments f16, 2.62 MB
static constexpr size_t OFF_H2    = 0x1100000;  // h2 f32, 4.9 MB
static constexpr size_t OFF_W1T   = 0x1600000;  // 2.36 MB transient
static constexpr size_t OFF_PART  = 0x1900000;  // cpart (20.5 MB) then split-K partials (34.3 MB), time-disjoint

__device__ inline float decode_dim(const void* p) {
    int iv = *(const int*)p;
    if (iv > 0 && iv < (1 << 20)) return (float)iv;
    return __int_as_float(iv);
}

// ---------------- 0. zero the padded feature buffer ----------------
__global__ void zero_fpad(float* __restrict__ fpad) {
    int i = blockIdx.x * 256 + threadIdx.x;   // float4 index, 256*3328/4 = 212992
    if (i < 212992) *(float4*)(fpad + (size_t)i * 4) = make_float4(0.f, 0.f, 0.f, 0.f);
}

// ---------------- 1. patchify conv: 16x16 stride16 VALID -> padded feat -----
__global__ void __launch_bounds__(256)
patch_conv(const float* __restrict__ x, const float* __restrict__ Wf,
           const float* __restrict__ bf, float* __restrict__ fpad) {
    __shared__ float w[3072];          // 4 co x 768
    int co0 = blockIdx.y * 4;
    for (int t = threadIdx.x; t < 3072; t += 256) w[t] = Wf[co0 * 768 + t];
    __syncthreads();
    int p = blockIdx.x * 256 + threadIdx.x;
    if (p >= NPIX) return;
    int py = p / 50, px = p % 50;
    float acc[4];
    #pragma unroll
    for (int c = 0; c < 4; ++c) acc[c] = bf[co0 + c];
    for (int ci = 0; ci < 3; ++ci) {
        const float* xp = x + ci * 640000 + (py * 16) * 800 + px * 16;
        #pragma unroll
        for (int ky = 0; ky < 16; ++ky) {
            const float* row = xp + ky * 800;
            #pragma unroll
            for (int kq = 0; kq < 4; ++kq) {
                float4 xv = *reinterpret_cast<const float4*>(row + kq * 4);
                int kb = ci * 256 + ky * 16 + kq * 4;
                #pragma unroll
                for (int c = 0; c < 4; ++c) {
                    const float* wc = w + c * 768 + kb;
                    acc[c] += xv.x * wc[0] + xv.y * wc[1] + xv.z * wc[2] + xv.w * wc[3];
                }
            }
        }
    }
    size_t o = (size_t)(py + 1) * 64 + (px + 1);
    #pragma unroll
    for (int c = 0; c < 4; ++c) fpad[(size_t)(co0 + c) * FPSTRIDE + o] = acc[c];
}

// ---------------- 1b. transpose W1 -> (ci*9+j, co) ----------------
__global__ void transpose_w1(const float* __restrict__ W1, float* __restrict__ W1t) {
    int idx = blockIdx.x * 256 + threadIdx.x;
    if (idx >= 2304 * 256) return;
    int r = idx >> 8, co = idx & 255;
    W1t[idx] = W1[co * 2304 + r];
}

// ---------------- 2. 3x3 SAME conv partials (lanes=co, 8-pixel batch, ci split) --
// grid (7, 50, zs): xgroup, row, ci-chunk of zci=256/zs. Output: cpart[z][pix][co].
__global__ void __launch_bounds__(256)
conv3x3_part(const float* __restrict__ fpad, const float* __restrict__ W1t,
             float* __restrict__ cpart, int zci) {
    int co = threadIdx.x;
    int xb = blockIdx.x * 8;          // 0,8,...,48
    int y  = blockIdx.y;              // 0..49
    int z  = blockIdx.z;
    float acc[8];
    #pragma unroll
    for (int p = 0; p < 8; ++p) acc[p] = 0.0f;
    const float* fp = fpad + (size_t)(z * zci) * FPSTRIDE + (size_t)y * 64 + xb;
    const float* wp = W1t + (size_t)(z * zci) * 9 * 256 + co;
    #pragma unroll 2
    for (int ci = 0; ci < zci; ++ci) {
        float v[3][12];
        #pragma unroll
        for (int dy = 0; dy < 3; ++dy) {
            #pragma unroll
            for (int q = 0; q < 3; ++q) {
                float4 r4 = *(const float4*)(fp + dy * 64 + q * 4);
                v[dy][q * 4 + 0] = r4.x; v[dy][q * 4 + 1] = r4.y;
                v[dy][q * 4 + 2] = r4.z; v[dy][q * 4 + 3] = r4.w;
            }
        }
        float wv[9];
        #pragma unroll
        for (int k = 0; k < 9; ++k) wv[k] = wp[k * 256];
        #pragma unroll
        for (int dy = 0; dy < 3; ++dy)
            #pragma unroll
            for (int dx = 0; dx < 3; ++dx) {
                float wvv = wv[dy * 3 + dx];
                #pragma unroll
                for (int p = 0; p < 8; ++p)
                    acc[p] += v[dy][p + dx] * wvv;
            }
        fp += FPSTRIDE;
        wp += 9 * 256;
    }
    size_t base = (size_t)z * (NPIX * 256) + (size_t)(y * 50 + xb) * 256 + co;
    #pragma unroll
    for (int p = 0; p < 8; ++p)
        if (xb + p < 50) cpart[base + (size_t)p * 256] = acc[p];
}

// ---------------- 2b+3. fused: reduce conv partials + bias + relu + heads ---
// wave per pixel; conv output lives only in registers (no hmap buffer).
__global__ void __launch_bounds__(256)
reducehead_k(const float* __restrict__ cpart, const float* __restrict__ b1,
             const float* __restrict__ Wc, const float* __restrict__ bc,
             const float* __restrict__ Wb, const float* __restrict__ bb,
             float* __restrict__ score, float* __restrict__ preb, int zs) {
    int lane = threadIdx.x & 63;
    int p = blockIdx.x * 4 + (threadIdx.x >> 6);
    if (p >= NPIX) return;
    size_t off = (size_t)p * 256 + lane * 4;
    float4 h = *(const float4*)(cpart + off);
    for (int z = 1; z < zs; ++z) {
        float4 v = *(const float4*)(cpart + (size_t)z * (NPIX * 256) + off);
        h.x += v.x; h.y += v.y; h.z += v.z; h.w += v.w;
    }
    float4 b = *(const float4*)(b1 + lane * 4);
    h.x = fmaxf(h.x + b.x, 0.f); h.y = fmaxf(h.y + b.y, 0.f);
    h.z = fmaxf(h.z + b.z, 0.f); h.w = fmaxf(h.w + b.w, 0.f);
    float4 c0 = *(const float4*)(Wc + lane * 4);
    float4 c1 = *(const float4*)(Wc + 256 + lane * 4);
    float4 w0 = *(const float4*)(Wb + lane * 4);
    float4 w1 = *(const float4*)(Wb + 256 + lane * 4);
    float4 w2 = *(const float4*)(Wb + 512 + lane * 4);
    float4 w3 = *(const float4*)(Wb + 768 + lane * 4);
    float s[6];
    s[0] = h.x*c0.x + h.y*c0.y + h.z*c0.z + h.w*c0.w;
    s[1] = h.x*c1.x + h.y*c1.y + h.z*c1.z + h.w*c1.w;
    s[2] = h.x*w0.x + h.y*w0.y + h.z*w0.z + h.w*w0.w;
    s[3] = h.x*w1.x + h.y*w1.y + h.z*w1.z + h.w*w1.w;
    s[4] = h.x*w2.x + h.y*w2.y + h.z*w2.z + h.w*w2.w;
    s[5] = h.x*w3.x + h.y*w3.y + h.z*w3.z + h.w*w3.w;
    #pragma unroll
    for (int o = 1; o < 64; o <<= 1) {
        #pragma unroll
        for (int q = 0; q < 6; ++q) s[q] += __shfl_xor(s[q], o, 64);
    }
    if (lane == 0) {
        float s0 = s[0] + bc[0], s1 = s[1] + bc[1];
        float m = fmaxf(s0, s1);
        float e0 = expf(s0 - m), e1 = expf(s1 - m);
        score[p] = e1 / (e0 + e1);
        preb[p * 4 + 0] = s[2] + bb[0];
        preb[p * 4 + 1] = s[3] + bb[1];
        preb[p * 4 + 2] = s[4] + bb[2];
        preb[p * 4 + 3] = s[5] + bb[3];
    }
}

// ---------------- 4+5+6. fused top-k sort + box decode + bitmask NMS --------
__global__ void __launch_bounds__(1024)
topknms_k(const float* __restrict__ score, const float* __restrict__ preb,
          const void* wp_, const void* hp_, int* __restrict__ keep,
          int* __restrict__ ixb, int* __restrict__ iyb) {
    __shared__ float sv[4096];
    __shared__ int   si[4096];
    __shared__ float X1[320], Y1[320], X2[320], Y2[320], AR[320];
    __shared__ unsigned long long MASK[320][5];
    __shared__ unsigned long long KEEPW[5];
    int tid = threadIdx.x;
    int lane = tid & 63;
    int w = tid >> 6;

    // ---- bitonic sort (desc value, tie -> asc index) ----
    for (int t = tid; t < 4096; t += 1024) {
        sv[t] = (t < NPIX) ? score[t] : -INFINITY;
        si[t] = t;
    }
    __syncthreads();
    for (int k = 2; k <= 4096; k <<= 1) {
        for (int j = k >> 1; j > 0; j >>= 1) {
            for (int t = tid; t < 4096; t += 1024) {
                int l = t ^ j;
                if (l > t) {
                    float vt = sv[t], vl = sv[l];
                    int it = si[t], il = si[l];
                    bool l_before_t = (vl > vt) || (vl == vt && il < it);
                    bool dir = ((t & k) == 0);
                    if (dir == l_before_t) {
                        sv[t] = vl; sv[l] = vt;
                        si[t] = il; si[l] = it;
                    }
                }
            }
            __syncthreads();
        }
    }

    // ---- phase A: box decode + roi coords + valid ballot ----
    if (tid < 320) {
        float x1 = 0.f, y1 = 0.f, x2 = 0.f, y2 = 0.f;
        bool v = false;
        if (tid < NTOP) {
            float wf = decode_dim(wp_), hf = decode_dim(hp_);
            int id = si[tid];
            float p0 = preb[id * 4 + 0], p1 = preb[id * 4 + 1];
            float p2 = preb[id * 4 + 2], p3 = preb[id * 4 + 3];
            x1 = fmaxf(p2 - p0 * 0.5f, 0.0f);
            y1 = fmaxf(p3 - p1 * 0.5f, 0.0f);
            x2 = fminf(p2 + p0, wf);
            y2 = fminf(p3 + p1, hf);
            v = sv[tid] > 0.5f;
            float bx1 = x1 * 0.0625f, by1 = y1 * 0.0625f;
            float bx2 = x2 * 0.0625f, by2 = y2 * 0.0625f;
            #pragma unroll
            for (int m = 0; m < 14; ++m) {
                int i = m >> 1, s = m & 1;
                float frac = ((float)i + (s ? 0.75f : 0.25f)) / 7.0f;
                float xs = bx1 + frac * (bx2 - bx1);
                float ys = by1 + frac * (by2 - by1);
                float fx = floorf(xs); fx = fminf(fmaxf(fx, 0.0f), 49.0f);
                float fy = floorf(ys); fy = fminf(fmaxf(fy, 0.0f), 49.0f);
                ixb[tid * 14 + m] = (int)fx;
                iyb[tid * 14 + m] = (int)fy;
            }
        }
        X1[tid] = x1; Y1[tid] = y1; X2[tid] = x2; Y2[tid] = y2;
        AR[tid] = fmaxf(x2 - x1, 0.0f) * fmaxf(y2 - y1, 0.0f);
        unsigned long long vb = __ballot(v);
        if (lane == 0) KEEPW[w] = vb;
    }
    __syncthreads();

    // ---- phase B: per-i suppression masks ----
    if (tid < 320) {
        float xi1 = X1[tid], yi1 = Y1[tid], xi2 = X2[tid], yi2 = Y2[tid], ai = AR[tid];
        #pragma unroll
        for (int jw = 0; jw < 5; ++jw) {
            unsigned long long mword = 0ull;
            #pragma unroll 4
            for (int j2 = 0; j2 < 64; ++j2) {
                int j = jw * 64 + j2;
                float ix1 = fmaxf(xi1, X1[j]);
                float iy1 = fmaxf(yi1, Y1[j]);
                float ix2 = fminf(xi2, X2[j]);
                float iy2 = fminf(yi2, Y2[j]);
                float inter = fmaxf(ix2 - ix1, 0.0f) * fmaxf(iy2 - iy1, 0.0f);
                float iou = inter / fmaxf(ai + AR[j] - inter, 1e-6f);
                bool sup = (iou > 0.7f) && (j > tid) && (j < NTOP);
                mword |= sup ? (1ull << j2) : 0ull;
            }
            MASK[tid][jw] = mword;
        }
    }
    __syncthreads();

    // ---- phase C: serial scan, wave 0, all in registers ----
    if (tid < 64) {
        unsigned long long m[5][5];
        #pragma unroll
        for (int g = 0; g < 5; ++g)
            #pragma unroll
            for (int q = 0; q < 5; ++q)
                m[g][q] = MASK[g * 64 + lane][q];
        unsigned long long kw0 = KEEPW[0], kw1 = KEEPW[1], kw2 = KEEPW[2],
                           kw3 = KEEPW[3], kw4 = KEEPW[4];
        #pragma unroll
        for (int g = 0; g < 5; ++g) {
            for (int i2 = 0; i2 < 64; ++i2) {
                unsigned long long kg = (g == 0) ? kw0 : (g == 1) ? kw1 :
                                        (g == 2) ? kw2 : (g == 3) ? kw3 : kw4;
                bool alive = (kg >> i2) & 1ull;
                unsigned long long b0 = __shfl(m[g][0], i2, 64);
                unsigned long long b1 = __shfl(m[g][1], i2, 64);
                unsigned long long b2 = __shfl(m[g][2], i2, 64);
                unsigned long long b3 = __shfl(m[g][3], i2, 64);
                unsigned long long b4 = __shfl(m[g][4], i2, 64);
                if (alive) {
                    kw0 &= ~b0; kw1 &= ~b1; kw2 &= ~b2; kw3 &= ~b3; kw4 &= ~b4;
                }
            }
        }
        #pragma unroll
        for (int g = 0; g < 5; ++g) {
            unsigned long long kg = (g == 0) ? kw0 : (g == 1) ? kw1 :
                                    (g == 2) ? kw2 : (g == 3) ? kw3 : kw4;
            int j = g * 64 + lane;
            if (j < NTOP) keep[j] = (int)((kg >> lane) & 1ull);
        }
    }
}

// ---------------- 7. ROI max pool -> A fragments (f16, MFMA per-lane layout) -
__global__ void __launch_bounds__(256)
roipool_frag(const float* __restrict__ fpad, const int* __restrict__ ixb,
             const int* __restrict__ iyb, _Float16* __restrict__ Af) {
    int wid = blockIdx.x * 256 + threadIdx.x;
    if (wid >= MT * KG1 * 64) return;
    int l = wid & 63;
    int g = (wid >> 6) % KG1;
    int T = wid / (KG1 * 64);
    int mm = T * 16 + (l & 15);
    int kbase = g * 32 + ((l >> 4) & 3) * 8;
    union { _Float16 h[8]; uint4 u; } o;
    if (mm < NTOP) {
        const int* ix = ixb + mm * 14;
        const int* iy = iyb + mm * 14;
        #pragma unroll
        for (int e = 0; e < 8; ++e) {
            int k = kbase + e;
            int c = k / 49, ij = k % 49, i = ij / 7, jx = ij % 7;
            int y0 = iy[2 * i] + 1, y1 = iy[2 * i + 1] + 1;
            int x0 = ix[2 * jx] + 1, x1 = ix[2 * jx + 1] + 1;
            const float* f = fpad + (size_t)c * FPSTRIDE;
            float v = fmaxf(fmaxf(f[y0 * 64 + x0], f[y0 * 64 + x1]),
                            fmaxf(f[y1 * 64 + x0], f[y1 * 64 + x1]));
            o.h[e] = (_Float16)v;
        }
    } else {
        o.u.x = 0u; o.u.y = 0u; o.u.z = 0u; o.u.w = 0u;
    }
    *(uint4*)(Af + (size_t)wid * 8) = o.u;
}

// ---------------- 8. full-M MFMA GEMM, double-buffered B (1 barrier/K-step) --
__global__ void __launch_bounds__(512)
gemm_fullm(const _Float16* __restrict__ Af, const float* __restrict__ B,
           float* __restrict__ part, int K, int KG, int kchunk) {
    __shared__ char Bs[2][64 * 128];   // 64 rows x 64 f16, swizzled
    int tid = threadIdx.x;
    int lane = tid & 63;
    int w = tid >> 6;
    int wm = w & 3, wn = w >> 2;
    int n0 = blockIdx.x * 64;
    int ks = blockIdx.y * kchunk;
    int nt = kchunk >> 6;

    f32x4 acc[5][2];
    #pragma unroll
    for (int tm = 0; tm < 5; ++tm)
        #pragma unroll
        for (int tn = 0; tn < 2; ++tn)
            acc[tm][tn] = f32x4{0.f, 0.f, 0.f, 0.f};

    int srow = tid >> 3;          // 0..63
    int skp  = (tid & 7) * 8;     // 0..56
    const float* bsrc = B + (size_t)(n0 + srow) * K + ks + skp;
    int sboff = srow * 128 + ((skp * 2) ^ ((srow & 7) << 4));

    float4 v0 = *(const float4*)(bsrc);
    float4 v1 = *(const float4*)(bsrc + 4);
    {
        union { _Float16 h[8]; uint4 u; } cv;
        cv.h[0] = (_Float16)v0.x; cv.h[1] = (_Float16)v0.y;
        cv.h[2] = (_Float16)v0.z; cv.h[3] = (_Float16)v0.w;
        cv.h[4] = (_Float16)v1.x; cv.h[5] = (_Float16)v1.y;
        cv.h[6] = (_Float16)v1.z; cv.h[7] = (_Float16)v1.w;
        *(uint4*)(Bs[0] + sboff) = cv.u;
    }
    if (nt > 1) {
        v0 = *(const float4*)(bsrc + 64);
        v1 = *(const float4*)(bsrc + 68);
    }
    __syncthreads();

    for (int k0 = 0; k0 < nt; ++k0) {
        const char* cur = Bs[k0 & 1];
        if (k0 + 1 < nt) {
            union { _Float16 h[8]; uint4 u; } cv;
            cv.h[0] = (_Float16)v0.x; cv.h[1] = (_Float16)v0.y;
            cv.h[2] = (_Float16)v0.z; cv.h[3] = (_Float16)v0.w;
            cv.h[4] = (_Float16)v1.x; cv.h[5] = (_Float16)v1.y;
            cv.h[6] = (_Float16)v1.z; cv.h[7] = (_Float16)v1.w;
            *(uint4*)(Bs[(k0 + 1) & 1] + sboff) = cv.u;
            if (k0 + 2 < nt) {
                v0 = *(const float4*)(bsrc + (k0 + 2) * 64);
                v1 = *(const float4*)(bsrc + (k0 + 2) * 64 + 4);
            }
        }
        #pragma unroll
        for (int kk = 0; kk < 2; ++kk) {
            int g = (ks + k0 * 64 + kk * 32) >> 5;
            f16x8 bfr[2];
            #pragma unroll
            for (int tn = 0; tn < 2; ++tn) {
                int row = wn * 32 + tn * 16 + (lane & 15);
                int kb = kk * 64 + (lane >> 4) * 16;
                bfr[tn] = *(const f16x8*)(cur + row * 128 + (kb ^ ((row & 7) << 4)));
            }
            #pragma unroll
            for (int tm = 0; tm < 5; ++tm) {
                int T = wm * 5 + tm;
                f16x8 a = *(const f16x8*)(Af + ((size_t)(T * KG + g) * 64 + lane) * 8);
                #pragma unroll
                for (int tn = 0; tn < 2; ++tn)
                    acc[tm][tn] = __builtin_amdgcn_mfma_f32_16x16x32_f16(a, bfr[tn], acc[tm][tn], 0, 0, 0);
            }
        }
        __syncthreads();
    }
    float* pout = part + (size_t)blockIdx.y * (NTOP * FCN);
    #pragma unroll
    for (int tm = 0; tm < 5; ++tm) {
        int mbase = (wm * 5 + tm) * 16 + (lane >> 4) * 4;
        #pragma unroll
        for (int j = 0; j < 4; ++j) {
            int m = mbase + j;
            if (m < NTOP) {
                #pragma unroll
                for (int tn = 0; tn < 2; ++tn) {
                    int n = n0 + wn * 32 + tn * 16 + (lane & 15);
                    pout[(size_t)m * FCN + n] = acc[tm][tn][j];
                }
            }
        }
    }
}

// ---------------- 8b. reduce fc1 partials + bias + relu -> h1 fragments f16 --
__global__ void reduce_fc1(const float* __restrict__ part, const float* __restrict__ bias,
                           _Float16* __restrict__ h1f, int ns) {
    int i = blockIdx.x * 256 + threadIdx.x;     // 300*512
    if (i >= NTOP * 512) return;
    int m = i >> 9;
    int f = (i & 511) * 8;
    float s[8];
    const float* p0 = part + (size_t)m * FCN + f;
    #pragma unroll
    for (int e = 0; e < 8; ++e) s[e] = p0[e];
    for (int z = 1; z < ns; ++z) {
        const float* pz = p0 + (size_t)z * (NTOP * FCN);
        #pragma unroll
        for (int e = 0; e < 8; ++e) s[e] += pz[e];
    }
    union { _Float16 h[8]; uint4 u; } o;
    #pragma unroll
    for (int e = 0; e < 8; ++e) o.h[e] = (_Float16)fmaxf(s[e] + bias[f + e], 0.0f);
    int T = m >> 4, g = f >> 5, l = (m & 15) + 16 * ((f >> 3) & 3);
    *(uint4*)(h1f + ((size_t)(T * KG2 + g) * 64 + l) * 8) = o.u;
}

// ---------------- 8c. reduce fc2 partials + bias + relu -> h2 f32 ----------
__global__ void reduce_fc2(const float* __restrict__ part, const float* __restrict__ bias,
                           float* __restrict__ outp, int ns) {
    size_t i = (size_t)blockIdx.x * 256 + threadIdx.x;    // float4 index
    size_t mn4 = (size_t)NTOP * FCN / 4;
    if (i >= mn4) return;
    float4 s = *(const float4*)(part + i * 4);
    for (int zz = 1; zz < ns; ++zz) {
        float4 v = *(const float4*)(part + (size_t)zz * (NTOP * FCN) + i * 4);
        s.x += v.x; s.y += v.y; s.z += v.z; s.w += v.w;
    }
    int n = (int)((i * 4) % FCN);
    float4 b = *(const float4*)(bias + n);
    s.x = fmaxf(s.x + b.x, 0.f); s.y = fmaxf(s.y + b.y, 0.f);
    s.z = fmaxf(s.z + b.z, 0.f); s.w = fmaxf(s.w + b.w, 0.f);
    *(float4*)(outp + i * 4) = s;
}

// ---------------- 9. final heads: wave per output + keep mask ----------------
__global__ void __launch_bounds__(256)
final_k(const float* __restrict__ h2, const float* __restrict__ clsw,
        const float* __restrict__ clsb, const float* __restrict__ boxw,
        const float* __restrict__ boxb, const int* __restrict__ keep,
        float* __restrict__ out) {
    int gid = blockIdx.x * 4 + (threadIdx.x >> 6);
    if (gid >= NTOP * 25) return;
    int lane = threadIdx.x & 63;
    int k = gid / 25, o = gid % 25;
    const float* w;
    float b;
    if (o < 21) { w = clsw + (size_t)o * 4096; b = clsb[o]; }
    else        { w = boxw + (size_t)(o - 21) * 4096; b = boxb[o - 21]; }
    const float* h = h2 + (size_t)k * 4096;
    float s = 0.0f;
    #pragma unroll
    for (int i = 0; i < 16; ++i) {
        float4 hv = *(const float4*)(h + (i * 64 + lane) * 4);
        float4 wv = *(const float4*)(w + (i * 64 + lane) * 4);
        s += hv.x * wv.x + hv.y * wv.y + hv.z * wv.z + hv.w * wv.w;
    }
    #pragma unroll
    for (int off = 1; off < 64; off <<= 1) s += __shfl_xor(s, off, 64);
    if (lane == 0) out[gid] = keep[k] ? (s + b) : 0.0f;
}

// ---------------- launch ----------------
extern "C" void kernel_launch(void* const* d_in, const int* in_sizes, int n_in,
                              void* d_out, int out_size, void* d_ws, size_t ws_size,
                              hipStream_t stream) {
    const float* x    = (const float*)d_in[0];
    const float* Wf   = (const float*)d_in[2];
    const float* bf   = (const float*)d_in[3];
    const float* W1   = (const float*)d_in[4];
    const float* b1   = (const float*)d_in[5];
    const float* Wc   = (const float*)d_in[6];
    const float* bc   = (const float*)d_in[7];
    const float* Wb   = (const float*)d_in[8];
    const float* bb   = (const float*)d_in[9];
    const float* fc1w = (const float*)d_in[10];
    const float* fc1b = (const float*)d_in[11];
    const float* fc2w = (const float*)d_in[12];
    const float* fc2b = (const float*)d_in[13];
    const float* clsw = (const float*)d_in[14];
    const float* clsb = (const float*)d_in[15];
    const float* boxw = (const float*)d_in[16];
    const float* boxb = (const float*)d_in[17];
    const void*  wp   = d_in[18];
    const void*  hp   = d_in[19];

    char* ws = (char*)d_ws;
    float*     fpad  = (float*)(ws + OFF_FPAD);
    float*     score = (float*)(ws + OFF_SCORE);
    float*     preb  = (float*)(ws + OFF_PREB);
    int*       keep  = (int*)(ws + OFF_KEEP);
    int*       ixb   = (int*)(ws + OFF_IX);
    int*       iyb   = (int*)(ws + OFF_IY);
    _Float16*  Af    = (_Float16*)(ws + OFF_AFRAG);
    _Float16*  h1f   = (_Float16*)(ws + OFF_H1F);
    float*     h2    = (float*)(ws + OFF_H2);
    float*     w1t   = (float*)(ws + OFF_W1T);
    float*     out   = (float*)d_out;

    // split-K slots + conv-partial split, guarded by ws_size
    size_t slot = (size_t)NTOP * FCN * 4;   // 4.9 MB
    size_t avail = ws_size > OFF_PART ? (ws_size - OFF_PART) / slot : 0;
    int ns1 = (avail >= 7) ? 7 : (avail >= 4) ? 4 : (avail >= 2) ? 2 : 1;
    int ns2 = (avail >= 4) ? 4 : (avail >= 2) ? 2 : 1;
    float* part1 = (avail >= 1) ? (float*)(ws + OFF_PART) : h2;              // h2 free during fc1
    float* part2 = (avail >= 1) ? (float*)(ws + OFF_PART) : (float*)Af;      // Af free after fc1
    int kch1 = (196 / ns1) * 64;
    int kch2 = (64 / ns2) * 64;
    // conv ci-split: 8-way partials (20.5 MB) share OFF_PART (time-disjoint with fc partials)
    int zs = (avail >= 5) ? 8 : 4;
    float* cpart = (avail >= 5) ? (float*)(ws + OFF_PART) : (float*)(ws + OFF_AFRAG);

    zero_fpad<<<832, 256, 0, stream>>>(fpad);
    patch_conv<<<dim3(10, 64), 256, 0, stream>>>(x, Wf, bf, fpad);
    transpose_w1<<<(2304 * 256 + 255) / 256, 256, 0, stream>>>(W1, w1t);
    conv3x3_part<<<dim3(7, 50, zs), 256, 0, stream>>>(fpad, w1t, cpart, 256 / zs);
    reducehead_k<<<625, 256, 0, stream>>>(cpart, b1, Wc, bc, Wb, bb, score, preb, zs);
    topknms_k<<<1, 1024, 0, stream>>>(score, preb, wp, hp, keep, ixb, iyb);
    roipool_frag<<<(MT * KG1 * 64 + 255) / 256, 256, 0, stream>>>(fpad, ixb, iyb, Af);
    gemm_fullm<<<dim3(64, ns1), 512, 0, stream>>>(Af, fc1w, part1, DFLAT, KG1, kch1);
    reduce_fc1<<<(NTOP * 512 + 255) / 256, 256, 0, stream>>>(part1, fc1b, h1f, ns1);
    gemm_fullm<<<dim3(64, ns2), 512, 0, stream>>>(h1f, fc2w, part2, FCN, KG2, kch2);
    reduce_fc2<<<(NTOP * FCN / 4 + 255) / 256, 256, 0, stream>>>(part2, fc2b, h2, ns2);
    final_k<<<(NTOP * 25 + 3) / 4, 256, 0, stream>>>(h2, clsw, clsb, boxw, boxb, keep, out);
}

// Round 8
// 357.758 us; speedup vs baseline: 5.6215x; 1.1407x over previous
//
#include <hip/hip_runtime.h>
#include <hip/hip_bf16.h>
#include <math.h>

// ---------------- problem constants ----------------
#define NPIX   2500      // 50*50
#define CFEAT  256
#define NTOP   300
#define DFLAT  12544     // 256*7*7
#define FCN    4096
#define FPSTRIDE 3328    // 52 rows * 64 floats per channel (padded feature)
#define KG1    392       // DFLAT/32
#define KG2    128       // FCN/32
#define MT     20        // m-tiles (320 rows padded)

typedef _Float16 f16x8 __attribute__((ext_vector_type(8)));
typedef float    f32x4 __attribute__((ext_vector_type(4)));

// ---------------- workspace offsets (bytes) ----------------
static constexpr size_t OFF_FPAD  = 0;          // 3.4 MB
static constexpr size_t OFF_SCORE = 0x5C0000;
static constexpr size_t OFF_PREB  = 0x5D0000;
static constexpr size_t OFF_KEEP  = 0x5E5000;
static constexpr size_t OFF_IX    = 0x5E6000;
static constexpr size_t OFF_IY    = 0x5EB000;
static constexpr size_t OFF_AFRAG = 0x600000;   // A fragments f16, 8.03 MB (ends 0xDA8000)
static constexpr size_t OFF_H1F   = 0xE00000;   // h1 fragments f16, 2.62 MB
static constexpr size_t OFF_H2    = 0x1100000;  // h2 f32, 4.9 MB
static constexpr size_t OFF_W1T   = 0x1600000;  // 2.36 MB transient
static constexpr size_t OFF_PART  = 0x1900000;  // cpart (20.5 MB) then split-K partials (34.3 MB), time-disjoint

__device__ inline float decode_dim(const void* p) {
    int iv = *(const int*)p;
    if (iv > 0 && iv < (1 << 20)) return (float)iv;
    return __int_as_float(iv);
}

// ---------------- 0. zero the padded feature buffer ----------------
__global__ void zero_fpad(float* __restrict__ fpad) {
    int i = blockIdx.x * 256 + threadIdx.x;   // float4 index, 256*3328/4 = 212992
    if (i < 212992) *(float4*)(fpad + (size_t)i * 4) = make_float4(0.f, 0.f, 0.f, 0.f);
}

// ---------------- 1. patchify conv: 16x16 stride16 VALID -> padded feat -----
__global__ void __launch_bounds__(256)
patch_conv(const float* __restrict__ x, const float* __restrict__ Wf,
           const float* __restrict__ bf, float* __restrict__ fpad) {
    __shared__ float w[3072];          // 4 co x 768
    int co0 = blockIdx.y * 4;
    for (int t = threadIdx.x; t < 3072; t += 256) w[t] = Wf[co0 * 768 + t];
    __syncthreads();
    int p = blockIdx.x * 256 + threadIdx.x;
    if (p >= NPIX) return;
    int py = p / 50, px = p % 50;
    float acc[4];
    #pragma unroll
    for (int c = 0; c < 4; ++c) acc[c] = bf[co0 + c];
    for (int ci = 0; ci < 3; ++ci) {
        const float* xp = x + ci * 640000 + (py * 16) * 800 + px * 16;
        #pragma unroll
        for (int ky = 0; ky < 16; ++ky) {
            const float* row = xp + ky * 800;
            #pragma unroll
            for (int kq = 0; kq < 4; ++kq) {
                float4 xv = *reinterpret_cast<const float4*>(row + kq * 4);
                int kb = ci * 256 + ky * 16 + kq * 4;
                #pragma unroll
                for (int c = 0; c < 4; ++c) {
                    const float* wc = w + c * 768 + kb;
                    acc[c] += xv.x * wc[0] + xv.y * wc[1] + xv.z * wc[2] + xv.w * wc[3];
                }
            }
        }
    }
    size_t o = (size_t)(py + 1) * 64 + (px + 1);
    #pragma unroll
    for (int c = 0; c < 4; ++c) fpad[(size_t)(co0 + c) * FPSTRIDE + o] = acc[c];
}

// ---------------- 1b. transpose W1 -> (ci*9+j, co) ----------------
__global__ void transpose_w1(const float* __restrict__ W1, float* __restrict__ W1t) {
    int idx = blockIdx.x * 256 + threadIdx.x;
    if (idx >= 2304 * 256) return;
    int r = idx >> 8, co = idx & 255;
    W1t[idx] = W1[co * 2304 + r];
}

// ---------------- 2. 3x3 SAME conv partials (lanes=co, 8-pixel batch, ci split) --
__global__ void __launch_bounds__(256)
conv3x3_part(const float* __restrict__ fpad, const float* __restrict__ W1t,
             float* __restrict__ cpart, int zci) {
    int co = threadIdx.x;
    int xb = blockIdx.x * 8;          // 0,8,...,48
    int y  = blockIdx.y;              // 0..49
    int z  = blockIdx.z;
    float acc[8];
    #pragma unroll
    for (int p = 0; p < 8; ++p) acc[p] = 0.0f;
    const float* fp = fpad + (size_t)(z * zci) * FPSTRIDE + (size_t)y * 64 + xb;
    const float* wp = W1t + (size_t)(z * zci) * 9 * 256 + co;
    #pragma unroll 2
    for (int ci = 0; ci < zci; ++ci) {
        float v[3][12];
        #pragma unroll
        for (int dy = 0; dy < 3; ++dy) {
            #pragma unroll
            for (int q = 0; q < 3; ++q) {
                float4 r4 = *(const float4*)(fp + dy * 64 + q * 4);
                v[dy][q * 4 + 0] = r4.x; v[dy][q * 4 + 1] = r4.y;
                v[dy][q * 4 + 2] = r4.z; v[dy][q * 4 + 3] = r4.w;
            }
        }
        float wv[9];
        #pragma unroll
        for (int k = 0; k < 9; ++k) wv[k] = wp[k * 256];
        #pragma unroll
        for (int dy = 0; dy < 3; ++dy)
            #pragma unroll
            for (int dx = 0; dx < 3; ++dx) {
                float wvv = wv[dy * 3 + dx];
                #pragma unroll
                for (int p = 0; p < 8; ++p)
                    acc[p] += v[dy][p + dx] * wvv;
            }
        fp += FPSTRIDE;
        wp += 9 * 256;
    }
    size_t base = (size_t)z * (NPIX * 256) + (size_t)(y * 50 + xb) * 256 + co;
    #pragma unroll
    for (int p = 0; p < 8; ++p)
        if (xb + p < 50) cpart[base + (size_t)p * 256] = acc[p];
}

// ---------------- 2b+3. fused: reduce conv partials + bias + relu + heads ---
__global__ void __launch_bounds__(256)
reducehead_k(const float* __restrict__ cpart, const float* __restrict__ b1,
             const float* __restrict__ Wc, const float* __restrict__ bc,
             const float* __restrict__ Wb, const float* __restrict__ bb,
             float* __restrict__ score, float* __restrict__ preb, int zs) {
    int lane = threadIdx.x & 63;
    int p = blockIdx.x * 4 + (threadIdx.x >> 6);
    if (p >= NPIX) return;
    size_t off = (size_t)p * 256 + lane * 4;
    float4 h = *(const float4*)(cpart + off);
    for (int z = 1; z < zs; ++z) {
        float4 v = *(const float4*)(cpart + (size_t)z * (NPIX * 256) + off);
        h.x += v.x; h.y += v.y; h.z += v.z; h.w += v.w;
    }
    float4 b = *(const float4*)(b1 + lane * 4);
    h.x = fmaxf(h.x + b.x, 0.f); h.y = fmaxf(h.y + b.y, 0.f);
    h.z = fmaxf(h.z + b.z, 0.f); h.w = fmaxf(h.w + b.w, 0.f);
    float4 c0 = *(const float4*)(Wc + lane * 4);
    float4 c1 = *(const float4*)(Wc + 256 + lane * 4);
    float4 w0 = *(const float4*)(Wb + lane * 4);
    float4 w1 = *(const float4*)(Wb + 256 + lane * 4);
    float4 w2 = *(const float4*)(Wb + 512 + lane * 4);
    float4 w3 = *(const float4*)(Wb + 768 + lane * 4);
    float s[6];
    s[0] = h.x*c0.x + h.y*c0.y + h.z*c0.z + h.w*c0.w;
    s[1] = h.x*c1.x + h.y*c1.y + h.z*c1.z + h.w*c1.w;
    s[2] = h.x*w0.x + h.y*w0.y + h.z*w0.z + h.w*w0.w;
    s[3] = h.x*w1.x + h.y*w1.y + h.z*w1.z + h.w*w1.w;
    s[4] = h.x*w2.x + h.y*w2.y + h.z*w2.z + h.w*w2.w;
    s[5] = h.x*w3.x + h.y*w3.y + h.z*w3.z + h.w*w3.w;
    #pragma unroll
    for (int o = 1; o < 64; o <<= 1) {
        #pragma unroll
        for (int q = 0; q < 6; ++q) s[q] += __shfl_xor(s[q], o, 64);
    }
    if (lane == 0) {
        float s0 = s[0] + bc[0], s1 = s[1] + bc[1];
        float m = fmaxf(s0, s1);
        float e0 = expf(s0 - m), e1 = expf(s1 - m);
        score[p] = e1 / (e0 + e1);
        preb[p * 4 + 0] = s[2] + bb[0];
        preb[p * 4 + 1] = s[3] + bb[1];
        preb[p * 4 + 2] = s[4] + bb[2];
        preb[p * 4 + 3] = s[5] + bb[3];
    }
}

// ---------------- 4+5+6. fused radix-select top-k + box decode + bitmask NMS --
// key = (score_bits << 32) | ~idx : unique, desc order == (score desc, idx asc)
__global__ void __launch_bounds__(1024)
topknms_k(const float* __restrict__ score, const float* __restrict__ preb,
          const void* wp_, const void* hp_, int* __restrict__ keep,
          int* __restrict__ ixb, int* __restrict__ iyb) {
    __shared__ unsigned long long KEYS[NPIX];
    __shared__ unsigned int hist[256];
    __shared__ int sh_digit, sh_newr, cnt;
    __shared__ unsigned long long SEL[NTOP];
    __shared__ unsigned long long SORT[NTOP];
    __shared__ float X1[320], Y1[320], X2[320], Y2[320], AR[320];
    __shared__ unsigned long long MASK[320][5];
    __shared__ unsigned long long KEEPW[5];
    int tid = threadIdx.x;
    int lane = tid & 63;
    int w = tid >> 6;

    // ---- build keys ----
    for (int e = tid; e < NPIX; e += 1024) {
        unsigned sb = __float_as_uint(score[e]);   // scores >= 0 -> uint order ok
        KEYS[e] = ((unsigned long long)sb << 32) | (unsigned)(~e);
    }
    if (tid == 0) cnt = 0;
    __syncthreads();

    // ---- 8-pass MSB radix select: find exact 300th-largest key T ----
    unsigned long long P = 0ull, M = 0ull;
    int r = NTOP;
    for (int pass = 0; pass < 8; ++pass) {
        int shift = 56 - 8 * pass;
        if (tid < 256) hist[tid] = 0u;
        __syncthreads();
        for (int e = tid; e < NPIX; e += 1024) {
            unsigned long long k = KEYS[e];
            if ((k & M) == P)
                atomicAdd(&hist[(unsigned)(k >> shift) & 255u], 1u);
        }
        __syncthreads();
        if (tid < 64) {
            unsigned c0 = hist[tid * 4 + 0], c1 = hist[tid * 4 + 1];
            unsigned c2 = hist[tid * 4 + 2], c3 = hist[tid * 4 + 3];
            unsigned sl = c0 + c1 + c2 + c3;
            unsigned suf = sl;
            #pragma unroll
            for (int off = 1; off < 64; off <<= 1) {
                unsigned o = __shfl_down(suf, off, 64);
                if (lane + off < 64) suf += o;
            }
            unsigned G = suf - sl;          // count of digits in lanes above
            if (G < (unsigned)r && G + sl >= (unsigned)r) {
                unsigned above = G;
                unsigned cc[4] = {c0, c1, c2, c3};
                int d = 0; unsigned ab = above;
                #pragma unroll
                for (int i = 3; i >= 0; --i) {
                    if (ab < (unsigned)r && ab + cc[i] >= (unsigned)r) { d = tid * 4 + i; break; }
                    ab += cc[i];
                }
                sh_digit = d;
                sh_newr = r - (int)ab;
            }
        }
        __syncthreads();
        P |= ((unsigned long long)(unsigned)sh_digit) << shift;
        M |= 0xFFull << shift;
        r = sh_newr;
    }
    unsigned long long T = P;

    // ---- compact the exactly-300 keys >= T (unordered) ----
    for (int e = tid; e < NPIX; e += 1024) {
        unsigned long long k = KEYS[e];
        if (k >= T) {
            int s = atomicAdd(&cnt, 1);
            SEL[s] = k;
        }
    }
    __syncthreads();

    // ---- rank by counting (broadcast LDS reads), scatter to sorted order ----
    if (tid < NTOP) {
        unsigned long long mine = SEL[tid];
        int rank = 0;
        for (int j = 0; j < NTOP; ++j) rank += (SEL[j] > mine) ? 1 : 0;
        SORT[rank] = mine;
    }
    __syncthreads();

    // ---- phase A: box decode + roi coords + valid ballot ----
    if (tid < 320) {
        float x1 = 0.f, y1 = 0.f, x2 = 0.f, y2 = 0.f;
        bool v = false;
        if (tid < NTOP) {
            unsigned long long key = SORT[tid];
            int id = (int)(~(unsigned)key);
            float sc = __uint_as_float((unsigned)(key >> 32));
            float wf = decode_dim(wp_), hf = decode_dim(hp_);
            float p0 = preb[id * 4 + 0], p1 = preb[id * 4 + 1];
            float p2 = preb[id * 4 + 2], p3 = preb[id * 4 + 3];
            x1 = fmaxf(p2 - p0 * 0.5f, 0.0f);
            y1 = fmaxf(p3 - p1 * 0.5f, 0.0f);
            x2 = fminf(p2 + p0, wf);
            y2 = fminf(p3 + p1, hf);
            v = sc > 0.5f;
            float bx1 = x1 * 0.0625f, by1 = y1 * 0.0625f;
            float bx2 = x2 * 0.0625f, by2 = y2 * 0.0625f;
            #pragma unroll
            for (int m = 0; m < 14; ++m) {
                int i = m >> 1, s = m & 1;
                float frac = ((float)i + (s ? 0.75f : 0.25f)) / 7.0f;
                float xs = bx1 + frac * (bx2 - bx1);
                float ys = by1 + frac * (by2 - by1);
                float fx = floorf(xs); fx = fminf(fmaxf(fx, 0.0f), 49.0f);
                float fy = floorf(ys); fy = fminf(fmaxf(fy, 0.0f), 49.0f);
                ixb[tid * 14 + m] = (int)fx;
                iyb[tid * 14 + m] = (int)fy;
            }
        }
        X1[tid] = x1; Y1[tid] = y1; X2[tid] = x2; Y2[tid] = y2;
        AR[tid] = fmaxf(x2 - x1, 0.0f) * fmaxf(y2 - y1, 0.0f);
        unsigned long long vb = __ballot(v);
        if (lane == 0 && w < 5) KEEPW[w] = vb;
    }
    __syncthreads();

    // ---- phase B: per-i suppression masks ----
    if (tid < 320) {
        float xi1 = X1[tid], yi1 = Y1[tid], xi2 = X2[tid], yi2 = Y2[tid], ai = AR[tid];
        #pragma unroll
        for (int jw = 0; jw < 5; ++jw) {
            unsigned long long mword = 0ull;
            #pragma unroll 4
            for (int j2 = 0; j2 < 64; ++j2) {
                int j = jw * 64 + j2;
                float ix1 = fmaxf(xi1, X1[j]);
                float iy1 = fmaxf(yi1, Y1[j]);
                float ix2 = fminf(xi2, X2[j]);
                float iy2 = fminf(yi2, Y2[j]);
                float inter = fmaxf(ix2 - ix1, 0.0f) * fmaxf(iy2 - iy1, 0.0f);
                float iou = inter / fmaxf(ai + AR[j] - inter, 1e-6f);
                bool sup = (iou > 0.7f) && (j > tid) && (j < NTOP);
                mword |= sup ? (1ull << j2) : 0ull;
            }
            MASK[tid][jw] = mword;
        }
    }
    __syncthreads();

    // ---- phase C: serial scan, wave 0, all in registers ----
    if (tid < 64) {
        unsigned long long m[5][5];
        #pragma unroll
        for (int g = 0; g < 5; ++g)
            #pragma unroll
            for (int q = 0; q < 5; ++q)
                m[g][q] = MASK[g * 64 + lane][q];
        unsigned long long kw0 = KEEPW[0], kw1 = KEEPW[1], kw2 = KEEPW[2],
                           kw3 = KEEPW[3], kw4 = KEEPW[4];
        #pragma unroll
        for (int g = 0; g < 5; ++g) {
            for (int i2 = 0; i2 < 64; ++i2) {
                unsigned long long kg = (g == 0) ? kw0 : (g == 1) ? kw1 :
                                        (g == 2) ? kw2 : (g == 3) ? kw3 : kw4;
                bool alive = (kg >> i2) & 1ull;
                unsigned long long b0 = __shfl(m[g][0], i2, 64);
                unsigned long long b1 = __shfl(m[g][1], i2, 64);
                unsigned long long b2 = __shfl(m[g][2], i2, 64);
                unsigned long long b3 = __shfl(m[g][3], i2, 64);
                unsigned long long b4 = __shfl(m[g][4], i2, 64);
                if (alive) {
                    kw0 &= ~b0; kw1 &= ~b1; kw2 &= ~b2; kw3 &= ~b3; kw4 &= ~b4;
                }
            }
        }
        #pragma unroll
        for (int g = 0; g < 5; ++g) {
            unsigned long long kg = (g == 0) ? kw0 : (g == 1) ? kw1 :
                                    (g == 2) ? kw2 : (g == 3) ? kw3 : kw4;
            int j = g * 64 + lane;
            if (j < NTOP) keep[j] = (int)((kg >> lane) & 1ull);
        }
    }
}

// ---------------- 7. ROI max pool -> A fragments (f16, MFMA per-lane layout) -
__global__ void __launch_bounds__(256)
roipool_frag(const float* __restrict__ fpad, const int* __restrict__ ixb,
             const int* __restrict__ iyb, _Float16* __restrict__ Af) {
    int wid = blockIdx.x * 256 + threadIdx.x;
    if (wid >= MT * KG1 * 64) return;
    int l = wid & 63;
    int g = (wid >> 6) % KG1;
    int T = wid / (KG1 * 64);
    int mm = T * 16 + (l & 15);
    int kbase = g * 32 + ((l >> 4) & 3) * 8;
    union { _Float16 h[8]; uint4 u; } o;
    if (mm < NTOP) {
        const int* ix = ixb + mm * 14;
        const int* iy = iyb + mm * 14;
        #pragma unroll
        for (int e = 0; e < 8; ++e) {
            int k = kbase + e;
            int c = k / 49, ij = k % 49, i = ij / 7, jx = ij % 7;
            int y0 = iy[2 * i] + 1, y1 = iy[2 * i + 1] + 1;
            int x0 = ix[2 * jx] + 1, x1 = ix[2 * jx + 1] + 1;
            const float* f = fpad + (size_t)c * FPSTRIDE;
            float v = fmaxf(fmaxf(f[y0 * 64 + x0], f[y0 * 64 + x1]),
                            fmaxf(f[y1 * 64 + x0], f[y1 * 64 + x1]));
            o.h[e] = (_Float16)v;
        }
    } else {
        o.u.x = 0u; o.u.y = 0u; o.u.z = 0u; o.u.w = 0u;
    }
    *(uint4*)(Af + (size_t)wid * 8) = o.u;
}

// ---------------- 8. full-M MFMA GEMM, double-buffered B (1 barrier/K-step) --
__global__ void __launch_bounds__(512)
gemm_fullm(const _Float16* __restrict__ Af, const float* __restrict__ B,
           float* __restrict__ part, int K, int KG, int kchunk) {
    __shared__ char Bs[2][64 * 128];   // 64 rows x 64 f16, swizzled
    int tid = threadIdx.x;
    int lane = tid & 63;
    int w = tid >> 6;
    int wm = w & 3, wn = w >> 2;
    int n0 = blockIdx.x * 64;
    int ks = blockIdx.y * kchunk;
    int nt = kchunk >> 6;

    f32x4 acc[5][2];
    #pragma unroll
    for (int tm = 0; tm < 5; ++tm)
        #pragma unroll
        for (int tn = 0; tn < 2; ++tn)
            acc[tm][tn] = f32x4{0.f, 0.f, 0.f, 0.f};

    int srow = tid >> 3;          // 0..63
    int skp  = (tid & 7) * 8;     // 0..56
    const float* bsrc = B + (size_t)(n0 + srow) * K + ks + skp;
    int sboff = srow * 128 + ((skp * 2) ^ ((srow & 7) << 4));

    float4 v0 = *(const float4*)(bsrc);
    float4 v1 = *(const float4*)(bsrc + 4);
    {
        union { _Float16 h[8]; uint4 u; } cv;
        cv.h[0] = (_Float16)v0.x; cv.h[1] = (_Float16)v0.y;
        cv.h[2] = (_Float16)v0.z; cv.h[3] = (_Float16)v0.w;
        cv.h[4] = (_Float16)v1.x; cv.h[5] = (_Float16)v1.y;
        cv.h[6] = (_Float16)v1.z; cv.h[7] = (_Float16)v1.w;
        *(uint4*)(Bs[0] + sboff) = cv.u;
    }
    if (nt > 1) {
        v0 = *(const float4*)(bsrc + 64);
        v1 = *(const float4*)(bsrc + 68);
    }
    __syncthreads();

    for (int k0 = 0; k0 < nt; ++k0) {
        const char* cur = Bs[k0 & 1];
        if (k0 + 1 < nt) {
            union { _Float16 h[8]; uint4 u; } cv;
            cv.h[0] = (_Float16)v0.x; cv.h[1] = (_Float16)v0.y;
            cv.h[2] = (_Float16)v0.z; cv.h[3] = (_Float16)v0.w;
            cv.h[4] = (_Float16)v1.x; cv.h[5] = (_Float16)v1.y;
            cv.h[6] = (_Float16)v1.z; cv.h[7] = (_Float16)v1.w;
            *(uint4*)(Bs[(k0 + 1) & 1] + sboff) = cv.u;
            if (k0 + 2 < nt) {
                v0 = *(const float4*)(bsrc + (k0 + 2) * 64);
                v1 = *(const float4*)(bsrc + (k0 + 2) * 64 + 4);
            }
        }
        #pragma unroll
        for (int kk = 0; kk < 2; ++kk) {
            int g = (ks + k0 * 64 + kk * 32) >> 5;
            f16x8 bfr[2];
            #pragma unroll
            for (int tn = 0; tn < 2; ++tn) {
                int row = wn * 32 + tn * 16 + (lane & 15);
                int kb = kk * 64 + (lane >> 4) * 16;
                bfr[tn] = *(const f16x8*)(cur + row * 128 + (kb ^ ((row & 7) << 4)));
            }
            #pragma unroll
            for (int tm = 0; tm < 5; ++tm) {
                int T = wm * 5 + tm;
                f16x8 a = *(const f16x8*)(Af + ((size_t)(T * KG + g) * 64 + lane) * 8);
                #pragma unroll
                for (int tn = 0; tn < 2; ++tn)
                    acc[tm][tn] = __builtin_amdgcn_mfma_f32_16x16x32_f16(a, bfr[tn], acc[tm][tn], 0, 0, 0);
            }
        }
        __syncthreads();
    }
    float* pout = part + (size_t)blockIdx.y * (NTOP * FCN);
    #pragma unroll
    for (int tm = 0; tm < 5; ++tm) {
        int mbase = (wm * 5 + tm) * 16 + (lane >> 4) * 4;
        #pragma unroll
        for (int j = 0; j < 4; ++j) {
            int m = mbase + j;
            if (m < NTOP) {
                #pragma unroll
                for (int tn = 0; tn < 2; ++tn) {
                    int n = n0 + wn * 32 + tn * 16 + (lane & 15);
                    pout[(size_t)m * FCN + n] = acc[tm][tn][j];
                }
            }
        }
    }
}

// ---------------- 8b. reduce fc1 partials + bias + relu -> h1 fragments f16 --
__global__ void reduce_fc1(const float* __restrict__ part, const float* __restrict__ bias,
                           _Float16* __restrict__ h1f, int ns) {
    int i = blockIdx.x * 256 + threadIdx.x;     // 300*512
    if (i >= NTOP * 512) return;
    int m = i >> 9;
    int f = (i & 511) * 8;
    float s[8];
    const float* p0 = part + (size_t)m * FCN + f;
    #pragma unroll
    for (int e = 0; e < 8; ++e) s[e] = p0[e];
    for (int z = 1; z < ns; ++z) {
        const float* pz = p0 + (size_t)z * (NTOP * FCN);
        #pragma unroll
        for (int e = 0; e < 8; ++e) s[e] += pz[e];
    }
    union { _Float16 h[8]; uint4 u; } o;
    #pragma unroll
    for (int e = 0; e < 8; ++e) o.h[e] = (_Float16)fmaxf(s[e] + bias[f + e], 0.0f);
    int T = m >> 4, g = f >> 5, l = (m & 15) + 16 * ((f >> 3) & 3);
    *(uint4*)(h1f + ((size_t)(T * KG2 + g) * 64 + l) * 8) = o.u;
}

// ---------------- 8c. reduce fc2 partials + bias + relu -> h2 f32 ----------
__global__ void reduce_fc2(const float* __restrict__ part, const float* __restrict__ bias,
                           float* __restrict__ outp, int ns) {
    size_t i = (size_t)blockIdx.x * 256 + threadIdx.x;    // float4 index
    size_t mn4 = (size_t)NTOP * FCN / 4;
    if (i >= mn4) return;
    float4 s = *(const float4*)(part + i * 4);
    for (int zz = 1; zz < ns; ++zz) {
        float4 v = *(const float4*)(part + (size_t)zz * (NTOP * FCN) + i * 4);
        s.x += v.x; s.y += v.y; s.z += v.z; s.w += v.w;
    }
    int n = (int)((i * 4) % FCN);
    float4 b = *(const float4*)(bias + n);
    s.x = fmaxf(s.x + b.x, 0.f); s.y = fmaxf(s.y + b.y, 0.f);
    s.z = fmaxf(s.z + b.z, 0.f); s.w = fmaxf(s.w + b.w, 0.f);
    *(float4*)(outp + i * 4) = s;
}

// ---------------- 9. final heads: wave per output + keep mask ----------------
__global__ void __launch_bounds__(256)
final_k(const float* __restrict__ h2, const float* __restrict__ clsw,
        const float* __restrict__ clsb, const float* __restrict__ boxw,
        const float* __restrict__ boxb, const int* __restrict__ keep,
        float* __restrict__ out) {
    int gid = blockIdx.x * 4 + (threadIdx.x >> 6);
    if (gid >= NTOP * 25) return;
    int lane = threadIdx.x & 63;
    int k = gid / 25, o = gid % 25;
    const float* w;
    float b;
    if (o < 21) { w = clsw + (size_t)o * 4096; b = clsb[o]; }
    else        { w = boxw + (size_t)(o - 21) * 4096; b = boxb[o - 21]; }
    const float* h = h2 + (size_t)k * 4096;
    float s = 0.0f;
    #pragma unroll
    for (int i = 0; i < 16; ++i) {
        float4 hv = *(const float4*)(h + (i * 64 + lane) * 4);
        float4 wv = *(const float4*)(w + (i * 64 + lane) * 4);
        s += hv.x * wv.x + hv.y * wv.y + hv.z * wv.z + hv.w * wv.w;
    }
    #pragma unroll
    for (int off = 1; off < 64; off <<= 1) s += __shfl_xor(s, off, 64);
    if (lane == 0) out[gid] = keep[k] ? (s + b) : 0.0f;
}

// ---------------- launch ----------------
extern "C" void kernel_launch(void* const* d_in, const int* in_sizes, int n_in,
                              void* d_out, int out_size, void* d_ws, size_t ws_size,
                              hipStream_t stream) {
    const float* x    = (const float*)d_in[0];
    const float* Wf   = (const float*)d_in[2];
    const float* bf   = (const float*)d_in[3];
    const float* W1   = (const float*)d_in[4];
    const float* b1   = (const float*)d_in[5];
    const float* Wc   = (const float*)d_in[6];
    const float* bc   = (const float*)d_in[7];
    const float* Wb   = (const float*)d_in[8];
    const float* bb   = (const float*)d_in[9];
    const float* fc1w = (const float*)d_in[10];
    const float* fc1b = (const float*)d_in[11];
    const float* fc2w = (const float*)d_in[12];
    const float* fc2b = (const float*)d_in[13];
    const float* clsw = (const float*)d_in[14];
    const float* clsb = (const float*)d_in[15];
    const float* boxw = (const float*)d_in[16];
    const float* boxb = (const float*)d_in[17];
    const void*  wp   = d_in[18];
    const void*  hp   = d_in[19];

    char* ws = (char*)d_ws;
    float*     fpad  = (float*)(ws + OFF_FPAD);
    float*     score = (float*)(ws + OFF_SCORE);
    float*     preb  = (float*)(ws + OFF_PREB);
    int*       keep  = (int*)(ws + OFF_KEEP);
    int*       ixb   = (int*)(ws + OFF_IX);
    int*       iyb   = (int*)(ws + OFF_IY);
    _Float16*  Af    = (_Float16*)(ws + OFF_AFRAG);
    _Float16*  h1f   = (_Float16*)(ws + OFF_H1F);
    float*     h2    = (float*)(ws + OFF_H2);
    float*     w1t   = (float*)(ws + OFF_W1T);
    float*     out   = (float*)d_out;

    // split-K slots + conv-partial split, guarded by ws_size
    size_t slot = (size_t)NTOP * FCN * 4;   // 4.9 MB
    size_t avail = ws_size > OFF_PART ? (ws_size - OFF_PART) / slot : 0;
    int ns1 = (avail >= 7) ? 7 : (avail >= 4) ? 4 : (avail >= 2) ? 2 : 1;
    int ns2 = (avail >= 4) ? 4 : (avail >= 2) ? 2 : 1;
    float* part1 = (avail >= 1) ? (float*)(ws + OFF_PART) : h2;              // h2 free during fc1
    float* part2 = (avail >= 1) ? (float*)(ws + OFF_PART) : (float*)Af;      // Af free after fc1
    int kch1 = (196 / ns1) * 64;
    int kch2 = (64 / ns2) * 64;
    // conv ci-split: 8-way partials (20.5 MB) share OFF_PART (time-disjoint with fc partials)
    int zs = (avail >= 5) ? 8 : 4;
    float* cpart = (avail >= 5) ? (float*)(ws + OFF_PART) : (float*)(ws + OFF_AFRAG);

    zero_fpad<<<832, 256, 0, stream>>>(fpad);
    patch_conv<<<dim3(10, 64), 256, 0, stream>>>(x, Wf, bf, fpad);
    transpose_w1<<<(2304 * 256 + 255) / 256, 256, 0, stream>>>(W1, w1t);
    conv3x3_part<<<dim3(7, 50, zs), 256, 0, stream>>>(fpad, w1t, cpart, 256 / zs);
    reducehead_k<<<625, 256, 0, stream>>>(cpart, b1, Wc, bc, Wb, bb, score, preb, zs);
    topknms_k<<<1, 1024, 0, stream>>>(score, preb, wp, hp, keep, ixb, iyb);
    roipool_frag<<<(MT * KG1 * 64 + 255) / 256, 256, 0, stream>>>(fpad, ixb, iyb, Af);
    gemm_fullm<<<dim3(64, ns1), 512, 0, stream>>>(Af, fc1w, part1, DFLAT, KG1, kch1);
    reduce_fc1<<<(NTOP * 512 + 255) / 256, 256, 0, stream>>>(part1, fc1b, h1f, ns1);
    gemm_fullm<<<dim3(64, ns2), 512, 0, stream>>>(h1f, fc2w, part2, FCN, KG2, kch2);
    reduce_fc2<<<(NTOP * FCN / 4 + 255) / 256, 256, 0, stream>>>(part2, fc2b, h2, ns2);
    final_k<<<(NTOP * 25 + 3) / 4, 256, 0, stream>>>(h2, clsw, clsb, boxw, boxb, keep, out);
}

// Round 9
// 345.887 us; speedup vs baseline: 5.8144x; 1.0343x over previous
//
#include <hip/hip_runtime.h>
#include <hip/hip_bf16.h>
#include <math.h>

// ---------------- problem constants ----------------
#define NPIX   2500      // 50*50
#define CFEAT  256
#define NTOP   300
#define DFLAT  12544     // 256*7*7
#define FCN    4096
#define FPSTRIDE 3328    // 52 rows * 64 floats per channel (padded feature)
#define KG1    392       // DFLAT/32
#define KG2    128       // FCN/32
#define MT     20        // m-tiles (320 rows padded)

typedef _Float16 f16x8 __attribute__((ext_vector_type(8)));
typedef float    f32x4 __attribute__((ext_vector_type(4)));

// ---------------- workspace offsets (bytes) ----------------
static constexpr size_t OFF_FPAD  = 0;          // 3.4 MB
static constexpr size_t OFF_SCORE = 0x5C0000;
static constexpr size_t OFF_PREB  = 0x5D0000;
static constexpr size_t OFF_KEEP  = 0x5E5000;
static constexpr size_t OFF_IX    = 0x5E6000;
static constexpr size_t OFF_IY    = 0x5EB000;
static constexpr size_t OFF_AFRAG = 0x600000;   // A fragments f16, 8.03 MB
static constexpr size_t OFF_H1F   = 0xE00000;   // h1 fragments f16, 2.62 MB
static constexpr size_t OFF_H2    = 0x1100000;  // h2 f32, 4.9 MB
static constexpr size_t OFF_W1T   = 0x1600000;  // 2.36 MB transient
static constexpr size_t OFF_PART  = 0x1900000;  // cpart (20.5 MB) then split-K partials (39.3 MB), time-disjoint

__device__ inline float decode_dim(const void* p) {
    int iv = *(const int*)p;
    if (iv > 0 && iv < (1 << 20)) return (float)iv;
    return __int_as_float(iv);
}

// ---------------- 0. zero the padded feature buffer ----------------
__global__ void zero_fpad(float* __restrict__ fpad) {
    int i = blockIdx.x * 256 + threadIdx.x;   // float4 index, 256*3328/4 = 212992
    if (i < 212992) *(float4*)(fpad + (size_t)i * 4) = make_float4(0.f, 0.f, 0.f, 0.f);
}

// ---------------- 1. patchify conv: 16x16 stride16 VALID -> padded feat -----
__global__ void __launch_bounds__(256)
patch_conv(const float* __restrict__ x, const float* __restrict__ Wf,
           const float* __restrict__ bf, float* __restrict__ fpad) {
    __shared__ float w[3072];          // 4 co x 768
    int co0 = blockIdx.y * 4;
    for (int t = threadIdx.x; t < 3072; t += 256) w[t] = Wf[co0 * 768 + t];
    __syncthreads();
    int p = blockIdx.x * 256 + threadIdx.x;
    if (p >= NPIX) return;
    int py = p / 50, px = p % 50;
    float acc[4];
    #pragma unroll
    for (int c = 0; c < 4; ++c) acc[c] = bf[co0 + c];
    for (int ci = 0; ci < 3; ++ci) {
        const float* xp = x + ci * 640000 + (py * 16) * 800 + px * 16;
        #pragma unroll
        for (int ky = 0; ky < 16; ++ky) {
            const float* row = xp + ky * 800;
            #pragma unroll
            for (int kq = 0; kq < 4; ++kq) {
                float4 xv = *reinterpret_cast<const float4*>(row + kq * 4);
                int kb = ci * 256 + ky * 16 + kq * 4;
                #pragma unroll
                for (int c = 0; c < 4; ++c) {
                    const float* wc = w + c * 768 + kb;
                    acc[c] += xv.x * wc[0] + xv.y * wc[1] + xv.z * wc[2] + xv.w * wc[3];
                }
            }
        }
    }
    size_t o = (size_t)(py + 1) * 64 + (px + 1);
    #pragma unroll
    for (int c = 0; c < 4; ++c) fpad[(size_t)(co0 + c) * FPSTRIDE + o] = acc[c];
}

// ---------------- 1b. transpose W1 -> (ci*9+j, co) ----------------
__global__ void transpose_w1(const float* __restrict__ W1, float* __restrict__ W1t) {
    int idx = blockIdx.x * 256 + threadIdx.x;
    if (idx >= 2304 * 256) return;
    int r = idx >> 8, co = idx & 255;
    W1t[idx] = W1[co * 2304 + r];
}

// ---------------- 2. 3x3 SAME conv partials (lanes=co, 8-pixel batch, ci split) --
__global__ void __launch_bounds__(256)
conv3x3_part(const float* __restrict__ fpad, const float* __restrict__ W1t,
             float* __restrict__ cpart, int zci) {
    int co = threadIdx.x;
    int xb = blockIdx.x * 8;          // 0,8,...,48
    int y  = blockIdx.y;              // 0..49
    int z  = blockIdx.z;
    float acc[8];
    #pragma unroll
    for (int p = 0; p < 8; ++p) acc[p] = 0.0f;
    const float* fp = fpad + (size_t)(z * zci) * FPSTRIDE + (size_t)y * 64 + xb;
    const float* wp = W1t + (size_t)(z * zci) * 9 * 256 + co;
    #pragma unroll 2
    for (int ci = 0; ci < zci; ++ci) {
        float v[3][12];
        #pragma unroll
        for (int dy = 0; dy < 3; ++dy) {
            #pragma unroll
            for (int q = 0; q < 3; ++q) {
                float4 r4 = *(const float4*)(fp + dy * 64 + q * 4);
                v[dy][q * 4 + 0] = r4.x; v[dy][q * 4 + 1] = r4.y;
                v[dy][q * 4 + 2] = r4.z; v[dy][q * 4 + 3] = r4.w;
            }
        }
        float wv[9];
        #pragma unroll
        for (int k = 0; k < 9; ++k) wv[k] = wp[k * 256];
        #pragma unroll
        for (int dy = 0; dy < 3; ++dy)
            #pragma unroll
            for (int dx = 0; dx < 3; ++dx) {
                float wvv = wv[dy * 3 + dx];
                #pragma unroll
                for (int p = 0; p < 8; ++p)
                    acc[p] += v[dy][p + dx] * wvv;
            }
        fp += FPSTRIDE;
        wp += 9 * 256;
    }
    size_t base = (size_t)z * (NPIX * 256) + (size_t)(y * 50 + xb) * 256 + co;
    #pragma unroll
    for (int p = 0; p < 8; ++p)
        if (xb + p < 50) cpart[base + (size_t)p * 256] = acc[p];
}

// ---------------- 2b+3. fused: reduce conv partials + bias + relu + heads ---
__global__ void __launch_bounds__(256)
reducehead_k(const float* __restrict__ cpart, const float* __restrict__ b1,
             const float* __restrict__ Wc, const float* __restrict__ bc,
             const float* __restrict__ Wb, const float* __restrict__ bb,
             float* __restrict__ score, float* __restrict__ preb, int zs) {
    int lane = threadIdx.x & 63;
    int p = blockIdx.x * 4 + (threadIdx.x >> 6);
    if (p >= NPIX) return;
    size_t off = (size_t)p * 256 + lane * 4;
    float4 h = *(const float4*)(cpart + off);
    for (int z = 1; z < zs; ++z) {
        float4 v = *(const float4*)(cpart + (size_t)z * (NPIX * 256) + off);
        h.x += v.x; h.y += v.y; h.z += v.z; h.w += v.w;
    }
    float4 b = *(const float4*)(b1 + lane * 4);
    h.x = fmaxf(h.x + b.x, 0.f); h.y = fmaxf(h.y + b.y, 0.f);
    h.z = fmaxf(h.z + b.z, 0.f); h.w = fmaxf(h.w + b.w, 0.f);
    float4 c0 = *(const float4*)(Wc + lane * 4);
    float4 c1 = *(const float4*)(Wc + 256 + lane * 4);
    float4 w0 = *(const float4*)(Wb + lane * 4);
    float4 w1 = *(const float4*)(Wb + 256 + lane * 4);
    float4 w2 = *(const float4*)(Wb + 512 + lane * 4);
    float4 w3 = *(const float4*)(Wb + 768 + lane * 4);
    float s[6];
    s[0] = h.x*c0.x + h.y*c0.y + h.z*c0.z + h.w*c0.w;
    s[1] = h.x*c1.x + h.y*c1.y + h.z*c1.z + h.w*c1.w;
    s[2] = h.x*w0.x + h.y*w0.y + h.z*w0.z + h.w*w0.w;
    s[3] = h.x*w1.x + h.y*w1.y + h.z*w1.z + h.w*w1.w;
    s[4] = h.x*w2.x + h.y*w2.y + h.z*w2.z + h.w*w2.w;
    s[5] = h.x*w3.x + h.y*w3.y + h.z*w3.z + h.w*w3.w;
    #pragma unroll
    for (int o = 1; o < 64; o <<= 1) {
        #pragma unroll
        for (int q = 0; q < 6; ++q) s[q] += __shfl_xor(s[q], o, 64);
    }
    if (lane == 0) {
        float s0 = s[0] + bc[0], s1 = s[1] + bc[1];
        float m = fmaxf(s0, s1);
        float e0 = expf(s0 - m), e1 = expf(s1 - m);
        score[p] = e1 / (e0 + e1);
        preb[p * 4 + 0] = s[2] + bb[0];
        preb[p * 4 + 1] = s[3] + bb[1];
        preb[p * 4 + 2] = s[4] + bb[2];
        preb[p * 4 + 3] = s[5] + bb[3];
    }
}

// ---------------- 4+5+6. fused radix-select top-k + box decode + bitmask NMS --
__global__ void __launch_bounds__(1024)
topknms_k(const float* __restrict__ score, const float* __restrict__ preb,
          const void* wp_, const void* hp_, int* __restrict__ keep,
          int* __restrict__ ixb, int* __restrict__ iyb) {
    __shared__ unsigned long long KEYS[NPIX];
    __shared__ unsigned int hist[256];
    __shared__ int sh_digit, sh_newr, cnt;
    __shared__ unsigned long long SEL[NTOP];
    __shared__ unsigned long long SORT[NTOP];
    __shared__ float X1[320], Y1[320], X2[320], Y2[320], AR[320];
    __shared__ unsigned long long MASK[320][5];
    __shared__ unsigned long long KEEPW[5];
    int tid = threadIdx.x;
    int lane = tid & 63;
    int w = tid >> 6;

    for (int e = tid; e < NPIX; e += 1024) {
        unsigned sb = __float_as_uint(score[e]);
        KEYS[e] = ((unsigned long long)sb << 32) | (unsigned)(~e);
    }
    if (tid == 0) cnt = 0;
    __syncthreads();

    unsigned long long P = 0ull, M = 0ull;
    int r = NTOP;
    for (int pass = 0; pass < 8; ++pass) {
        int shift = 56 - 8 * pass;
        if (tid < 256) hist[tid] = 0u;
        __syncthreads();
        for (int e = tid; e < NPIX; e += 1024) {
            unsigned long long k = KEYS[e];
            if ((k & M) == P)
                atomicAdd(&hist[(unsigned)(k >> shift) & 255u], 1u);
        }
        __syncthreads();
        if (tid < 64) {
            unsigned c0 = hist[tid * 4 + 0], c1 = hist[tid * 4 + 1];
            unsigned c2 = hist[tid * 4 + 2], c3 = hist[tid * 4 + 3];
            unsigned sl = c0 + c1 + c2 + c3;
            unsigned suf = sl;
            #pragma unroll
            for (int off = 1; off < 64; off <<= 1) {
                unsigned o = __shfl_down(suf, off, 64);
                if (lane + off < 64) suf += o;
            }
            unsigned G = suf - sl;
            if (G < (unsigned)r && G + sl >= (unsigned)r) {
                unsigned cc[4] = {c0, c1, c2, c3};
                int d = 0; unsigned ab = G;
                #pragma unroll
                for (int i = 3; i >= 0; --i) {
                    if (ab < (unsigned)r && ab + cc[i] >= (unsigned)r) { d = tid * 4 + i; break; }
                    ab += cc[i];
                }
                sh_digit = d;
                sh_newr = r - (int)ab;
            }
        }
        __syncthreads();
        P |= ((unsigned long long)(unsigned)sh_digit) << shift;
        M |= 0xFFull << shift;
        r = sh_newr;
    }
    unsigned long long T = P;

    for (int e = tid; e < NPIX; e += 1024) {
        unsigned long long k = KEYS[e];
        if (k >= T) {
            int s = atomicAdd(&cnt, 1);
            SEL[s] = k;
        }
    }
    __syncthreads();

    if (tid < NTOP) {
        unsigned long long mine = SEL[tid];
        int rank = 0;
        for (int j = 0; j < NTOP; ++j) rank += (SEL[j] > mine) ? 1 : 0;
        SORT[rank] = mine;
    }
    __syncthreads();

    if (tid < 320) {
        float x1 = 0.f, y1 = 0.f, x2 = 0.f, y2 = 0.f;
        bool v = false;
        if (tid < NTOP) {
            unsigned long long key = SORT[tid];
            int id = (int)(~(unsigned)key);
            float sc = __uint_as_float((unsigned)(key >> 32));
            float wf = decode_dim(wp_), hf = decode_dim(hp_);
            float p0 = preb[id * 4 + 0], p1 = preb[id * 4 + 1];
            float p2 = preb[id * 4 + 2], p3 = preb[id * 4 + 3];
            x1 = fmaxf(p2 - p0 * 0.5f, 0.0f);
            y1 = fmaxf(p3 - p1 * 0.5f, 0.0f);
            x2 = fminf(p2 + p0, wf);
            y2 = fminf(p3 + p1, hf);
            v = sc > 0.5f;
            float bx1 = x1 * 0.0625f, by1 = y1 * 0.0625f;
            float bx2 = x2 * 0.0625f, by2 = y2 * 0.0625f;
            #pragma unroll
            for (int m = 0; m < 14; ++m) {
                int i = m >> 1, s = m & 1;
                float frac = ((float)i + (s ? 0.75f : 0.25f)) / 7.0f;
                float xs = bx1 + frac * (bx2 - bx1);
                float ys = by1 + frac * (by2 - by1);
                float fx = floorf(xs); fx = fminf(fmaxf(fx, 0.0f), 49.0f);
                float fy = floorf(ys); fy = fminf(fmaxf(fy, 0.0f), 49.0f);
                ixb[tid * 14 + m] = (int)fx;
                iyb[tid * 14 + m] = (int)fy;
            }
        }
        X1[tid] = x1; Y1[tid] = y1; X2[tid] = x2; Y2[tid] = y2;
        AR[tid] = fmaxf(x2 - x1, 0.0f) * fmaxf(y2 - y1, 0.0f);
        unsigned long long vb = __ballot(v);
        if (lane == 0 && w < 5) KEEPW[w] = vb;
    }
    __syncthreads();

    if (tid < 320) {
        float xi1 = X1[tid], yi1 = Y1[tid], xi2 = X2[tid], yi2 = Y2[tid], ai = AR[tid];
        #pragma unroll
        for (int jw = 0; jw < 5; ++jw) {
            unsigned long long mword = 0ull;
            #pragma unroll 4
            for (int j2 = 0; j2 < 64; ++j2) {
                int j = jw * 64 + j2;
                float ix1 = fmaxf(xi1, X1[j]);
                float iy1 = fmaxf(yi1, Y1[j]);
                float ix2 = fminf(xi2, X2[j]);
                float iy2 = fminf(yi2, Y2[j]);
                float inter = fmaxf(ix2 - ix1, 0.0f) * fmaxf(iy2 - iy1, 0.0f);
                float iou = inter / fmaxf(ai + AR[j] - inter, 1e-6f);
                bool sup = (iou > 0.7f) && (j > tid) && (j < NTOP);
                mword |= sup ? (1ull << j2) : 0ull;
            }
            MASK[tid][jw] = mword;
        }
    }
    __syncthreads();

    if (tid < 64) {
        unsigned long long m[5][5];
        #pragma unroll
        for (int g = 0; g < 5; ++g)
            #pragma unroll
            for (int q = 0; q < 5; ++q)
                m[g][q] = MASK[g * 64 + lane][q];
        unsigned long long kw0 = KEEPW[0], kw1 = KEEPW[1], kw2 = KEEPW[2],
                           kw3 = KEEPW[3], kw4 = KEEPW[4];
        #pragma unroll
        for (int g = 0; g < 5; ++g) {
            for (int i2 = 0; i2 < 64; ++i2) {
                unsigned long long kg = (g == 0) ? kw0 : (g == 1) ? kw1 :
                                        (g == 2) ? kw2 : (g == 3) ? kw3 : kw4;
                bool alive = (kg >> i2) & 1ull;
                unsigned long long b0 = __shfl(m[g][0], i2, 64);
                unsigned long long b1 = __shfl(m[g][1], i2, 64);
                unsigned long long b2 = __shfl(m[g][2], i2, 64);
                unsigned long long b3 = __shfl(m[g][3], i2, 64);
                unsigned long long b4 = __shfl(m[g][4], i2, 64);
                if (alive) {
                    kw0 &= ~b0; kw1 &= ~b1; kw2 &= ~b2; kw3 &= ~b3; kw4 &= ~b4;
                }
            }
        }
        #pragma unroll
        for (int g = 0; g < 5; ++g) {
            unsigned long long kg = (g == 0) ? kw0 : (g == 1) ? kw1 :
                                    (g == 2) ? kw2 : (g == 3) ? kw3 : kw4;
            int j = g * 64 + lane;
            if (j < NTOP) keep[j] = (int)((kg >> lane) & 1ull);
        }
    }
}

// ---------------- 7. ROI max pool -> A fragments (f16, MFMA per-lane layout) -
__global__ void __launch_bounds__(256)
roipool_frag(const float* __restrict__ fpad, const int* __restrict__ ixb,
             const int* __restrict__ iyb, _Float16* __restrict__ Af) {
    int wid = blockIdx.x * 256 + threadIdx.x;
    if (wid >= MT * KG1 * 64) return;
    int l = wid & 63;
    int g = (wid >> 6) % KG1;
    int T = wid / (KG1 * 64);
    int mm = T * 16 + (l & 15);
    int kbase = g * 32 + ((l >> 4) & 3) * 8;
    union { _Float16 h[8]; uint4 u; } o;
    if (mm < NTOP) {
        const int* ix = ixb + mm * 14;
        const int* iy = iyb + mm * 14;
        #pragma unroll
        for (int e = 0; e < 8; ++e) {
            int k = kbase + e;
            int c = k / 49, ij = k % 49, i = ij / 7, jx = ij % 7;
            int y0 = iy[2 * i] + 1, y1 = iy[2 * i + 1] + 1;
            int x0 = ix[2 * jx] + 1, x1 = ix[2 * jx + 1] + 1;
            const float* f = fpad + (size_t)c * FPSTRIDE;
            float v = fmaxf(fmaxf(f[y0 * 64 + x0], f[y0 * 64 + x1]),
                            fmaxf(f[y1 * 64 + x0], f[y1 * 64 + x1]));
            o.h[e] = (_Float16)v;
        }
    } else {
        o.u.x = 0u; o.u.y = 0u; o.u.z = 0u; o.u.w = 0u;
    }
    *(uint4*)(Af + (size_t)wid * 8) = o.u;
}

// ---------------- 8. full-M MFMA GEMM, BN=128, 16 waves, split-K XCD-grouped --
// 1-D grid of 32*ns blocks: kz = wg % ns (XCD-grouped under round-robin),
// n0 = (wg / ns) * 128. B streamed once from HBM (f32->f16, swizzled LDS dbuf).
__global__ void __launch_bounds__(1024)
gemm_fullm(const _Float16* __restrict__ Af, const float* __restrict__ B,
           float* __restrict__ part, int K, int KG, int kchunk, int ns) {
    __shared__ char Bs[2][128 * 128];   // 128 rows x 64 f16, swizzled
    int tid = threadIdx.x;
    int lane = tid & 63;
    int w = tid >> 6;
    int wm = w & 3, wn = w >> 2;        // 4 m-groups x 4 n-groups
    int wg = blockIdx.x;
    int kz = wg % ns;
    int n0 = (wg / ns) * 128;
    int ks = kz * kchunk;
    int klen = K - ks; if (klen > kchunk) klen = kchunk;
    int nt = klen >> 6;

    f32x4 acc[5][2];
    #pragma unroll
    for (int tm = 0; tm < 5; ++tm)
        #pragma unroll
        for (int tn = 0; tn < 2; ++tn)
            acc[tm][tn] = f32x4{0.f, 0.f, 0.f, 0.f};

    int srow = tid >> 3;          // 0..127
    int skp  = (tid & 7) * 8;     // 0..56
    const float* bsrc = B + (size_t)(n0 + srow) * K + ks + skp;
    int sboff = srow * 128 + ((skp * 2) ^ ((srow & 7) << 4));

    float4 v0 = *(const float4*)(bsrc);
    float4 v1 = *(const float4*)(bsrc + 4);
    {
        union { _Float16 h[8]; uint4 u; } cv;
        cv.h[0] = (_Float16)v0.x; cv.h[1] = (_Float16)v0.y;
        cv.h[2] = (_Float16)v0.z; cv.h[3] = (_Float16)v0.w;
        cv.h[4] = (_Float16)v1.x; cv.h[5] = (_Float16)v1.y;
        cv.h[6] = (_Float16)v1.z; cv.h[7] = (_Float16)v1.w;
        *(uint4*)(Bs[0] + sboff) = cv.u;
    }
    if (nt > 1) {
        v0 = *(const float4*)(bsrc + 64);
        v1 = *(const float4*)(bsrc + 68);
    }
    __syncthreads();

    for (int k0 = 0; k0 < nt; ++k0) {
        const char* cur = Bs[k0 & 1];
        if (k0 + 1 < nt) {
            union { _Float16 h[8]; uint4 u; } cv;
            cv.h[0] = (_Float16)v0.x; cv.h[1] = (_Float16)v0.y;
            cv.h[2] = (_Float16)v0.z; cv.h[3] = (_Float16)v0.w;
            cv.h[4] = (_Float16)v1.x; cv.h[5] = (_Float16)v1.y;
            cv.h[6] = (_Float16)v1.z; cv.h[7] = (_Float16)v1.w;
            *(uint4*)(Bs[(k0 + 1) & 1] + sboff) = cv.u;
            if (k0 + 2 < nt) {
                v0 = *(const float4*)(bsrc + (k0 + 2) * 64);
                v1 = *(const float4*)(bsrc + (k0 + 2) * 64 + 4);
            }
        }
        // A fragments for both K=32 halves, issued up-front
        int g0 = (ks + k0 * 64) >> 5;
        f16x8 a0[5], a1[5];
        #pragma unroll
        for (int tm = 0; tm < 5; ++tm) {
            int T = wm * 5 + tm;
            a0[tm] = *(const f16x8*)(Af + ((size_t)(T * KG + g0) * 64 + lane) * 8);
            a1[tm] = *(const f16x8*)(Af + ((size_t)(T * KG + g0 + 1) * 64 + lane) * 8);
        }
        f16x8 b0[2], b1[2];
        #pragma unroll
        for (int tn = 0; tn < 2; ++tn) {
            int row = wn * 32 + tn * 16 + (lane & 15);
            int kb0 = (lane >> 4) * 16;
            b0[tn] = *(const f16x8*)(cur + row * 128 + (kb0 ^ ((row & 7) << 4)));
            b1[tn] = *(const f16x8*)(cur + row * 128 + ((kb0 + 64) ^ ((row & 7) << 4)));
        }
        #pragma unroll
        for (int tm = 0; tm < 5; ++tm)
            #pragma unroll
            for (int tn = 0; tn < 2; ++tn) {
                acc[tm][tn] = __builtin_amdgcn_mfma_f32_16x16x32_f16(a0[tm], b0[tn], acc[tm][tn], 0, 0, 0);
                acc[tm][tn] = __builtin_amdgcn_mfma_f32_16x16x32_f16(a1[tm], b1[tn], acc[tm][tn], 0, 0, 0);
            }
        __syncthreads();
    }
    float* pout = part + (size_t)kz * (NTOP * FCN);
    #pragma unroll
    for (int tm = 0; tm < 5; ++tm) {
        int mbase = (wm * 5 + tm) * 16 + (lane >> 4) * 4;
        #pragma unroll
        for (int j = 0; j < 4; ++j) {
            int m = mbase + j;
            if (m < NTOP) {
                #pragma unroll
                for (int tn = 0; tn < 2; ++tn) {
                    int n = n0 + wn * 32 + tn * 16 + (lane & 15);
                    pout[(size_t)m * FCN + n] = acc[tm][tn][j];
                }
            }
        }
    }
}

// ---------------- 8b. reduce fc1 partials + bias + relu -> h1 fragments f16 --
__global__ void reduce_fc1(const float* __restrict__ part, const float* __restrict__ bias,
                           _Float16* __restrict__ h1f, int ns) {
    int i = blockIdx.x * 256 + threadIdx.x;     // 300*512
    if (i >= NTOP * 512) return;
    int m = i >> 9;
    int f = (i & 511) * 8;
    float s[8];
    const float* p0 = part + (size_t)m * FCN + f;
    #pragma unroll
    for (int e = 0; e < 8; ++e) s[e] = p0[e];
    for (int z = 1; z < ns; ++z) {
        const float* pz = p0 + (size_t)z * (NTOP * FCN);
        #pragma unroll
        for (int e = 0; e < 8; ++e) s[e] += pz[e];
    }
    union { _Float16 h[8]; uint4 u; } o;
    #pragma unroll
    for (int e = 0; e < 8; ++e) o.h[e] = (_Float16)fmaxf(s[e] + bias[f + e], 0.0f);
    int T = m >> 4, g = f >> 5, l = (m & 15) + 16 * ((f >> 3) & 3);
    *(uint4*)(h1f + ((size_t)(T * KG2 + g) * 64 + l) * 8) = o.u;
}

// ---------------- 8c. reduce fc2 partials + bias + relu -> h2 f32 ----------
__global__ void reduce_fc2(const float* __restrict__ part, const float* __restrict__ bias,
                           float* __restrict__ outp, int ns) {
    size_t i = (size_t)blockIdx.x * 256 + threadIdx.x;    // float4 index
    size_t mn4 = (size_t)NTOP * FCN / 4;
    if (i >= mn4) return;
    float4 s = *(const float4*)(part + i * 4);
    for (int zz = 1; zz < ns; ++zz) {
        float4 v = *(const float4*)(part + (size_t)zz * (NTOP * FCN) + i * 4);
        s.x += v.x; s.y += v.y; s.z += v.z; s.w += v.w;
    }
    int n = (int)((i * 4) % FCN);
    float4 b = *(const float4*)(bias + n);
    s.x = fmaxf(s.x + b.x, 0.f); s.y = fmaxf(s.y + b.y, 0.f);
    s.z = fmaxf(s.z + b.z, 0.f); s.w = fmaxf(s.w + b.w, 0.f);
    *(float4*)(outp + i * 4) = s;
}

// ---------------- 9. final heads: wave per output + keep mask ----------------
__global__ void __launch_bounds__(256)
final_k(const float* __restrict__ h2, const float* __restrict__ clsw,
        const float* __restrict__ clsb, const float* __restrict__ boxw,
        const float* __restrict__ boxb, const int* __restrict__ keep,
        float* __restrict__ out) {
    int gid = blockIdx.x * 4 + (threadIdx.x >> 6);
    if (gid >= NTOP * 25) return;
    int lane = threadIdx.x & 63;
    int k = gid / 25, o = gid % 25;
    const float* w;
    float b;
    if (o < 21) { w = clsw + (size_t)o * 4096; b = clsb[o]; }
    else        { w = boxw + (size_t)(o - 21) * 4096; b = boxb[o - 21]; }
    const float* h = h2 + (size_t)k * 4096;
    float s = 0.0f;
    #pragma unroll
    for (int i = 0; i < 16; ++i) {
        float4 hv = *(const float4*)(h + (i * 64 + lane) * 4);
        float4 wv = *(const float4*)(w + (i * 64 + lane) * 4);
        s += hv.x * wv.x + hv.y * wv.y + hv.z * wv.z + hv.w * wv.w;
    }
    #pragma unroll
    for (int off = 1; off < 64; off <<= 1) s += __shfl_xor(s, off, 64);
    if (lane == 0) out[gid] = keep[k] ? (s + b) : 0.0f;
}

// ---------------- launch ----------------
extern "C" void kernel_launch(void* const* d_in, const int* in_sizes, int n_in,
                              void* d_out, int out_size, void* d_ws, size_t ws_size,
                              hipStream_t stream) {
    const float* x    = (const float*)d_in[0];
    const float* Wf   = (const float*)d_in[2];
    const float* bf   = (const float*)d_in[3];
    const float* W1   = (const float*)d_in[4];
    const float* b1   = (const float*)d_in[5];
    const float* Wc   = (const float*)d_in[6];
    const float* bc   = (const float*)d_in[7];
    const float* Wb   = (const float*)d_in[8];
    const float* bb   = (const float*)d_in[9];
    const float* fc1w = (const float*)d_in[10];
    const float* fc1b = (const float*)d_in[11];
    const float* fc2w = (const float*)d_in[12];
    const float* fc2b = (const float*)d_in[13];
    const float* clsw = (const float*)d_in[14];
    const float* clsb = (const float*)d_in[15];
    const float* boxw = (const float*)d_in[16];
    const float* boxb = (const float*)d_in[17];
    const void*  wp   = d_in[18];
    const void*  hp   = d_in[19];

    char* ws = (char*)d_ws;
    float*     fpad  = (float*)(ws + OFF_FPAD);
    float*     score = (float*)(ws + OFF_SCORE);
    float*     preb  = (float*)(ws + OFF_PREB);
    int*       keep  = (int*)(ws + OFF_KEEP);
    int*       ixb   = (int*)(ws + OFF_IX);
    int*       iyb   = (int*)(ws + OFF_IY);
    _Float16*  Af    = (_Float16*)(ws + OFF_AFRAG);
    _Float16*  h1f   = (_Float16*)(ws + OFF_H1F);
    float*     h2    = (float*)(ws + OFF_H2);
    float*     w1t   = (float*)(ws + OFF_W1T);
    float*     out   = (float*)d_out;

    // split-K slots + conv-partial split, guarded by ws_size
    size_t slot = (size_t)NTOP * FCN * 4;   // 4.9 MB
    size_t avail = ws_size > OFF_PART ? (ws_size - OFF_PART) / slot : 0;
    int ns1 = (avail >= 8) ? 8 : (avail >= 4) ? 4 : (avail >= 2) ? 2 : 1;
    int ns2 = ns1;
    float* part1 = (avail >= 1) ? (float*)(ws + OFF_PART) : h2;              // h2 free during fc1
    float* part2 = (avail >= 1) ? (float*)(ws + OFF_PART) : (float*)Af;      // Af free after fc1
    int st1 = (196 + ns1 - 1) / ns1;  int kch1 = st1 * 64;  int ns1e = (196 + st1 - 1) / st1;
    int st2 = (64 + ns2 - 1) / ns2;   int kch2 = st2 * 64;  int ns2e = (64 + st2 - 1) / st2;
    // conv ci-split: 8-way partials (20.5 MB) share OFF_PART (time-disjoint with fc partials)
    int zs = (avail >= 5) ? 8 : 4;
    float* cpart = (avail >= 5) ? (float*)(ws + OFF_PART) : (float*)(ws + OFF_AFRAG);

    zero_fpad<<<832, 256, 0, stream>>>(fpad);
    patch_conv<<<dim3(10, 64), 256, 0, stream>>>(x, Wf, bf, fpad);
    transpose_w1<<<(2304 * 256 + 255) / 256, 256, 0, stream>>>(W1, w1t);
    conv3x3_part<<<dim3(7, 50, zs), 256, 0, stream>>>(fpad, w1t, cpart, 256 / zs);
    reducehead_k<<<625, 256, 0, stream>>>(cpart, b1, Wc, bc, Wb, bb, score, preb, zs);
    topknms_k<<<1, 1024, 0, stream>>>(score, preb, wp, hp, keep, ixb, iyb);
    roipool_frag<<<(MT * KG1 * 64 + 255) / 256, 256, 0, stream>>>(fpad, ixb, iyb, Af);
    gemm_fullm<<<32 * ns1e, 1024, 0, stream>>>(Af, fc1w, part1, DFLAT, KG1, kch1, ns1e);
    reduce_fc1<<<(NTOP * 512 + 255) / 256, 256, 0, stream>>>(part1, fc1b, h1f, ns1e);
    gemm_fullm<<<32 * ns2e, 1024, 0, stream>>>(h1f, fc2w, part2, FCN, KG2, kch2, ns2e);
    reduce_fc2<<<(NTOP * FCN / 4 + 255) / 256, 256, 0, stream>>>(part2, fc2b, h2, ns2e);
    final_k<<<(NTOP * 25 + 3) / 4, 256, 0, stream>>>(h2, clsw, clsb, boxw, boxb, keep, out);
}

// Round 10
// 342.899 us; speedup vs baseline: 5.8651x; 1.0087x over previous
//
#include <hip/hip_runtime.h>
#include <hip/hip_bf16.h>
#include <math.h>

// ---------------- problem constants ----------------
#define NPIX   2500      // 50*50
#define CFEAT  256
#define NTOP   300
#define DFLAT  12544     // 256*7*7
#define FCN    4096
#define FPSTRIDE 3328    // 52 rows * 64 floats per channel (padded feature)
#define KG1    392       // DFLAT/32
#define KG2    128       // FCN/32
#define MT     20        // m-tiles (320 rows padded)

typedef _Float16 f16x8 __attribute__((ext_vector_type(8)));
typedef float    f32x4 __attribute__((ext_vector_type(4)));

// ---------------- workspace offsets (bytes) ----------------
static constexpr size_t OFF_FPAD  = 0;          // 3.4 MB
static constexpr size_t OFF_SCORE = 0x5C0000;
static constexpr size_t OFF_PREB  = 0x5D0000;
static constexpr size_t OFF_KEEP  = 0x5E5000;
static constexpr size_t OFF_IX    = 0x5E6000;
static constexpr size_t OFF_IY    = 0x5EB000;
static constexpr size_t OFF_AFRAG = 0x600000;   // A fragments f16, 8.03 MB
static constexpr size_t OFF_H1F   = 0xE00000;   // h1 fragments f16, 2.62 MB
static constexpr size_t OFF_H2    = 0x1100000;  // h2 f32, 4.9 MB
static constexpr size_t OFF_W1T   = 0x1600000;  // 2.36 MB transient
static constexpr size_t OFF_PART  = 0x1900000;  // cpart (20.5 MB) then split-K partials, time-disjoint

__device__ inline float decode_dim(const void* p) {
    int iv = *(const int*)p;
    if (iv > 0 && iv < (1 << 20)) return (float)iv;
    return __int_as_float(iv);
}

// ---------------- 0. fused: zero padded feature buffer + transpose W1 -------
__global__ void prep_k(float* __restrict__ fpad, const float* __restrict__ W1,
                       float* __restrict__ W1t) {
    int b = blockIdx.x;
    if (b < 832) {
        int i = b * 256 + threadIdx.x;   // float4 index, 212992 total
        if (i < 212992) *(float4*)(fpad + (size_t)i * 4) = make_float4(0.f, 0.f, 0.f, 0.f);
    } else {
        int idx = (b - 832) * 256 + threadIdx.x;
        if (idx < 2304 * 256) {
            int r = idx >> 8, co = idx & 255;
            W1t[idx] = W1[co * 2304 + r];
        }
    }
}

// ---------------- 1. patchify conv: 16x16 stride16 VALID -> padded feat -----
__global__ void __launch_bounds__(256)
patch_conv(const float* __restrict__ x, const float* __restrict__ Wf,
           const float* __restrict__ bf, float* __restrict__ fpad) {
    __shared__ float w[3072];          // 4 co x 768
    int co0 = blockIdx.y * 4;
    for (int t = threadIdx.x; t < 3072; t += 256) w[t] = Wf[co0 * 768 + t];
    __syncthreads();
    int p = blockIdx.x * 256 + threadIdx.x;
    if (p >= NPIX) return;
    int py = p / 50, px = p % 50;
    float acc[4];
    #pragma unroll
    for (int c = 0; c < 4; ++c) acc[c] = bf[co0 + c];
    for (int ci = 0; ci < 3; ++ci) {
        const float* xp = x + ci * 640000 + (py * 16) * 800 + px * 16;
        #pragma unroll
        for (int ky = 0; ky < 16; ++ky) {
            const float* row = xp + ky * 800;
            #pragma unroll
            for (int kq = 0; kq < 4; ++kq) {
                float4 xv = *reinterpret_cast<const float4*>(row + kq * 4);
                int kb = ci * 256 + ky * 16 + kq * 4;
                #pragma unroll
                for (int c = 0; c < 4; ++c) {
                    const float* wc = w + c * 768 + kb;
                    acc[c] += xv.x * wc[0] + xv.y * wc[1] + xv.z * wc[2] + xv.w * wc[3];
                }
            }
        }
    }
    size_t o = (size_t)(py + 1) * 64 + (px + 1);
    #pragma unroll
    for (int c = 0; c < 4; ++c) fpad[(size_t)(co0 + c) * FPSTRIDE + o] = acc[c];
}

// ---------------- 2. 3x3 SAME conv partials (lanes=co, 8-pixel batch, ci split) --
__global__ void __launch_bounds__(256)
conv3x3_part(const float* __restrict__ fpad, const float* __restrict__ W1t,
             float* __restrict__ cpart, int zci) {
    int co = threadIdx.x;
    int xb = blockIdx.x * 8;          // 0,8,...,48
    int y  = blockIdx.y;              // 0..49
    int z  = blockIdx.z;
    float acc[8];
    #pragma unroll
    for (int p = 0; p < 8; ++p) acc[p] = 0.0f;
    const float* fp = fpad + (size_t)(z * zci) * FPSTRIDE + (size_t)y * 64 + xb;
    const float* wp = W1t + (size_t)(z * zci) * 9 * 256 + co;
    #pragma unroll 2
    for (int ci = 0; ci < zci; ++ci) {
        float v[3][12];
        #pragma unroll
        for (int dy = 0; dy < 3; ++dy) {
            #pragma unroll
            for (int q = 0; q < 3; ++q) {
                float4 r4 = *(const float4*)(fp + dy * 64 + q * 4);
                v[dy][q * 4 + 0] = r4.x; v[dy][q * 4 + 1] = r4.y;
                v[dy][q * 4 + 2] = r4.z; v[dy][q * 4 + 3] = r4.w;
            }
        }
        float wv[9];
        #pragma unroll
        for (int k = 0; k < 9; ++k) wv[k] = wp[k * 256];
        #pragma unroll
        for (int dy = 0; dy < 3; ++dy)
            #pragma unroll
            for (int dx = 0; dx < 3; ++dx) {
                float wvv = wv[dy * 3 + dx];
                #pragma unroll
                for (int p = 0; p < 8; ++p)
                    acc[p] += v[dy][p + dx] * wvv;
            }
        fp += FPSTRIDE;
        wp += 9 * 256;
    }
    size_t base = (size_t)z * (NPIX * 256) + (size_t)(y * 50 + xb) * 256 + co;
    #pragma unroll
    for (int p = 0; p < 8; ++p)
        if (xb + p < 50) cpart[base + (size_t)p * 256] = acc[p];
}

// ---------------- 2b+3. fused: reduce conv partials + bias + relu + heads ---
__global__ void __launch_bounds__(256)
reducehead_k(const float* __restrict__ cpart, const float* __restrict__ b1,
             const float* __restrict__ Wc, const float* __restrict__ bc,
             const float* __restrict__ Wb, const float* __restrict__ bb,
             float* __restrict__ score, float* __restrict__ preb, int zs) {
    int lane = threadIdx.x & 63;
    int p = blockIdx.x * 4 + (threadIdx.x >> 6);
    if (p >= NPIX) return;
    size_t off = (size_t)p * 256 + lane * 4;
    float4 h = *(const float4*)(cpart + off);
    for (int z = 1; z < zs; ++z) {
        float4 v = *(const float4*)(cpart + (size_t)z * (NPIX * 256) + off);
        h.x += v.x; h.y += v.y; h.z += v.z; h.w += v.w;
    }
    float4 b = *(const float4*)(b1 + lane * 4);
    h.x = fmaxf(h.x + b.x, 0.f); h.y = fmaxf(h.y + b.y, 0.f);
    h.z = fmaxf(h.z + b.z, 0.f); h.w = fmaxf(h.w + b.w, 0.f);
    float4 c0 = *(const float4*)(Wc + lane * 4);
    float4 c1 = *(const float4*)(Wc + 256 + lane * 4);
    float4 w0 = *(const float4*)(Wb + lane * 4);
    float4 w1 = *(const float4*)(Wb + 256 + lane * 4);
    float4 w2 = *(const float4*)(Wb + 512 + lane * 4);
    float4 w3 = *(const float4*)(Wb + 768 + lane * 4);
    float s[6];
    s[0] = h.x*c0.x + h.y*c0.y + h.z*c0.z + h.w*c0.w;
    s[1] = h.x*c1.x + h.y*c1.y + h.z*c1.z + h.w*c1.w;
    s[2] = h.x*w0.x + h.y*w0.y + h.z*w0.z + h.w*w0.w;
    s[3] = h.x*w1.x + h.y*w1.y + h.z*w1.z + h.w*w1.w;
    s[4] = h.x*w2.x + h.y*w2.y + h.z*w2.z + h.w*w2.w;
    s[5] = h.x*w3.x + h.y*w3.y + h.z*w3.z + h.w*w3.w;
    #pragma unroll
    for (int o = 1; o < 64; o <<= 1) {
        #pragma unroll
        for (int q = 0; q < 6; ++q) s[q] += __shfl_xor(s[q], o, 64);
    }
    if (lane == 0) {
        float s0 = s[0] + bc[0], s1 = s[1] + bc[1];
        float m = fmaxf(s0, s1);
        float e0 = expf(s0 - m), e1 = expf(s1 - m);
        score[p] = e1 / (e0 + e1);
        preb[p * 4 + 0] = s[2] + bb[0];
        preb[p * 4 + 1] = s[3] + bb[1];
        preb[p * 4 + 2] = s[4] + bb[2];
        preb[p * 4 + 3] = s[5] + bb[3];
    }
}

// ---------------- 4+5+6. fused radix-select top-k + box decode + bitmask NMS --
__global__ void __launch_bounds__(1024)
topknms_k(const float* __restrict__ score, const float* __restrict__ preb,
          const void* wp_, const void* hp_, int* __restrict__ keep,
          int* __restrict__ ixb, int* __restrict__ iyb) {
    __shared__ unsigned long long KEYS[NPIX];
    __shared__ unsigned int whist[16][256];     // per-wave histograms
    __shared__ int sh_digit, sh_newr, cnt;
    __shared__ unsigned long long SEL[NTOP];
    __shared__ unsigned long long SORT[NTOP];
    __shared__ float X1[320], Y1[320], X2[320], Y2[320], AR[320];
    __shared__ unsigned long long MASK[320][5];
    __shared__ unsigned long long KEEPW[5];
    int tid = threadIdx.x;
    int lane = tid & 63;
    int w = tid >> 6;

    for (int e = tid; e < NPIX; e += 1024) {
        unsigned sb = __float_as_uint(score[e]);
        KEYS[e] = ((unsigned long long)sb << 32) | (unsigned)(~e);
    }
    if (tid == 0) cnt = 0;
    __syncthreads();

    unsigned long long P = 0ull, M = 0ull;
    int r = NTOP;
    for (int pass = 0; pass < 8; ++pass) {
        int shift = 56 - 8 * pass;
        // zero own wave's histogram row (wave-private: no barrier needed)
        *(uint4*)&whist[w][lane * 4] = uint4{0u, 0u, 0u, 0u};
        for (int e = tid; e < NPIX; e += 1024) {
            unsigned long long k = KEYS[e];
            if ((k & M) == P)
                atomicAdd(&whist[w][(unsigned)(k >> shift) & 255u], 1u);
        }
        __syncthreads();
        if (tid < 64) {
            unsigned c0 = 0, c1 = 0, c2 = 0, c3 = 0;
            #pragma unroll
            for (int ww = 0; ww < 16; ++ww) {
                c0 += whist[ww][tid * 4 + 0];
                c1 += whist[ww][tid * 4 + 1];
                c2 += whist[ww][tid * 4 + 2];
                c3 += whist[ww][tid * 4 + 3];
            }
            unsigned sl = c0 + c1 + c2 + c3;
            unsigned suf = sl;
            #pragma unroll
            for (int off = 1; off < 64; off <<= 1) {
                unsigned o = __shfl_down(suf, off, 64);
                if (lane + off < 64) suf += o;
            }
            unsigned G = suf - sl;
            if (G < (unsigned)r && G + sl >= (unsigned)r) {
                unsigned cc[4] = {c0, c1, c2, c3};
                int d = 0; unsigned ab = G;
                #pragma unroll
                for (int i = 3; i >= 0; --i) {
                    if (ab < (unsigned)r && ab + cc[i] >= (unsigned)r) { d = tid * 4 + i; break; }
                    ab += cc[i];
                }
                sh_digit = d;
                sh_newr = r - (int)ab;
            }
        }
        __syncthreads();
        P |= ((unsigned long long)(unsigned)sh_digit) << shift;
        M |= 0xFFull << shift;
        r = sh_newr;
    }
    unsigned long long T = P;

    for (int e = tid; e < NPIX; e += 1024) {
        unsigned long long k = KEYS[e];
        if (k >= T) {
            int s = atomicAdd(&cnt, 1);
            SEL[s] = k;
        }
    }
    __syncthreads();

    if (tid < NTOP) {
        unsigned long long mine = SEL[tid];
        int rank = 0;
        for (int j = 0; j < NTOP; ++j) rank += (SEL[j] > mine) ? 1 : 0;
        SORT[rank] = mine;
    }
    __syncthreads();

    if (tid < 320) {
        float x1 = 0.f, y1 = 0.f, x2 = 0.f, y2 = 0.f;
        bool v = false;
        if (tid < NTOP) {
            unsigned long long key = SORT[tid];
            int id = (int)(~(unsigned)key);
            float sc = __uint_as_float((unsigned)(key >> 32));
            float wf = decode_dim(wp_), hf = decode_dim(hp_);
            float p0 = preb[id * 4 + 0], p1 = preb[id * 4 + 1];
            float p2 = preb[id * 4 + 2], p3 = preb[id * 4 + 3];
            x1 = fmaxf(p2 - p0 * 0.5f, 0.0f);
            y1 = fmaxf(p3 - p1 * 0.5f, 0.0f);
            x2 = fminf(p2 + p0, wf);
            y2 = fminf(p3 + p1, hf);
            v = sc > 0.5f;
            float bx1 = x1 * 0.0625f, by1 = y1 * 0.0625f;
            float bx2 = x2 * 0.0625f, by2 = y2 * 0.0625f;
            #pragma unroll
            for (int m = 0; m < 14; ++m) {
                int i = m >> 1, s = m & 1;
                float frac = ((float)i + (s ? 0.75f : 0.25f)) / 7.0f;
                float xs = bx1 + frac * (bx2 - bx1);
                float ys = by1 + frac * (by2 - by1);
                float fx = floorf(xs); fx = fminf(fmaxf(fx, 0.0f), 49.0f);
                float fy = floorf(ys); fy = fminf(fmaxf(fy, 0.0f), 49.0f);
                ixb[tid * 14 + m] = (int)fx;
                iyb[tid * 14 + m] = (int)fy;
            }
        }
        X1[tid] = x1; Y1[tid] = y1; X2[tid] = x2; Y2[tid] = y2;
        AR[tid] = fmaxf(x2 - x1, 0.0f) * fmaxf(y2 - y1, 0.0f);
        unsigned long long vb = __ballot(v);
        if (lane == 0 && w < 5) KEEPW[w] = vb;
    }
    __syncthreads();

    if (tid < 320) {
        float xi1 = X1[tid], yi1 = Y1[tid], xi2 = X2[tid], yi2 = Y2[tid], ai = AR[tid];
        #pragma unroll
        for (int jw = 0; jw < 5; ++jw) {
            unsigned long long mword = 0ull;
            #pragma unroll 4
            for (int j2 = 0; j2 < 64; ++j2) {
                int j = jw * 64 + j2;
                float ix1 = fmaxf(xi1, X1[j]);
                float iy1 = fmaxf(yi1, Y1[j]);
                float ix2 = fminf(xi2, X2[j]);
                float iy2 = fminf(yi2, Y2[j]);
                float inter = fmaxf(ix2 - ix1, 0.0f) * fmaxf(iy2 - iy1, 0.0f);
                float iou = inter / fmaxf(ai + AR[j] - inter, 1e-6f);
                bool sup = (iou > 0.7f) && (j > tid) && (j < NTOP);
                mword |= sup ? (1ull << j2) : 0ull;
            }
            MASK[tid][jw] = mword;
        }
    }
    __syncthreads();

    if (tid < 64) {
        unsigned long long m[5][5];
        #pragma unroll
        for (int g = 0; g < 5; ++g)
            #pragma unroll
            for (int q = 0; q < 5; ++q)
                m[g][q] = MASK[g * 64 + lane][q];
        unsigned long long kw0 = KEEPW[0], kw1 = KEEPW[1], kw2 = KEEPW[2],
                           kw3 = KEEPW[3], kw4 = KEEPW[4];
        #pragma unroll
        for (int g = 0; g < 5; ++g) {
            for (int i2 = 0; i2 < 64; ++i2) {
                unsigned long long kg = (g == 0) ? kw0 : (g == 1) ? kw1 :
                                        (g == 2) ? kw2 : (g == 3) ? kw3 : kw4;
                bool alive = (kg >> i2) & 1ull;
                unsigned long long b0 = __shfl(m[g][0], i2, 64);
                unsigned long long b1 = __shfl(m[g][1], i2, 64);
                unsigned long long b2 = __shfl(m[g][2], i2, 64);
                unsigned long long b3 = __shfl(m[g][3], i2, 64);
                unsigned long long b4 = __shfl(m[g][4], i2, 64);
                if (alive) {
                    kw0 &= ~b0; kw1 &= ~b1; kw2 &= ~b2; kw3 &= ~b3; kw4 &= ~b4;
                }
            }
        }
        #pragma unroll
        for (int g = 0; g < 5; ++g) {
            unsigned long long kg = (g == 0) ? kw0 : (g == 1) ? kw1 :
                                    (g == 2) ? kw2 : (g == 3) ? kw3 : kw4;
            int j = g * 64 + lane;
            if (j < NTOP) keep[j] = (int)((kg >> lane) & 1ull);
        }
    }
}

// ---------------- 7. ROI max pool -> A fragments (f16, MFMA per-lane layout) -
__global__ void __launch_bounds__(256)
roipool_frag(const float* __restrict__ fpad, const int* __restrict__ ixb,
             const int* __restrict__ iyb, _Float16* __restrict__ Af) {
    int wid = blockIdx.x * 256 + threadIdx.x;
    if (wid >= MT * KG1 * 64) return;
    int l = wid & 63;
    int g = (wid >> 6) % KG1;
    int T = wid / (KG1 * 64);
    int mm = T * 16 + (l & 15);
    int kbase = g * 32 + ((l >> 4) & 3) * 8;
    union { _Float16 h[8]; uint4 u; } o;
    if (mm < NTOP) {
        const int* ix = ixb + mm * 14;
        const int* iy = iyb + mm * 14;
        #pragma unroll
        for (int e = 0; e < 8; ++e) {
            int k = kbase + e;
            int c = k / 49, ij = k % 49, i = ij / 7, jx = ij % 7;
            int y0 = iy[2 * i] + 1, y1 = iy[2 * i + 1] + 1;
            int x0 = ix[2 * jx] + 1, x1 = ix[2 * jx + 1] + 1;
            const float* f = fpad + (size_t)c * FPSTRIDE;
            float v = fmaxf(fmaxf(f[y0 * 64 + x0], f[y0 * 64 + x1]),
                            fmaxf(f[y1 * 64 + x0], f[y1 * 64 + x1]));
            o.h[e] = (_Float16)v;
        }
    } else {
        o.u.x = 0u; o.u.y = 0u; o.u.z = 0u; o.u.w = 0u;
    }
    *(uint4*)(Af + (size_t)wid * 8) = o.u;
}

// ---------------- 8. full-M MFMA GEMM: 512 thr, BN=64, 2 blocks/CU, kz-grouped --
// 1-D grid of 64*ns blocks: kz = wg % ns (XCD-local A slice ~1 MB -> L2-resident),
// n0 = (wg / ns) * 64. B streamed once (f32->f16, swizzled LDS dbuf, 1 barrier/step).
__global__ void __launch_bounds__(512, 4)
gemm_fullm(const _Float16* __restrict__ Af, const float* __restrict__ B,
           float* __restrict__ part, int K, int KG, int kchunk, int ns) {
    __shared__ char Bs[2][64 * 128];   // 64 rows x 64 f16, swizzled
    int tid = threadIdx.x;
    int lane = tid & 63;
    int w = tid >> 6;
    int wm = w & 3, wn = w >> 2;        // 4 m-groups x 2 n-groups
    int wg = blockIdx.x;
    int kz = wg % ns;
    int n0 = (wg / ns) * 64;
    int ks = kz * kchunk;
    int klen = K - ks; if (klen > kchunk) klen = kchunk;
    int nt = klen >> 6;

    f32x4 acc[5][2];
    #pragma unroll
    for (int tm = 0; tm < 5; ++tm)
        #pragma unroll
        for (int tn = 0; tn < 2; ++tn)
            acc[tm][tn] = f32x4{0.f, 0.f, 0.f, 0.f};

    int srow = tid >> 3;          // 0..63
    int skp  = (tid & 7) * 8;     // 0..56
    const float* bsrc = B + (size_t)(n0 + srow) * K + ks + skp;
    int sboff = srow * 128 + ((skp * 2) ^ ((srow & 7) << 4));

    float4 v0 = *(const float4*)(bsrc);
    float4 v1 = *(const float4*)(bsrc + 4);
    {
        union { _Float16 h[8]; uint4 u; } cv;
        cv.h[0] = (_Float16)v0.x; cv.h[1] = (_Float16)v0.y;
        cv.h[2] = (_Float16)v0.z; cv.h[3] = (_Float16)v0.w;
        cv.h[4] = (_Float16)v1.x; cv.h[5] = (_Float16)v1.y;
        cv.h[6] = (_Float16)v1.z; cv.h[7] = (_Float16)v1.w;
        *(uint4*)(Bs[0] + sboff) = cv.u;
    }
    if (nt > 1) {
        v0 = *(const float4*)(bsrc + 64);
        v1 = *(const float4*)(bsrc + 68);
    }
    __syncthreads();

    for (int k0 = 0; k0 < nt; ++k0) {
        const char* cur = Bs[k0 & 1];
        if (k0 + 1 < nt) {
            union { _Float16 h[8]; uint4 u; } cv;
            cv.h[0] = (_Float16)v0.x; cv.h[1] = (_Float16)v0.y;
            cv.h[2] = (_Float16)v0.z; cv.h[3] = (_Float16)v0.w;
            cv.h[4] = (_Float16)v1.x; cv.h[5] = (_Float16)v1.y;
            cv.h[6] = (_Float16)v1.z; cv.h[7] = (_Float16)v1.w;
            *(uint4*)(Bs[(k0 + 1) & 1] + sboff) = cv.u;
            if (k0 + 2 < nt) {
                v0 = *(const float4*)(bsrc + (k0 + 2) * 64);
                v1 = *(const float4*)(bsrc + (k0 + 2) * 64 + 4);
            }
        }
        int g0 = (ks + k0 * 64) >> 5;
        #pragma unroll
        for (int kk = 0; kk < 2; ++kk) {
            f16x8 bfr[2];
            #pragma unroll
            for (int tn = 0; tn < 2; ++tn) {
                int row = wn * 32 + tn * 16 + (lane & 15);
                int kb = kk * 64 + (lane >> 4) * 16;
                bfr[tn] = *(const f16x8*)(cur + row * 128 + (kb ^ ((row & 7) << 4)));
            }
            f16x8 a[5];
            #pragma unroll
            for (int tm = 0; tm < 5; ++tm) {
                int T = wm * 5 + tm;
                a[tm] = *(const f16x8*)(Af + ((size_t)(T * KG + g0 + kk) * 64 + lane) * 8);
            }
            #pragma unroll
            for (int tm = 0; tm < 5; ++tm)
                #pragma unroll
                for (int tn = 0; tn < 2; ++tn)
                    acc[tm][tn] = __builtin_amdgcn_mfma_f32_16x16x32_f16(a[tm], bfr[tn], acc[tm][tn], 0, 0, 0);
        }
        __syncthreads();
    }
    float* pout = part + (size_t)kz * (NTOP * FCN);
    #pragma unroll
    for (int tm = 0; tm < 5; ++tm) {
        int mbase = (wm * 5 + tm) * 16 + (lane >> 4) * 4;
        #pragma unroll
        for (int j = 0; j < 4; ++j) {
            int m = mbase + j;
            if (m < NTOP) {
                #pragma unroll
                for (int tn = 0; tn < 2; ++tn) {
                    int n = n0 + wn * 32 + tn * 16 + (lane & 15);
                    pout[(size_t)m * FCN + n] = acc[tm][tn][j];
                }
            }
        }
    }
}

// ---------------- 8b. reduce fc1 partials + bias + relu -> h1 fragments f16 --
__global__ void reduce_fc1(const float* __restrict__ part, const float* __restrict__ bias,
                           _Float16* __restrict__ h1f, int ns) {
    int i = blockIdx.x * 256 + threadIdx.x;     // 300*512
    if (i >= NTOP * 512) return;
    int m = i >> 9;
    int f = (i & 511) * 8;
    float s[8];
    const float* p0 = part + (size_t)m * FCN + f;
    #pragma unroll
    for (int e = 0; e < 8; ++e) s[e] = p0[e];
    for (int z = 1; z < ns; ++z) {
        const float* pz = p0 + (size_t)z * (NTOP * FCN);
        #pragma unroll
        for (int e = 0; e < 8; ++e) s[e] += pz[e];
    }
    union { _Float16 h[8]; uint4 u; } o;
    #pragma unroll
    for (int e = 0; e < 8; ++e) o.h[e] = (_Float16)fmaxf(s[e] + bias[f + e], 0.0f);
    int T = m >> 4, g = f >> 5, l = (m & 15) + 16 * ((f >> 3) & 3);
    *(uint4*)(h1f + ((size_t)(T * KG2 + g) * 64 + l) * 8) = o.u;
}

// ---------------- 8c. reduce fc2 partials + bias + relu -> h2 f32 ----------
__global__ void reduce_fc2(const float* __restrict__ part, const float* __restrict__ bias,
                           float* __restrict__ outp, int ns) {
    size_t i = (size_t)blockIdx.x * 256 + threadIdx.x;    // float4 index
    size_t mn4 = (size_t)NTOP * FCN / 4;
    if (i >= mn4) return;
    float4 s = *(const float4*)(part + i * 4);
    for (int zz = 1; zz < ns; ++zz) {
        float4 v = *(const float4*)(part + (size_t)zz * (NTOP * FCN) + i * 4);
        s.x += v.x; s.y += v.y; s.z += v.z; s.w += v.w;
    }
    int n = (int)((i * 4) % FCN);
    float4 b = *(const float4*)(bias + n);
    s.x = fmaxf(s.x + b.x, 0.f); s.y = fmaxf(s.y + b.y, 0.f);
    s.z = fmaxf(s.z + b.z, 0.f); s.w = fmaxf(s.w + b.w, 0.f);
    *(float4*)(outp + i * 4) = s;
}

// ---------------- 9. final heads: wave per output + keep mask ----------------
__global__ void __launch_bounds__(256)
final_k(const float* __restrict__ h2, const float* __restrict__ clsw,
        const float* __restrict__ clsb, const float* __restrict__ boxw,
        const float* __restrict__ boxb, const int* __restrict__ keep,
        float* __restrict__ out) {
    int gid = blockIdx.x * 4 + (threadIdx.x >> 6);
    if (gid >= NTOP * 25) return;
    int lane = threadIdx.x & 63;
    int k = gid / 25, o = gid % 25;
    const float* w;
    float b;
    if (o < 21) { w = clsw + (size_t)o * 4096; b = clsb[o]; }
    else        { w = boxw + (size_t)(o - 21) * 4096; b = boxb[o - 21]; }
    const float* h = h2 + (size_t)k * 4096;
    float s = 0.0f;
    #pragma unroll
    for (int i = 0; i < 16; ++i) {
        float4 hv = *(const float4*)(h + (i * 64 + lane) * 4);
        float4 wv = *(const float4*)(w + (i * 64 + lane) * 4);
        s += hv.x * wv.x + hv.y * wv.y + hv.z * wv.z + hv.w * wv.w;
    }
    #pragma unroll
    for (int off = 1; off < 64; off <<= 1) s += __shfl_xor(s, off, 64);
    if (lane == 0) out[gid] = keep[k] ? (s + b) : 0.0f;
}

// ---------------- launch ----------------
extern "C" void kernel_launch(void* const* d_in, const int* in_sizes, int n_in,
                              void* d_out, int out_size, void* d_ws, size_t ws_size,
                              hipStream_t stream) {
    const float* x    = (const float*)d_in[0];
    const float* Wf   = (const float*)d_in[2];
    const float* bf   = (const float*)d_in[3];
    const float* W1   = (const float*)d_in[4];
    const float* b1   = (const float*)d_in[5];
    const float* Wc   = (const float*)d_in[6];
    const float* bc   = (const float*)d_in[7];
    const float* Wb   = (const float*)d_in[8];
    const float* bb   = (const float*)d_in[9];
    const float* fc1w = (const float*)d_in[10];
    const float* fc1b = (const float*)d_in[11];
    const float* fc2w = (const float*)d_in[12];
    const float* fc2b = (const float*)d_in[13];
    const float* clsw = (const float*)d_in[14];
    const float* clsb = (const float*)d_in[15];
    const float* boxw = (const float*)d_in[16];
    const float* boxb = (const float*)d_in[17];
    const void*  wp   = d_in[18];
    const void*  hp   = d_in[19];

    char* ws = (char*)d_ws;
    float*     fpad  = (float*)(ws + OFF_FPAD);
    float*     score = (float*)(ws + OFF_SCORE);
    float*     preb  = (float*)(ws + OFF_PREB);
    int*       keep  = (int*)(ws + OFF_KEEP);
    int*       ixb   = (int*)(ws + OFF_IX);
    int*       iyb   = (int*)(ws + OFF_IY);
    _Float16*  Af    = (_Float16*)(ws + OFF_AFRAG);
    _Float16*  h1f   = (_Float16*)(ws + OFF_H1F);
    float*     h2    = (float*)(ws + OFF_H2);
    float*     w1t   = (float*)(ws + OFF_W1T);
    float*     out   = (float*)d_out;

    // split-K slots + conv-partial split, guarded by ws_size
    size_t slot = (size_t)NTOP * FCN * 4;   // 4.9 MB
    size_t avail = ws_size > OFF_PART ? (ws_size - OFF_PART) / slot : 0;
    int ns1 = (avail >= 8) ? 8 : (avail >= 4) ? 4 : (avail >= 2) ? 2 : 1;
    int ns2 = ns1;
    float* part1 = (avail >= 1) ? (float*)(ws + OFF_PART) : h2;              // h2 free during fc1
    float* part2 = (avail >= 1) ? (float*)(ws + OFF_PART) : (float*)Af;      // Af free after fc1
    int st1 = (196 + ns1 - 1) / ns1;  int kch1 = st1 * 64;  int ns1e = (196 + st1 - 1) / st1;
    int st2 = (64 + ns2 - 1) / ns2;   int kch2 = st2 * 64;  int ns2e = (64 + st2 - 1) / st2;
    // conv ci-split: 8-way partials (20.5 MB) share OFF_PART (time-disjoint with fc partials)
    int zs = (avail >= 5) ? 8 : 4;
    float* cpart = (avail >= 5) ? (float*)(ws + OFF_PART) : (float*)(ws + OFF_AFRAG);

    prep_k<<<832 + 2304, 256, 0, stream>>>(fpad, W1, w1t);
    patch_conv<<<dim3(10, 64), 256, 0, stream>>>(x, Wf, bf, fpad);
    conv3x3_part<<<dim3(7, 50, zs), 256, 0, stream>>>(fpad, w1t, cpart, 256 / zs);
    reducehead_k<<<625, 256, 0, stream>>>(cpart, b1, Wc, bc, Wb, bb, score, preb, zs);
    topknms_k<<<1, 1024, 0, stream>>>(score, preb, wp, hp, keep, ixb, iyb);
    roipool_frag<<<(MT * KG1 * 64 + 255) / 256, 256, 0, stream>>>(fpad, ixb, iyb, Af);
    gemm_fullm<<<64 * ns1e, 512, 0, stream>>>(Af, fc1w, part1, DFLAT, KG1, kch1, ns1e);
    reduce_fc1<<<(NTOP * 512 + 255) / 256, 256, 0, stream>>>(part1, fc1b, h1f, ns1e);
    gemm_fullm<<<64 * ns2e, 512, 0, stream>>>(h1f, fc2w, part2, FCN, KG2, kch2, ns2e);
    reduce_fc2<<<(NTOP * FCN / 4 + 255) / 256, 256, 0, stream>>>(part2, fc2b, h2, ns2e);
    final_k<<<(NTOP * 25 + 3) / 4, 256, 0, stream>>>(h2, clsw, clsb, boxw, boxb, keep, out);
}

// Round 11
// 341.944 us; speedup vs baseline: 5.8814x; 1.0028x over previous
//
#include <hip/hip_runtime.h>
#include <hip/hip_bf16.h>
#include <math.h>

// ---------------- problem constants ----------------
#define NPIX   2500      // 50*50
#define CFEAT  256
#define NTOP   300
#define DFLAT  12544     // 256*7*7
#define FCN    4096
#define FPSTRIDE 3328    // 52 rows * 64 floats per channel (padded feature)
#define KG1    392       // DFLAT/32
#define KG2    128       // FCN/32
#define MT     20        // m-tiles (320 rows padded)

typedef _Float16 f16x8 __attribute__((ext_vector_type(8)));
typedef float    f32x4 __attribute__((ext_vector_type(4)));

// ---------------- workspace offsets (bytes) ----------------
static constexpr size_t OFF_FPAD  = 0;          // 3.4 MB
static constexpr size_t OFF_SCORE = 0x5C0000;
static constexpr size_t OFF_PREB  = 0x5D0000;
static constexpr size_t OFF_KEEP  = 0x5E5000;
static constexpr size_t OFF_IX    = 0x5E6000;
static constexpr size_t OFF_IY    = 0x5EB000;
static constexpr size_t OFF_AFRAG = 0x600000;   // A fragments f16, 8.03 MB
static constexpr size_t OFF_H1F   = 0xE00000;   // h1 fragments f16, 2.62 MB
static constexpr size_t OFF_H2    = 0x1100000;  // h2 f32, 4.9 MB
static constexpr size_t OFF_W1T   = 0x1600000;  // 2.36 MB transient
static constexpr size_t OFF_PART  = 0x1900000;  // cpart (20.5 MB) then split-K partials, time-disjoint

__device__ inline float decode_dim(const void* p) {
    int iv = *(const int*)p;
    if (iv > 0 && iv < (1 << 20)) return (float)iv;
    return __int_as_float(iv);
}

// ---------------- 0. fused: zero padded feature buffer + transpose W1 -------
__global__ void prep_k(float* __restrict__ fpad, const float* __restrict__ W1,
                       float* __restrict__ W1t) {
    int b = blockIdx.x;
    if (b < 832) {
        int i = b * 256 + threadIdx.x;   // float4 index, 212992 total
        if (i < 212992) *(float4*)(fpad + (size_t)i * 4) = make_float4(0.f, 0.f, 0.f, 0.f);
    } else {
        int idx = (b - 832) * 256 + threadIdx.x;
        if (idx < 2304 * 256) {
            int r = idx >> 8, co = idx & 255;
            W1t[idx] = W1[co * 2304 + r];
        }
    }
}

// ---------------- 1. patchify conv -> padded feat -----
// grid (64, 10): co-group FASTEST so concurrent blocks share the same x tile (L2).
__global__ void __launch_bounds__(256)
patch_conv(const float* __restrict__ x, const float* __restrict__ Wf,
           const float* __restrict__ bf, float* __restrict__ fpad) {
    __shared__ float w[3072];          // 4 co x 768
    int co0 = blockIdx.x * 4;
    for (int t = threadIdx.x; t < 3072; t += 256) w[t] = Wf[co0 * 768 + t];
    __syncthreads();
    int p = blockIdx.y * 256 + threadIdx.x;
    if (p >= NPIX) return;
    int py = p / 50, px = p % 50;
    float acc[4];
    #pragma unroll
    for (int c = 0; c < 4; ++c) acc[c] = bf[co0 + c];
    for (int ci = 0; ci < 3; ++ci) {
        const float* xp = x + ci * 640000 + (py * 16) * 800 + px * 16;
        #pragma unroll
        for (int ky = 0; ky < 16; ++ky) {
            const float* row = xp + ky * 800;
            #pragma unroll
            for (int kq = 0; kq < 4; ++kq) {
                float4 xv = *reinterpret_cast<const float4*>(row + kq * 4);
                int kb = ci * 256 + ky * 16 + kq * 4;
                #pragma unroll
                for (int c = 0; c < 4; ++c) {
                    const float* wc = w + c * 768 + kb;
                    acc[c] += xv.x * wc[0] + xv.y * wc[1] + xv.z * wc[2] + xv.w * wc[3];
                }
            }
        }
    }
    size_t o = (size_t)(py + 1) * 64 + (px + 1);
    #pragma unroll
    for (int c = 0; c < 4; ++c) fpad[(size_t)(co0 + c) * FPSTRIDE + o] = acc[c];
}

// ---------------- 2. 3x3 SAME conv partials (lanes=co, 8-pixel batch, ci split) --
__global__ void __launch_bounds__(256)
conv3x3_part(const float* __restrict__ fpad, const float* __restrict__ W1t,
             float* __restrict__ cpart, int zci) {
    int co = threadIdx.x;
    int xb = blockIdx.x * 8;          // 0,8,...,48
    int y  = blockIdx.y;              // 0..49
    int z  = blockIdx.z;
    float acc[8];
    #pragma unroll
    for (int p = 0; p < 8; ++p) acc[p] = 0.0f;
    const float* fp = fpad + (size_t)(z * zci) * FPSTRIDE + (size_t)y * 64 + xb;
    const float* wp = W1t + (size_t)(z * zci) * 9 * 256 + co;
    #pragma unroll 2
    for (int ci = 0; ci < zci; ++ci) {
        float v[3][12];
        #pragma unroll
        for (int dy = 0; dy < 3; ++dy) {
            #pragma unroll
            for (int q = 0; q < 3; ++q) {
                float4 r4 = *(const float4*)(fp + dy * 64 + q * 4);
                v[dy][q * 4 + 0] = r4.x; v[dy][q * 4 + 1] = r4.y;
                v[dy][q * 4 + 2] = r4.z; v[dy][q * 4 + 3] = r4.w;
            }
        }
        float wv[9];
        #pragma unroll
        for (int k = 0; k < 9; ++k) wv[k] = wp[k * 256];
        #pragma unroll
        for (int dy = 0; dy < 3; ++dy)
            #pragma unroll
            for (int dx = 0; dx < 3; ++dx) {
                float wvv = wv[dy * 3 + dx];
                #pragma unroll
                for (int p = 0; p < 8; ++p)
                    acc[p] += v[dy][p + dx] * wvv;
            }
        fp += FPSTRIDE;
        wp += 9 * 256;
    }
    size_t base = (size_t)z * (NPIX * 256) + (size_t)(y * 50 + xb) * 256 + co;
    #pragma unroll
    for (int p = 0; p < 8; ++p)
        if (xb + p < 50) cpart[base + (size_t)p * 256] = acc[p];
}

// ---------------- 2b+3. fused: reduce conv partials + bias + relu + heads ---
__global__ void __launch_bounds__(256)
reducehead_k(const float* __restrict__ cpart, const float* __restrict__ b1,
             const float* __restrict__ Wc, const float* __restrict__ bc,
             const float* __restrict__ Wb, const float* __restrict__ bb,
             float* __restrict__ score, float* __restrict__ preb, int zs) {
    int lane = threadIdx.x & 63;
    int p = blockIdx.x * 4 + (threadIdx.x >> 6);
    if (p >= NPIX) return;
    size_t off = (size_t)p * 256 + lane * 4;
    float4 h = *(const float4*)(cpart + off);
    for (int z = 1; z < zs; ++z) {
        float4 v = *(const float4*)(cpart + (size_t)z * (NPIX * 256) + off);
        h.x += v.x; h.y += v.y; h.z += v.z; h.w += v.w;
    }
    float4 b = *(const float4*)(b1 + lane * 4);
    h.x = fmaxf(h.x + b.x, 0.f); h.y = fmaxf(h.y + b.y, 0.f);
    h.z = fmaxf(h.z + b.z, 0.f); h.w = fmaxf(h.w + b.w, 0.f);
    float4 c0 = *(const float4*)(Wc + lane * 4);
    float4 c1 = *(const float4*)(Wc + 256 + lane * 4);
    float4 w0 = *(const float4*)(Wb + lane * 4);
    float4 w1 = *(const float4*)(Wb + 256 + lane * 4);
    float4 w2 = *(const float4*)(Wb + 512 + lane * 4);
    float4 w3 = *(const float4*)(Wb + 768 + lane * 4);
    float s[6];
    s[0] = h.x*c0.x + h.y*c0.y + h.z*c0.z + h.w*c0.w;
    s[1] = h.x*c1.x + h.y*c1.y + h.z*c1.z + h.w*c1.w;
    s[2] = h.x*w0.x + h.y*w0.y + h.z*w0.z + h.w*w0.w;
    s[3] = h.x*w1.x + h.y*w1.y + h.z*w1.z + h.w*w1.w;
    s[4] = h.x*w2.x + h.y*w2.y + h.z*w2.z + h.w*w2.w;
    s[5] = h.x*w3.x + h.y*w3.y + h.z*w3.z + h.w*w3.w;
    #pragma unroll
    for (int o = 1; o < 64; o <<= 1) {
        #pragma unroll
        for (int q = 0; q < 6; ++q) s[q] += __shfl_xor(s[q], o, 64);
    }
    if (lane == 0) {
        float s0 = s[0] + bc[0], s1 = s[1] + bc[1];
        float m = fmaxf(s0, s1);
        float e0 = expf(s0 - m), e1 = expf(s1 - m);
        score[p] = e1 / (e0 + e1);
        preb[p * 4 + 0] = s[2] + bb[0];
        preb[p * 4 + 1] = s[3] + bb[1];
        preb[p * 4 + 2] = s[4] + bb[2];
        preb[p * 4 + 3] = s[5] + bb[3];
    }
}

// ---------------- 4+5+6. fused radix-select top-k + box decode + bitmask NMS --
// 48-bit key = (score_bits << 12) | (~idx & 0xFFF): unique, desc == (score desc, idx asc)
__global__ void __launch_bounds__(1024)
topknms_k(const float* __restrict__ score, const float* __restrict__ preb,
          const void* wp_, const void* hp_, int* __restrict__ keep,
          int* __restrict__ ixb, int* __restrict__ iyb) {
    __shared__ unsigned long long KEYS[NPIX];
    __shared__ unsigned int whist[16][256];     // per-wave histograms
    __shared__ int sh_digit, sh_newr, cnt;
    __shared__ unsigned long long SEL[NTOP];
    __shared__ unsigned long long SORT[NTOP];
    __shared__ float X1[320], Y1[320], X2[320], Y2[320], AR[320];
    __shared__ unsigned long long MASK[320][5];
    __shared__ unsigned long long KEEPW[5];
    int tid = threadIdx.x;
    int lane = tid & 63;
    int w = tid >> 6;

    for (int e = tid; e < NPIX; e += 1024) {
        unsigned sb = __float_as_uint(score[e]);
        KEYS[e] = ((unsigned long long)sb << 12) | (unsigned)((~e) & 0xFFF);
    }
    if (tid == 0) cnt = 0;
    __syncthreads();

    unsigned long long P = 0ull, M = 0ull;
    int r = NTOP;
    for (int pass = 0; pass < 6; ++pass) {
        int shift = 40 - 8 * pass;
        *(uint4*)&whist[w][lane * 4] = uint4{0u, 0u, 0u, 0u};
        for (int e = tid; e < NPIX; e += 1024) {
            unsigned long long k = KEYS[e];
            if ((k & M) == P)
                atomicAdd(&whist[w][(unsigned)(k >> shift) & 255u], 1u);
        }
        __syncthreads();
        if (tid < 64) {
            unsigned c0 = 0, c1 = 0, c2 = 0, c3 = 0;
            #pragma unroll
            for (int ww = 0; ww < 16; ++ww) {
                c0 += whist[ww][tid * 4 + 0];
                c1 += whist[ww][tid * 4 + 1];
                c2 += whist[ww][tid * 4 + 2];
                c3 += whist[ww][tid * 4 + 3];
            }
            unsigned sl = c0 + c1 + c2 + c3;
            unsigned suf = sl;
            #pragma unroll
            for (int off = 1; off < 64; off <<= 1) {
                unsigned o = __shfl_down(suf, off, 64);
                if (lane + off < 64) suf += o;
            }
            unsigned G = suf - sl;
            if (G < (unsigned)r && G + sl >= (unsigned)r) {
                unsigned cc[4] = {c0, c1, c2, c3};
                int d = 0; unsigned ab = G;
                #pragma unroll
                for (int i = 3; i >= 0; --i) {
                    if (ab < (unsigned)r && ab + cc[i] >= (unsigned)r) { d = tid * 4 + i; break; }
                    ab += cc[i];
                }
                sh_digit = d;
                sh_newr = r - (int)ab;
            }
        }
        __syncthreads();
        P |= ((unsigned long long)(unsigned)sh_digit) << shift;
        M |= 0xFFull << shift;
        r = sh_newr;
    }
    unsigned long long T = P;

    for (int e = tid; e < NPIX; e += 1024) {
        unsigned long long k = KEYS[e];
        if (k >= T) {
            int s = atomicAdd(&cnt, 1);
            SEL[s] = k;
        }
    }
    __syncthreads();

    if (tid < NTOP) {
        unsigned long long mine = SEL[tid];
        int rank = 0;
        for (int j = 0; j < NTOP; ++j) rank += (SEL[j] > mine) ? 1 : 0;
        SORT[rank] = mine;
    }
    __syncthreads();

    if (tid < 320) {
        float x1 = 0.f, y1 = 0.f, x2 = 0.f, y2 = 0.f;
        bool v = false;
        if (tid < NTOP) {
            unsigned long long key = SORT[tid];
            int id = 4095 - (int)(key & 0xFFF);
            float sc = __uint_as_float((unsigned)(key >> 12));
            float wf = decode_dim(wp_), hf = decode_dim(hp_);
            float p0 = preb[id * 4 + 0], p1 = preb[id * 4 + 1];
            float p2 = preb[id * 4 + 2], p3 = preb[id * 4 + 3];
            x1 = fmaxf(p2 - p0 * 0.5f, 0.0f);
            y1 = fmaxf(p3 - p1 * 0.5f, 0.0f);
            x2 = fminf(p2 + p0, wf);
            y2 = fminf(p3 + p1, hf);
            v = sc > 0.5f;
            float bx1 = x1 * 0.0625f, by1 = y1 * 0.0625f;
            float bx2 = x2 * 0.0625f, by2 = y2 * 0.0625f;
            #pragma unroll
            for (int m = 0; m < 14; ++m) {
                int i = m >> 1, s = m & 1;
                float frac = ((float)i + (s ? 0.75f : 0.25f)) / 7.0f;
                float xs = bx1 + frac * (bx2 - bx1);
                float ys = by1 + frac * (by2 - by1);
                float fx = floorf(xs); fx = fminf(fmaxf(fx, 0.0f), 49.0f);
                float fy = floorf(ys); fy = fminf(fmaxf(fy, 0.0f), 49.0f);
                ixb[tid * 14 + m] = (int)fx;
                iyb[tid * 14 + m] = (int)fy;
            }
        }
        X1[tid] = x1; Y1[tid] = y1; X2[tid] = x2; Y2[tid] = y2;
        AR[tid] = fmaxf(x2 - x1, 0.0f) * fmaxf(y2 - y1, 0.0f);
        unsigned long long vb = __ballot(v);
        if (lane == 0 && w < 5) KEEPW[w] = vb;
    }
    __syncthreads();

    if (tid < 320) {
        float xi1 = X1[tid], yi1 = Y1[tid], xi2 = X2[tid], yi2 = Y2[tid], ai = AR[tid];
        #pragma unroll
        for (int jw = 0; jw < 5; ++jw) {
            unsigned long long mword = 0ull;
            #pragma unroll 4
            for (int j2 = 0; j2 < 64; ++j2) {
                int j = jw * 64 + j2;
                float ix1 = fmaxf(xi1, X1[j]);
                float iy1 = fmaxf(yi1, Y1[j]);
                float ix2 = fminf(xi2, X2[j]);
                float iy2 = fminf(yi2, Y2[j]);
                float inter = fmaxf(ix2 - ix1, 0.0f) * fmaxf(iy2 - iy1, 0.0f);
                float iou = inter / fmaxf(ai + AR[j] - inter, 1e-6f);
                bool sup = (iou > 0.7f) && (j > tid) && (j < NTOP);
                mword |= sup ? (1ull << j2) : 0ull;
            }
            MASK[tid][jw] = mword;
        }
    }
    __syncthreads();

    if (tid < 64) {
        unsigned long long m[5][5];
        #pragma unroll
        for (int g = 0; g < 5; ++g)
            #pragma unroll
            for (int q = 0; q < 5; ++q)
                m[g][q] = MASK[g * 64 + lane][q];
        unsigned long long kw0 = KEEPW[0], kw1 = KEEPW[1], kw2 = KEEPW[2],
                           kw3 = KEEPW[3], kw4 = KEEPW[4];
        #pragma unroll
        for (int g = 0; g < 5; ++g) {
            for (int i2 = 0; i2 < 64; ++i2) {
                unsigned long long kg = (g == 0) ? kw0 : (g == 1) ? kw1 :
                                        (g == 2) ? kw2 : (g == 3) ? kw3 : kw4;
                bool alive = (kg >> i2) & 1ull;
                unsigned long long b0 = __shfl(m[g][0], i2, 64);
                unsigned long long b1 = __shfl(m[g][1], i2, 64);
                unsigned long long b2 = __shfl(m[g][2], i2, 64);
                unsigned long long b3 = __shfl(m[g][3], i2, 64);
                unsigned long long b4 = __shfl(m[g][4], i2, 64);
                if (alive) {
                    kw0 &= ~b0; kw1 &= ~b1; kw2 &= ~b2; kw3 &= ~b3; kw4 &= ~b4;
                }
            }
        }
        #pragma unroll
        for (int g = 0; g < 5; ++g) {
            unsigned long long kg = (g == 0) ? kw0 : (g == 1) ? kw1 :
                                    (g == 2) ? kw2 : (g == 3) ? kw3 : kw4;
            int j = g * 64 + lane;
            if (j < NTOP) keep[j] = (int)((kg >> lane) & 1ull);
        }
    }
}

// ---------------- 7. ROI max pool -> A fragments (f16, MFMA per-lane layout) -
__global__ void __launch_bounds__(256)
roipool_frag(const float* __restrict__ fpad, const int* __restrict__ ixb,
             const int* __restrict__ iyb, _Float16* __restrict__ Af) {
    int wid = blockIdx.x * 256 + threadIdx.x;
    if (wid >= MT * KG1 * 64) return;
    int l = wid & 63;
    int g = (wid >> 6) % KG1;
    int T = wid / (KG1 * 64);
    int mm = T * 16 + (l & 15);
    int kbase = g * 32 + ((l >> 4) & 3) * 8;
    union { _Float16 h[8]; uint4 u; } o;
    if (mm < NTOP) {
        const int* ix = ixb + mm * 14;
        const int* iy = iyb + mm * 14;
        #pragma unroll
        for (int e = 0; e < 8; ++e) {
            int k = kbase + e;
            int c = k / 49, ij = k % 49, i = ij / 7, jx = ij % 7;
            int y0 = iy[2 * i] + 1, y1 = iy[2 * i + 1] + 1;
            int x0 = ix[2 * jx] + 1, x1 = ix[2 * jx + 1] + 1;
            const float* f = fpad + (size_t)c * FPSTRIDE;
            float v = fmaxf(fmaxf(f[y0 * 64 + x0], f[y0 * 64 + x1]),
                            fmaxf(f[y1 * 64 + x0], f[y1 * 64 + x1]));
            o.h[e] = (_Float16)v;
        }
    } else {
        o.u.x = 0u; o.u.y = 0u; o.u.z = 0u; o.u.w = 0u;
    }
    *(uint4*)(Af + (size_t)wid * 8) = o.u;
}

// ---------------- 8. full-M MFMA GEMM: 512 thr, BN=64, 3-deep B pipeline -----
// 1-D grid of 64*ns blocks: kz = wg % ns (ns=8 aligns kz with XCD round-robin
// -> per-XCD A slice ~1 MB L2-resident). B streamed once, loads 2 iters ahead.
__global__ void __launch_bounds__(512, 4)
gemm_fullm(const _Float16* __restrict__ Af, const float* __restrict__ B,
           float* __restrict__ part, int K, int KG, int kchunk, int ns) {
    __shared__ char Bs[2][64 * 128];   // 64 rows x 64 f16, swizzled
    int tid = threadIdx.x;
    int lane = tid & 63;
    int w = tid >> 6;
    int wm = w & 3, wn = w >> 2;        // 4 m-groups x 2 n-groups
    int wg = blockIdx.x;
    int kz = wg % ns;
    int n0 = (wg / ns) * 64;
    int ks = kz * kchunk;
    int klen = K - ks; if (klen > kchunk) klen = kchunk;
    int nt = klen >> 6;

    f32x4 acc[5][2];
    #pragma unroll
    for (int tm = 0; tm < 5; ++tm)
        #pragma unroll
        for (int tn = 0; tn < 2; ++tn)
            acc[tm][tn] = f32x4{0.f, 0.f, 0.f, 0.f};

    int srow = tid >> 3;          // 0..63
    int skp  = (tid & 7) * 8;     // 0..56
    const float* bsrc = B + (size_t)(n0 + srow) * K + ks + skp;
    int sboff = srow * 128 + ((skp * 2) ^ ((srow & 7) << 4));

    // 3-deep pipeline: c1 = loads for step k0+1, c2 = step k0+2 (rotated)
    float4 c0a = *(const float4*)(bsrc);
    float4 c0b = *(const float4*)(bsrc + 4);
    float4 c1a, c1b, c2a, c2b;
    if (nt > 1) { c1a = *(const float4*)(bsrc + 64);  c1b = *(const float4*)(bsrc + 68); }
    if (nt > 2) { c2a = *(const float4*)(bsrc + 128); c2b = *(const float4*)(bsrc + 132); }
    {
        union { _Float16 h[8]; uint4 u; } cv;
        cv.h[0] = (_Float16)c0a.x; cv.h[1] = (_Float16)c0a.y;
        cv.h[2] = (_Float16)c0a.z; cv.h[3] = (_Float16)c0a.w;
        cv.h[4] = (_Float16)c0b.x; cv.h[5] = (_Float16)c0b.y;
        cv.h[6] = (_Float16)c0b.z; cv.h[7] = (_Float16)c0b.w;
        *(uint4*)(Bs[0] + sboff) = cv.u;
    }
    __syncthreads();

    for (int k0 = 0; k0 < nt; ++k0) {
        const char* cur = Bs[k0 & 1];
        if (k0 + 1 < nt) {
            union { _Float16 h[8]; uint4 u; } cv;
            cv.h[0] = (_Float16)c1a.x; cv.h[1] = (_Float16)c1a.y;
            cv.h[2] = (_Float16)c1a.z; cv.h[3] = (_Float16)c1a.w;
            cv.h[4] = (_Float16)c1b.x; cv.h[5] = (_Float16)c1b.y;
            cv.h[6] = (_Float16)c1b.z; cv.h[7] = (_Float16)c1b.w;
            *(uint4*)(Bs[(k0 + 1) & 1] + sboff) = cv.u;
        }
        // rotate pipeline and issue load for step k0+3 (2 iterations of latency cover)
        c1a = c2a; c1b = c2b;
        if (k0 + 3 < nt) {
            c2a = *(const float4*)(bsrc + (k0 + 3) * 64);
            c2b = *(const float4*)(bsrc + (k0 + 3) * 64 + 4);
        }
        int g0 = (ks + k0 * 64) >> 5;
        #pragma unroll
        for (int kk = 0; kk < 2; ++kk) {
            f16x8 bfr[2];
            #pragma unroll
            for (int tn = 0; tn < 2; ++tn) {
                int row = wn * 32 + tn * 16 + (lane & 15);
                int kb = kk * 64 + (lane >> 4) * 16;
                bfr[tn] = *(const f16x8*)(cur + row * 128 + (kb ^ ((row & 7) << 4)));
            }
            f16x8 a[5];
            #pragma unroll
            for (int tm = 0; tm < 5; ++tm) {
                int T = wm * 5 + tm;
                a[tm] = *(const f16x8*)(Af + ((size_t)(T * KG + g0 + kk) * 64 + lane) * 8);
            }
            #pragma unroll
            for (int tm = 0; tm < 5; ++tm)
                #pragma unroll
                for (int tn = 0; tn < 2; ++tn)
                    acc[tm][tn] = __builtin_amdgcn_mfma_f32_16x16x32_f16(a[tm], bfr[tn], acc[tm][tn], 0, 0, 0);
        }
        __syncthreads();
    }
    float* pout = part + (size_t)kz * (NTOP * FCN);
    #pragma unroll
    for (int tm = 0; tm < 5; ++tm) {
        int mbase = (wm * 5 + tm) * 16 + (lane >> 4) * 4;
        #pragma unroll
        for (int j = 0; j < 4; ++j) {
            int m = mbase + j;
            if (m < NTOP) {
                #pragma unroll
                for (int tn = 0; tn < 2; ++tn) {
                    int n = n0 + wn * 32 + tn * 16 + (lane & 15);
                    pout[(size_t)m * FCN + n] = acc[tm][tn][j];
                }
            }
        }
    }
}

// ---------------- 8b. reduce fc1 partials + bias + relu -> h1 fragments f16 --
__global__ void reduce_fc1(const float* __restrict__ part, const float* __restrict__ bias,
                           _Float16* __restrict__ h1f, int ns) {
    int i = blockIdx.x * 256 + threadIdx.x;     // 300*512
    if (i >= NTOP * 512) return;
    int m = i >> 9;
    int f = (i & 511) * 8;
    float s[8];
    const float* p0 = part + (size_t)m * FCN + f;
    #pragma unroll
    for (int e = 0; e < 8; ++e) s[e] = p0[e];
    for (int z = 1; z < ns; ++z) {
        const float* pz = p0 + (size_t)z * (NTOP * FCN);
        #pragma unroll
        for (int e = 0; e < 8; ++e) s[e] += pz[e];
    }
    union { _Float16 h[8]; uint4 u; } o;
    #pragma unroll
    for (int e = 0; e < 8; ++e) o.h[e] = (_Float16)fmaxf(s[e] + bias[f + e], 0.0f);
    int T = m >> 4, g = f >> 5, l = (m & 15) + 16 * ((f >> 3) & 3);
    *(uint4*)(h1f + ((size_t)(T * KG2 + g) * 64 + l) * 8) = o.u;
}

// ---------------- 8c. reduce fc2 partials + bias + relu -> h2 f32 ----------
__global__ void reduce_fc2(const float* __restrict__ part, const float* __restrict__ bias,
                           float* __restrict__ outp, int ns) {
    size_t i = (size_t)blockIdx.x * 256 + threadIdx.x;    // float4 index
    size_t mn4 = (size_t)NTOP * FCN / 4;
    if (i >= mn4) return;
    float4 s = *(const float4*)(part + i * 4);
    for (int zz = 1; zz < ns; ++zz) {
        float4 v = *(const float4*)(part + (size_t)zz * (NTOP * FCN) + i * 4);
        s.x += v.x; s.y += v.y; s.z += v.z; s.w += v.w;
    }
    int n = (int)((i * 4) % FCN);
    float4 b = *(const float4*)(bias + n);
    s.x = fmaxf(s.x + b.x, 0.f); s.y = fmaxf(s.y + b.y, 0.f);
    s.z = fmaxf(s.z + b.z, 0.f); s.w = fmaxf(s.w + b.w, 0.f);
    *(float4*)(outp + i * 4) = s;
}

// ---------------- 9. final heads: wave per output + keep mask ----------------
__global__ void __launch_bounds__(256)
final_k(const float* __restrict__ h2, const float* __restrict__ clsw,
        const float* __restrict__ clsb, const float* __restrict__ boxw,
        const float* __restrict__ boxb, const int* __restrict__ keep,
        float* __restrict__ out) {
    int gid = blockIdx.x * 4 + (threadIdx.x >> 6);
    if (gid >= NTOP * 25) return;
    int lane = threadIdx.x & 63;
    int k = gid / 25, o = gid % 25;
    const float* w;
    float b;
    if (o < 21) { w = clsw + (size_t)o * 4096; b = clsb[o]; }
    else        { w = boxw + (size_t)(o - 21) * 4096; b = boxb[o - 21]; }
    const float* h = h2 + (size_t)k * 4096;
    float s = 0.0f;
    #pragma unroll
    for (int i = 0; i < 16; ++i) {
        float4 hv = *(const float4*)(h + (i * 64 + lane) * 4);
        float4 wv = *(const float4*)(w + (i * 64 + lane) * 4);
        s += hv.x * wv.x + hv.y * wv.y + hv.z * wv.z + hv.w * wv.w;
    }
    #pragma unroll
    for (int off = 1; off < 64; off <<= 1) s += __shfl_xor(s, off, 64);
    if (lane == 0) out[gid] = keep[k] ? (s + b) : 0.0f;
}

// ---------------- launch ----------------
extern "C" void kernel_launch(void* const* d_in, const int* in_sizes, int n_in,
                              void* d_out, int out_size, void* d_ws, size_t ws_size,
                              hipStream_t stream) {
    const float* x    = (const float*)d_in[0];
    const float* Wf   = (const float*)d_in[2];
    const float* bf   = (const float*)d_in[3];
    const float* W1   = (const float*)d_in[4];
    const float* b1   = (const float*)d_in[5];
    const float* Wc   = (const float*)d_in[6];
    const float* bc   = (const float*)d_in[7];
    const float* Wb   = (const float*)d_in[8];
    const float* bb   = (const float*)d_in[9];
    const float* fc1w = (const float*)d_in[10];
    const float* fc1b = (const float*)d_in[11];
    const float* fc2w = (const float*)d_in[12];
    const float* fc2b = (const float*)d_in[13];
    const float* clsw = (const float*)d_in[14];
    const float* clsb = (const float*)d_in[15];
    const float* boxw = (const float*)d_in[16];
    const float* boxb = (const float*)d_in[17];
    const void*  wp   = d_in[18];
    const void*  hp   = d_in[19];

    char* ws = (char*)d_ws;
    float*     fpad  = (float*)(ws + OFF_FPAD);
    float*     score = (float*)(ws + OFF_SCORE);
    float*     preb  = (float*)(ws + OFF_PREB);
    int*       keep  = (int*)(ws + OFF_KEEP);
    int*       ixb   = (int*)(ws + OFF_IX);
    int*       iyb   = (int*)(ws + OFF_IY);
    _Float16*  Af    = (_Float16*)(ws + OFF_AFRAG);
    _Float16*  h1f   = (_Float16*)(ws + OFF_H1F);
    float*     h2    = (float*)(ws + OFF_H2);
    float*     w1t   = (float*)(ws + OFF_W1T);
    float*     out   = (float*)d_out;

    // split-K slots + conv-partial split, guarded by ws_size
    size_t slot = (size_t)NTOP * FCN * 4;   // 4.9 MB
    size_t avail = ws_size > OFF_PART ? (ws_size - OFF_PART) / slot : 0;
    int ns1 = (avail >= 8) ? 8 : (avail >= 4) ? 4 : (avail >= 2) ? 2 : 1;
    int ns2 = ns1;
    float* part1 = (avail >= 1) ? (float*)(ws + OFF_PART) : h2;              // h2 free during fc1
    float* part2 = (avail >= 1) ? (float*)(ws + OFF_PART) : (float*)Af;      // Af free after fc1
    int st1 = (196 + ns1 - 1) / ns1;  int kch1 = st1 * 64;  int ns1e = (196 + st1 - 1) / st1;
    int st2 = (64 + ns2 - 1) / ns2;   int kch2 = st2 * 64;  int ns2e = (64 + st2 - 1) / st2;
    // conv ci-split: 8-way partials (20.5 MB) share OFF_PART (time-disjoint with fc partials)
    int zs = (avail >= 5) ? 8 : 4;
    float* cpart = (avail >= 5) ? (float*)(ws + OFF_PART) : (float*)(ws + OFF_AFRAG);

    prep_k<<<832 + 2304, 256, 0, stream>>>(fpad, W1, w1t);
    patch_conv<<<dim3(64, 10), 256, 0, stream>>>(x, Wf, bf, fpad);
    conv3x3_part<<<dim3(7, 50, zs), 256, 0, stream>>>(fpad, w1t, cpart, 256 / zs);
    reducehead_k<<<625, 256, 0, stream>>>(cpart, b1, Wc, bc, Wb, bb, score, preb, zs);
    topknms_k<<<1, 1024, 0, stream>>>(score, preb, wp, hp, keep, ixb, iyb);
    roipool_frag<<<(MT * KG1 * 64 + 255) / 256, 256, 0, stream>>>(fpad, ixb, iyb, Af);
    gemm_fullm<<<64 * ns1e, 512, 0, stream>>>(Af, fc1w, part1, DFLAT, KG1, kch1, ns1e);
    reduce_fc1<<<(NTOP * 512 + 255) / 256, 256, 0, stream>>>(part1, fc1b, h1f, ns1e);
    gemm_fullm<<<64 * ns2e, 512, 0, stream>>>(h1f, fc2w, part2, FCN, KG2, kch2, ns2e);
    reduce_fc2<<<(NTOP * FCN / 4 + 255) / 256, 256, 0, stream>>>(part2, fc2b, h2, ns2e);
    final_k<<<(NTOP * 25 + 3) / 4, 256, 0, stream>>>(h2, clsw, clsb, boxw, boxb, keep, out);
}